// Round 3
// baseline (19244.156 us; speedup 1.0000x reference)
//
#include <hip/hip_runtime.h>

// ---------------- problem constants ----------------
constexpr int NB  = 4;      // batch
constexpr int NT  = 512;    // seq len
constexpr int ND  = 1024;   // model dim
constexpr int NL  = 12;     // layers
constexpr int NH  = 16;     // heads
constexpr int NF  = 4096;   // ffn dim
constexpr int NHD = 64;     // head dim
constexpr int NBT = NB * NT;   // 2048 token rows
constexpr int NV  = 32000;  // vocab

// =====================================================================
// Generic tiled fp32 GEMM.
//   C[M,N] = A[M,K] @ B[K,N]            (TRANSB=false, B row-major [K,N])
//   C[M,N] = A[M,K] @ Bt[N,K]^T         (TRANSB=true,  B row-major [N,K])
// EPI: 0 = plain store (+bias, +addsrc), 1 = gelu(tanh) after bias,
//      2 = TXL rel-shift accumulate: C[t][t+n-(M-1)] += v  (no bias/add)
// Optional two-level batch: z -> (zb=z/bdiv, zh=z%bdiv) with strides.
// Requirements: K % 16 == 0, N % 4 == 0, 16B-aligned base pointers,
//               lda/ldb % 4 == 0. (All call sites below satisfy these.)
// =====================================================================
template<int BM, int BN, int TM, int TN, bool TRANSB, int EPI>
__global__ __launch_bounds__(256)
void sgemm_k(const float* __restrict__ A, const float* __restrict__ Bm,
             float* __restrict__ C,
             const float* __restrict__ bias, const float* __restrict__ addsrc,
             int M, int N, int K, int lda, int ldb, int ldc,
             int bdiv, long sAb, long sAh, long sBb, long sBh, long sCb, long sCh)
{
    constexpr int BK = 16;
    static_assert((BM / TM) * (BN / TN) == 256, "256 threads");
    if (bdiv > 0) {
        int z  = blockIdx.z;
        int zb = z / bdiv, zh = z % bdiv;
        A  += zb * sAb + zh * sAh;
        Bm += zb * sBb + zh * sBh;
        long co = zb * sCb + zh * sCh;
        C += co;
        if (addsrc) addsrc += co;
    }
    __shared__ float As[BK][BM + 4];
    __shared__ float Bs[BK][BN + 4];
    const int tid  = threadIdx.x;
    const int tx   = tid % (BN / TN);
    const int ty   = tid / (BN / TN);
    const int row0 = blockIdx.y * BM;
    const int col0 = blockIdx.x * BN;

    float acc[TM][TN];
#pragma unroll
    for (int i = 0; i < TM; ++i)
#pragma unroll
        for (int j = 0; j < TN; ++j) acc[i][j] = 0.f;

    constexpr int AF4 = BM * BK / 1024;   // float4 loads per thread (A tile)
    constexpr int BF4 = BK * BN / 1024;   // float4 loads per thread (B tile)

    for (int k0 = 0; k0 < K; k0 += BK) {
        // ---- A tile: [BM][BK] -> As[k][m] (transposed in LDS) ----
#pragma unroll
        for (int i = 0; i < AF4; ++i) {
            int fid = tid + i * 256;
            int m   = fid >> 2;            // 4 float4 per 16-wide row
            int kk  = (fid & 3) << 2;
            int gm  = row0 + m;
            float4 v = make_float4(0.f, 0.f, 0.f, 0.f);
            if (gm < M)
                v = *reinterpret_cast<const float4*>(&A[(long)gm * lda + k0 + kk]);
            As[kk + 0][m] = v.x; As[kk + 1][m] = v.y;
            As[kk + 2][m] = v.z; As[kk + 3][m] = v.w;
        }
        // ---- B tile -> Bs[k][n] ----
        if (!TRANSB) {
#pragma unroll
            for (int i = 0; i < BF4; ++i) {
                int fid = tid + i * 256;
                int kk  = fid / (BN / 4);
                int n   = (fid % (BN / 4)) << 2;
                int gn  = col0 + n;
                float4 v = make_float4(0.f, 0.f, 0.f, 0.f);
                if (gn < N)   // N % 4 == 0 at all call sites
                    v = *reinterpret_cast<const float4*>(&Bm[(long)(k0 + kk) * ldb + gn]);
                *reinterpret_cast<float4*>(&Bs[kk][n]) = v;
            }
        } else {
#pragma unroll
            for (int i = 0; i < BF4; ++i) {
                int fid = tid + i * 256;
                int n   = fid >> 2;
                int kk  = (fid & 3) << 2;
                int gn  = col0 + n;
                float4 v = make_float4(0.f, 0.f, 0.f, 0.f);
                if (gn < N)
                    v = *reinterpret_cast<const float4*>(&Bm[(long)gn * ldb + k0 + kk]);
                Bs[kk + 0][n] = v.x; Bs[kk + 1][n] = v.y;
                Bs[kk + 2][n] = v.z; Bs[kk + 3][n] = v.w;
            }
        }
        __syncthreads();
#pragma unroll
        for (int kk = 0; kk < BK; ++kk) {
            float a[TM], b[TN];
#pragma unroll
            for (int i = 0; i < TM; i += 4) {
                float4 v = *reinterpret_cast<const float4*>(&As[kk][ty * TM + i]);
                a[i] = v.x; a[i + 1] = v.y; a[i + 2] = v.z; a[i + 3] = v.w;
            }
#pragma unroll
            for (int j = 0; j < TN; j += 4) {
                float4 v = *reinterpret_cast<const float4*>(&Bs[kk][tx * TN + j]);
                b[j] = v.x; b[j + 1] = v.y; b[j + 2] = v.z; b[j + 3] = v.w;
            }
#pragma unroll
            for (int i = 0; i < TM; ++i)
#pragma unroll
                for (int j = 0; j < TN; ++j)
                    acc[i][j] = fmaf(a[i], b[j], acc[i][j]);
        }
        __syncthreads();
    }

    // ---- epilogue ----
#pragma unroll
    for (int i = 0; i < TM; ++i) {
        int gm = row0 + ty * TM + i;
        if (gm >= M) continue;
#pragma unroll
        for (int j = 0; j < TN; ++j) {
            int gn = col0 + tx * TN + j;
            if (gn >= N) continue;
            float v = acc[i][j];
            if (bias) v += bias[gn];
            if (EPI == 1) {  // gelu, tanh approximation (jax.nn.gelu default)
                float xx = v;
                v = 0.5f * xx * (1.f + tanhf(0.7978845608028654f
                                             * (xx + 0.044715f * xx * xx * xx)));
            }
            if (EPI == 2) {  // TXL rel-shift: col j of rel row t -> col s of scores
                int s = gm + gn - (M - 1);
                if (s >= 0) C[(long)gm * ldc + s] += v;
            } else {
                float av = v;
                if (addsrc) av += addsrc[(long)gm * ldc + gn];
                C[(long)gm * ldc + gn] = av;
            }
        }
    }
}

// =====================================================================
// LayerNorm over D=1024, one block (256 thr) per row, float4 per thread
// =====================================================================
__global__ __launch_bounds__(256)
void layernorm_kernel(const float* __restrict__ x, float* __restrict__ y,
                      const float* __restrict__ sc, const float* __restrict__ bi)
{
    int row = blockIdx.x;
    const float* xr = x + (long)row * ND;
    float* yr       = y + (long)row * ND;
    int d4 = threadIdx.x * 4;
    float4 v = *reinterpret_cast<const float4*>(&xr[d4]);
    float sum = v.x + v.y + v.z + v.w;
    float sq  = v.x * v.x + v.y * v.y + v.z * v.z + v.w * v.w;
#pragma unroll
    for (int o = 32; o; o >>= 1) {
        sum += __shfl_xor(sum, o);
        sq  += __shfl_xor(sq, o);
    }
    __shared__ float red[8];
    int w = threadIdx.x >> 6;
    if ((threadIdx.x & 63) == 0) { red[w] = sum; red[4 + w] = sq; }
    __syncthreads();
    sum = red[0] + red[1] + red[2] + red[3];
    sq  = red[4] + red[5] + red[6] + red[7];
    float mean = sum * (1.f / ND);
    float var  = fmaxf(sq * (1.f / ND) - mean * mean, 0.f);
    float inv  = rsqrtf(var + 1e-5f);
    float4 s4 = *reinterpret_cast<const float4*>(&sc[d4]);
    float4 b4 = *reinterpret_cast<const float4*>(&bi[d4]);
    float4 o4;
    o4.x = (v.x - mean) * inv * s4.x + b4.x;
    o4.y = (v.y - mean) * inv * s4.y + b4.y;
    o4.z = (v.z - mean) * inv * s4.z + b4.z;
    o4.w = (v.w - mean) * inv * s4.w + b4.w;
    *reinterpret_cast<float4*>(&yr[d4]) = o4;
}

// =====================================================================
// qw = q + r_w_bias, qr = q + r_r_bias  (biases broadcast over 1024 dim)
// =====================================================================
__global__ __launch_bounds__(256)
void qbias_kernel(const float* __restrict__ q, const float* __restrict__ rwb,
                  const float* __restrict__ rrb, float* __restrict__ qw,
                  float* __restrict__ qr)
{
    long i4 = ((long)blockIdx.x * 256 + threadIdx.x) * 4;
    int d = (int)(i4 & (ND - 1));
    float4 v = *reinterpret_cast<const float4*>(&q[i4]);
    float4 w = *reinterpret_cast<const float4*>(&rwb[d]);
    float4 r = *reinterpret_cast<const float4*>(&rrb[d]);
    float4 a; a.x = v.x + w.x; a.y = v.y + w.y; a.z = v.z + w.z; a.w = v.w + w.w;
    float4 b; b.x = v.x + r.x; b.y = v.y + r.y; b.z = v.z + r.z; b.w = v.w + r.w;
    *reinterpret_cast<float4*>(&qw[i4]) = a;
    *reinterpret_cast<float4*>(&qr[i4]) = b;
}

// =====================================================================
// Causal masked softmax over scores rows (in place).
// grid = (T, B*H); blockIdx.x = t. scale = 1/sqrt(HD).
// s <= t: softmax(score*scale); s > t: 0.
// =====================================================================
__global__ __launch_bounds__(256)
void softmax_kernel(float* __restrict__ scores)
{
    int t = blockIdx.x;
    float* row = scores + ((long)blockIdx.y * NT + t) * NT;
    const float scale = 0.125f;
    int s0 = threadIdx.x, s1 = threadIdx.x + 256;
    float v0 = (s0 <= t) ? row[s0] * scale : -3.4e38f;
    float v1 = (s1 <= t) ? row[s1] * scale : -3.4e38f;
    float m = fmaxf(v0, v1);
#pragma unroll
    for (int o = 32; o; o >>= 1) m = fmaxf(m, __shfl_xor(m, o));
    __shared__ float red[8];
    int w = threadIdx.x >> 6;
    if ((threadIdx.x & 63) == 0) red[w] = m;
    __syncthreads();
    m = fmaxf(fmaxf(red[0], red[1]), fmaxf(red[2], red[3]));
    float e0 = (s0 <= t) ? expf(v0 - m) : 0.f;
    float e1 = (s1 <= t) ? expf(v1 - m) : 0.f;
    float sum = e0 + e1;
#pragma unroll
    for (int o = 32; o; o >>= 1) sum += __shfl_xor(sum, o);
    if ((threadIdx.x & 63) == 0) red[4 + w] = sum;
    __syncthreads();
    sum = red[4] + red[5] + red[6] + red[7];
    float inv = 1.f / sum;
    row[s0] = e0 * inv;
    row[s1] = e1 * inv;
}

// =====================================================================
// Sinusoid position embedding, TXL convention: row t has pos = T-1-t.
// pemb[t] = [sin(pos*invf_0..511), cos(pos*invf_0..511)]
// =====================================================================
__global__ __launch_bounds__(256)
void pemb_kernel(float* __restrict__ pemb)
{
    int t = blockIdx.x;
    float pos = (float)(NT - 1 - t);
    for (int j = threadIdx.x; j < ND / 2; j += 256) {
        float ex   = (float)j * (9.210340371976184f / 512.0f);  // ln(1e4)*2j/D
        float invf = expf(-ex);
        float ang  = pos * invf;
        pemb[(long)t * ND + j]          = sinf(ang);
        pemb[(long)t * ND + ND / 2 + j] = cosf(ang);
    }
}

// =====================================================================
// Adaptive input embedding: one block per token. Cluster 0 is a plain
// gather*32; clusters 1/2 gather into LDS then up-project (256/64 -> 1024).
// =====================================================================
__global__ __launch_bounds__(256)
void embed_kernel(const int* __restrict__ x,
                  const float* __restrict__ e0, const float* __restrict__ e1,
                  const float* __restrict__ e2, const float* __restrict__ p1,
                  const float* __restrict__ p2, float* __restrict__ h)
{
    __shared__ float e[256];
    int tok = blockIdx.x;
    int v = x[tok];
    float* outp = h + (long)tok * ND;
    if (v < 2000) {
        const float* r = e0 + (long)v * ND;
        for (int d = threadIdx.x; d < ND; d += 256)
            outp[d] = r[d] * 32.0f;
    } else if (v < 8000) {
        const float* r = e1 + (long)(v - 2000) * 256;
        e[threadIdx.x] = r[threadIdx.x];
        __syncthreads();
        for (int d = threadIdx.x; d < ND; d += 256) {
            float acc = 0.f;
#pragma unroll 4
            for (int i = 0; i < 256; ++i) acc += e[i] * p1[(long)i * ND + d];
            outp[d] = acc * 32.0f;
        }
    } else {
        const float* r = e2 + (long)(v - 8000) * 64;
        if (threadIdx.x < 64) e[threadIdx.x] = r[threadIdx.x];
        __syncthreads();
        for (int d = threadIdx.x; d < ND; d += 256) {
            float acc = 0.f;
#pragma unroll 4
            for (int i = 0; i < 64; ++i) acc += e[i] * p2[(long)i * ND + d];
            outp[d] = acc * 32.0f;
        }
    }
}

// ---------------------------------------------------------------- host
static inline void gemm_nn64(const float* A, const float* B, float* C,
                             const float* bias, const float* add,
                             int M, int N, int K, int lda, int ldb, int ldc,
                             hipStream_t s)
{
    // 128x64 tile -> grid 256 blocks for M=2048,N=1024 (exactly 1/CU)
    dim3 g((N + 63) / 64, (M + 127) / 128, 1);
    sgemm_k<128, 64, 8, 4, false, 0><<<g, 256, 0, s>>>(
        A, B, C, bias, add, M, N, K, lda, ldb, ldc, 0, 0, 0, 0, 0, 0, 0);
}

extern "C" void kernel_launch(void* const* d_in, const int* in_sizes, int n_in,
                              void* d_out, int out_size, void* d_ws, size_t ws_size,
                              hipStream_t stream)
{
    (void)in_sizes; (void)n_in; (void)out_size; (void)ws_size;
    const int*   x     = (const int*)  d_in[0];
    const float* emb0  = (const float*)d_in[1];
    const float* emb1  = (const float*)d_in[2];
    const float* emb2  = (const float*)d_in[3];
    const float* proj1 = (const float*)d_in[4];
    const float* proj2 = (const float*)d_in[5];
    const float* obias = (const float*)d_in[6];
    const float* rwb   = (const float*)d_in[7];
    const float* rrb   = (const float*)d_in[8];
    const float* ln1s  = (const float*)d_in[9];
    const float* ln1b  = (const float*)d_in[10];
    const float* Wq    = (const float*)d_in[11];
    const float* bq    = (const float*)d_in[12];
    const float* Wk    = (const float*)d_in[13];
    const float* bk    = (const float*)d_in[14];
    const float* Wv    = (const float*)d_in[15];
    const float* bv    = (const float*)d_in[16];
    const float* Wr    = (const float*)d_in[17];
    const float* Wo    = (const float*)d_in[18];
    const float* bo    = (const float*)d_in[19];
    const float* ln2s  = (const float*)d_in[20];
    const float* ln2b  = (const float*)d_in[21];
    const float* W1    = (const float*)d_in[22];
    const float* b1    = (const float*)d_in[23];
    const float* W2    = (const float*)d_in[24];
    const float* b2    = (const float*)d_in[25];
    float* out = (float*)d_out;

    // ---- workspace layout (fp32), ~57 MB ----
    float* ws   = (float*)d_ws;
    float* pemb = ws;  ws += (long)NT * ND;    // 0.5M
    float* h    = ws;  ws += (long)NBT * ND;   // 2.1M
    float* ain  = ws;  ws += (long)NBT * ND;   // 2.1M (also attention out 'o')
    float* qw   = ws;  ws += (long)NBT * ND;   // 2.1M
    float* qr   = ws;  ws += (long)NBT * ND;   // 2.1M
    float* kbuf = ws;  ws += (long)NBT * ND;   // 2.1M
    float* vbuf = ws;  ws += (long)NBT * ND;   // 2.1M
    float* rk   = ws;  ws += (long)NT * ND;    // 0.5M
    float* hp1  = ws;  ws += (long)NBT * 256;  // 0.5M
    float* hp2  = ws;  ws += (long)NBT * 64;   // 0.13M
    // Big scratch lives in d_out: scores (16.7M fp32) + ffn-mid/q-tmp (8.4M).
    // Both are dead before the final vocab projections fully rewrite d_out.
    float* sc  = out;
    float* mid = out + (long)NB * NH * NT * NT;

    pemb_kernel<<<NT, 256, 0, stream>>>(pemb);
    embed_kernel<<<NBT, 256, 0, stream>>>(x, emb0, emb1, emb2, proj1, proj2, h);

    for (int l = 0; l < NL; ++l) {
        const float* wq = Wq + (long)l * ND * ND;
        const float* wk = Wk + (long)l * ND * ND;
        const float* wv = Wv + (long)l * ND * ND;
        const float* wr = Wr + (long)l * ND * ND;
        const float* wo = Wo + (long)l * ND * ND;
        const float* w1 = W1 + (long)l * ND * NF;
        const float* w2 = W2 + (long)l * NF * ND;

        // pre-norm 1
        layernorm_kernel<<<NBT, 256, 0, stream>>>(h, ain, ln1s + l * ND, ln1b + l * ND);
        // q (-> mid as temp), k, v, r_k
        gemm_nn64(ain, wq, mid, bq + l * ND, nullptr, NBT, ND, ND, ND, ND, ND, stream);
        qbias_kernel<<<(NBT * ND) / 1024, 256, 0, stream>>>(mid, rwb, rrb, qw, qr);
        gemm_nn64(ain, wk, kbuf, bk + l * ND, nullptr, NBT, ND, ND, ND, ND, ND, stream);
        gemm_nn64(ain, wv, vbuf, bv + l * ND, nullptr, NBT, ND, ND, ND, ND, ND, stream);
        gemm_nn64(pemb, wr, rk, nullptr, nullptr, NT, ND, ND, ND, ND, ND, stream);

        // content scores: sc[bh][t][s] = qw[b,t,h,:] . k[b,s,h,:]
        sgemm_k<128, 128, 8, 8, true, 0><<<dim3(NT / 128, NT / 128, NB * NH), 256, 0, stream>>>(
            qw, kbuf, sc, nullptr, nullptr,
            NT, NT, NHD, ND, ND, NT,
            NH, (long)NT * ND, NHD, (long)NT * ND, NHD,
            (long)NH * NT * NT, (long)NT * NT);
        // rel scores with fused rel_shift accumulate into sc
        sgemm_k<128, 128, 8, 8, true, 2><<<dim3(NT / 128, NT / 128, NB * NH), 256, 0, stream>>>(
            qr, rk, sc, nullptr, nullptr,
            NT, NT, NHD, ND, ND, NT,
            NH, (long)NT * ND, NHD, 0L, NHD,
            (long)NH * NT * NT, (long)NT * NT);
        // causal softmax (scale fused)
        softmax_kernel<<<dim3(NT, NB * NH), 256, 0, stream>>>(sc);
        // o = attn @ v   (o into 'ain' buffer, [B,T,H,HD] layout)
        sgemm_k<64, 64, 4, 4, false, 0><<<dim3(1, NT / 64, NB * NH), 256, 0, stream>>>(
            sc, vbuf, ain, nullptr, nullptr,
            NT, NHD, NT, NT, ND, ND,
            NH, (long)NH * NT * NT, (long)NT * NT,
            (long)NT * ND, NHD, (long)NT * ND, NHD);
        // h += o @ Wo + bo
        gemm_nn64(ain, wo, h, bo + l * ND, h, NBT, ND, ND, ND, ND, ND, stream);

        // FFN (pre-norm, gelu)
        layernorm_kernel<<<NBT, 256, 0, stream>>>(h, ain, ln2s + l * ND, ln2b + l * ND);
        sgemm_k<128, 128, 8, 8, false, 1><<<dim3(NF / 128, NBT / 128, 1), 256, 0, stream>>>(
            ain, w1, mid, b1 + l * NF, nullptr,
            NBT, NF, ND, ND, NF, NF, 0, 0, 0, 0, 0, 0, 0);
        gemm_nn64(mid, w2, h, b2 + l * ND, h, NBT, ND, NF, NF, ND, ND, stream);
    }

    // ---- tied adaptive-softmax output: factored as (h @ proj^T) @ emb^T ----
    // cluster 0: cols [0, 2000)
    sgemm_k<128, 128, 8, 8, true, 0><<<dim3((2000 + 127) / 128, NBT / 128, 1), 256, 0, stream>>>(
        h, emb0, out, obias, nullptr,
        NBT, 2000, ND, ND, ND, NV, 0, 0, 0, 0, 0, 0, 0);
    // cluster 1: cols [2000, 8000)
    sgemm_k<128, 128, 8, 8, true, 0><<<dim3(2, NBT / 128, 1), 256, 0, stream>>>(
        h, proj1, hp1, nullptr, nullptr,
        NBT, 256, ND, ND, ND, 256, 0, 0, 0, 0, 0, 0, 0);
    sgemm_k<128, 128, 8, 8, true, 0><<<dim3((6000 + 127) / 128, NBT / 128, 1), 256, 0, stream>>>(
        hp1, emb1, out + 2000, obias + 2000, nullptr,
        NBT, 6000, 256, 256, 256, NV, 0, 0, 0, 0, 0, 0, 0);
    // cluster 2: cols [8000, 32000)
    sgemm_k<64, 64, 4, 4, true, 0><<<dim3(1, NBT / 64, 1), 256, 0, stream>>>(
        h, proj2, hp2, nullptr, nullptr,
        NBT, 64, ND, ND, ND, 64, 0, 0, 0, 0, 0, 0, 0);
    sgemm_k<128, 128, 8, 8, true, 0><<<dim3((24000 + 127) / 128, NBT / 128, 1), 256, 0, stream>>>(
        hp2, emb2, out + 8000, obias + 8000, nullptr,
        NBT, 24000, 64, 64, 64, NV, 0, 0, 0, 0, 0, 0, 0);
}

// Round 4
// 7131.475 us; speedup vs baseline: 2.6985x; 2.6985x over previous
//
#include <hip/hip_runtime.h>

using us = unsigned short;
typedef short short8v __attribute__((ext_vector_type(8)));
typedef float float4v __attribute__((ext_vector_type(4)));

// ---------------- problem constants ----------------
constexpr int NB  = 4;
constexpr int NT  = 512;
constexpr int ND  = 1024;
constexpr int NL  = 12;
constexpr int NH  = 16;
constexpr int NF  = 4096;
constexpr int NHD = 64;
constexpr int NBT = NB * NT;   // 2048
constexpr int NV  = 32000;
constexpr long QOFF = (long)NBT * ND;  // 2,097,152 (qw|qr|k|v stride in qkvbuf)

__device__ __forceinline__ us f2bf(float f) {
    unsigned u = __float_as_uint(f);
    u += 0x7fffu + ((u >> 16) & 1u);      // RNE
    return (us)(u >> 16);
}

// =====================================================================
// bf16 MFMA GEMM:  C[M,N] = A[M,K] @ B[N,K]^T   (both row-major, k-contig)
// 256 threads = 4 waves (2x2), per-wave tile (BM/2)x(BN/2), BK=64.
// LDS XOR-swizzle: 16B slot s at row r stored at slot s^(r&7) (involution).
// EPI: 0 plain (+bias,+addsrc, OUTBF), 1 gelu->bf16, 2 rel-shift += fp32,
//      3 fused QKV epilogue (bias=concat bqkv; p0=r_w_bias, p1=r_r_bias;
//        C base = qkvbuf: qw|qr|k|v at QOFF strides, all bf16)
// Grid must cover M exactly (M % BM == 0); N guarded at store.
// =====================================================================
template<int BM, int BN, int EPI, bool OUTBF>
__global__ __launch_bounds__(256)
void bgemm_k(const us* __restrict__ A, const us* __restrict__ B, void* Cv,
             const float* __restrict__ bias, const float* addsrc,
             const float* __restrict__ p0, const float* __restrict__ p1,
             int N, int K, int lda, int ldb, int ldc, int shift,
             int bdiv, long sAb, long sAh, long sBb, long sBh, long sCb, long sCh)
{
    constexpr int BK = 64;
    constexpr int WTM = BM / 2, WTN = BN / 2;
    constexpr int FM = WTM / 16, FN = WTN / 16;
    constexpr int AIT = BM * 8 / 256;   // 16B chunks per thread (A tile)
    constexpr int BIT = BN * 8 / 256;

    long coff = 0;
    if (bdiv > 0) {
        int z = blockIdx.z, zb = z / bdiv, zh = z % bdiv;
        A += zb * sAb + zh * sAh;
        B += zb * sBb + zh * sBh;
        coff = zb * sCb + zh * sCh;
    }
    float*    Cf = (float*)Cv + coff;
    us*       Ch = (us*)Cv + coff;
    if (addsrc) addsrc += coff;

    __shared__ us As[BM * BK];
    __shared__ us Bs[BN * BK];

    const int tid  = threadIdx.x;
    const int lane = tid & 63;
    const int wm   = (tid >> 6) >> 1;     // wave row (0..1)
    const int wn   = (tid >> 6) & 1;      // wave col (0..1)
    const int row0 = blockIdx.y * BM;
    const int col0 = blockIdx.x * BN;

    float4v acc[FM][FN];
#pragma unroll
    for (int i = 0; i < FM; ++i)
#pragma unroll
        for (int j = 0; j < FN; ++j) acc[i][j] = (float4v)0.f;

    uint4 ar[AIT], br[BIT];
    auto ldg = [&](int k0) {
#pragma unroll
        for (int i = 0; i < AIT; ++i) {
            int c = tid + i * 256, r = c >> 3, s = c & 7;
            ar[i] = *reinterpret_cast<const uint4*>(A + (long)(row0 + r) * lda + k0 + s * 8);
        }
#pragma unroll
        for (int i = 0; i < BIT; ++i) {
            int c = tid + i * 256, r = c >> 3, s = c & 7;
            br[i] = *reinterpret_cast<const uint4*>(B + (long)(col0 + r) * ldb + k0 + s * 8);
        }
    };

    ldg(0);
    for (int k0 = 0; k0 < K; k0 += BK) {
        __syncthreads();   // prior iteration's LDS reads complete
#pragma unroll
        for (int i = 0; i < AIT; ++i) {
            int c = tid + i * 256, r = c >> 3, s = c & 7;
            *reinterpret_cast<uint4*>((char*)As + r * 128 + ((s ^ (r & 7)) << 4)) = ar[i];
        }
#pragma unroll
        for (int i = 0; i < BIT; ++i) {
            int c = tid + i * 256, r = c >> 3, s = c & 7;
            *reinterpret_cast<uint4*>((char*)Bs + r * 128 + ((s ^ (r & 7)) << 4)) = br[i];
        }
        __syncthreads();
        if (k0 + BK < K) ldg(k0 + BK);   // prefetch hides under MFMA
#pragma unroll
        for (int ks = 0; ks < 2; ++ks) {
            short8v af[FM], bfr[FN];
            int sw = ks * 4 + (lane >> 4);
#pragma unroll
            for (int i = 0; i < FM; ++i) {
                int r = wm * WTM + i * 16 + (lane & 15);
                af[i] = *reinterpret_cast<const short8v*>((const char*)As + r * 128 + ((sw ^ (r & 7)) << 4));
            }
#pragma unroll
            for (int j = 0; j < FN; ++j) {
                int r = wn * WTN + j * 16 + (lane & 15);
                bfr[j] = *reinterpret_cast<const short8v*>((const char*)Bs + r * 128 + ((sw ^ (r & 7)) << 4));
            }
#pragma unroll
            for (int i = 0; i < FM; ++i)
#pragma unroll
                for (int j = 0; j < FN; ++j)
                    acc[i][j] = __builtin_amdgcn_mfma_f32_16x16x32_bf16(af[i], bfr[j], acc[i][j], 0, 0, 0);
        }
    }

    // ---- epilogue.  D layout: col = lane&15, row = (lane>>4)*4 + reg ----
#pragma unroll
    for (int i = 0; i < FM; ++i) {
        int growb = row0 + wm * WTM + i * 16 + ((lane >> 4) << 2);
#pragma unroll
        for (int j = 0; j < FN; ++j) {
            int gcol = col0 + wn * WTN + j * 16 + (lane & 15);
            if (EPI != 2 && EPI != 3 && gcol >= N) continue;
#pragma unroll
            for (int r = 0; r < 4; ++r) {
                int gr = growb + r;
                float v = acc[i][j][r];
                if (EPI == 3) {
                    v += bias[gcol];               // concat bq|bk|bv
                    int seg = gcol >> 10, c = gcol & 1023;
                    long o = (long)gr * 1024 + c;
                    us* base = (us*)Cv;            // qkvbuf
                    if (seg == 0) {
                        base[o]        = f2bf(v + p0[c]);   // qw = q + r_w_bias
                        base[o + QOFF] = f2bf(v + p1[c]);   // qr = q + r_r_bias
                    } else if (seg == 1) base[o + 2 * QOFF] = f2bf(v);
                    else                 base[o + 3 * QOFF] = f2bf(v);
                } else if (EPI == 2) {
                    int s = gr + gcol - shift;     // rel_shift: col j -> key s
                    if (s >= 0) Cf[(long)gr * ldc + s] += v;
                } else {
                    if (bias) v += bias[gcol];
                    if (EPI == 1) {
                        float xx = v;
                        v = 0.5f * xx * (1.f + tanhf(0.7978845608028654f
                                                     * (xx + 0.044715f * xx * xx * xx)));
                    }
                    if (addsrc) v += addsrc[(long)gr * ldc + gcol];
                    if (OUTBF) Ch[(long)gr * ldc + gcol] = f2bf(v);
                    else       Cf[(long)gr * ldc + gcol] = v;
                }
            }
        }
    }
}

// =====================================================================
// Transpose-convert: fp32 in[R][C] -> bf16 out[C][R].  R,C % 32 == 0.
// =====================================================================
__global__ __launch_bounds__(256)
void tconv_k(const float* __restrict__ in, us* __restrict__ out, int R, int C)
{
    __shared__ float t[32][33];
    int c0 = blockIdx.x * 32, r0 = blockIdx.y * 32;
    int tx = threadIdx.x & 31, ty = threadIdx.x >> 5;
#pragma unroll
    for (int j = 0; j < 4; ++j)
        t[ty + j * 8][tx] = in[(long)(r0 + ty + j * 8) * C + c0 + tx];
    __syncthreads();
#pragma unroll
    for (int j = 0; j < 4; ++j)
        out[(long)(c0 + ty + j * 8) * R + r0 + tx] = f2bf(t[tx][ty + j * 8]);
}

// Batched bf16 transpose: v[B,T,H,HD] -> vt[B,H,HD,T]
__global__ __launch_bounds__(256)
void vtrans_k(const us* __restrict__ v, us* __restrict__ vt)
{
    __shared__ us t[32][33];
    int z = blockIdx.z;                    // b*NH + h
    int b = z >> 4, h = z & 15;
    const us* in = v + ((long)b * NT) * ND + h * NHD;
    us* out = vt + (long)z * NHD * NT;
    int d0 = blockIdx.x * 32, t0 = blockIdx.y * 32;
    int tx = threadIdx.x & 31, ty = threadIdx.x >> 5;
#pragma unroll
    for (int j = 0; j < 4; ++j)
        t[ty + j * 8][tx] = in[(long)(t0 + ty + j * 8) * ND + d0 + tx];
    __syncthreads();
#pragma unroll
    for (int j = 0; j < 4; ++j)
        out[(long)(d0 + ty + j * 8) * NT + t0 + tx] = t[tx][ty + j * 8];
}

// flat fp32 -> bf16 (n % 4 == 0)
__global__ __launch_bounds__(256)
void conv_k(const float* __restrict__ in, us* __restrict__ out, long n)
{
    long i = ((long)blockIdx.x * 256 + threadIdx.x) * 4;
    if (i >= n) return;
    float4 v = *reinterpret_cast<const float4*>(in + i);
    uint2 p;
    p.x = (unsigned)f2bf(v.x) | ((unsigned)f2bf(v.y) << 16);
    p.y = (unsigned)f2bf(v.z) | ((unsigned)f2bf(v.w) << 16);
    *reinterpret_cast<uint2*>(out + i) = p;
}

// concat per-layer qkv biases: bqkv[l][3072] = [bq|bk|bv]
__global__ __launch_bounds__(256)
void bcat_k(const float* __restrict__ bq, const float* __restrict__ bk,
            const float* __restrict__ bv, float* __restrict__ o)
{
    int i = blockIdx.x * 256 + threadIdx.x;       // 12*3072
    int l = i / 3072, rr = i % 3072, seg = rr >> 10, c = rr & 1023;
    const float* s = seg == 0 ? bq : seg == 1 ? bk : bv;
    o[i] = s[l * 1024 + c];
}

// =====================================================================
// LayerNorm D=1024 fp32 -> bf16, one block/row
// =====================================================================
__global__ __launch_bounds__(256)
void ln_k(const float* __restrict__ x, us* __restrict__ y,
          const float* __restrict__ sc, const float* __restrict__ bi)
{
    int row = blockIdx.x;
    const float* xr = x + (long)row * ND;
    int d4 = threadIdx.x * 4;
    float4 v = *reinterpret_cast<const float4*>(&xr[d4]);
    float sum = v.x + v.y + v.z + v.w;
    float sq  = v.x * v.x + v.y * v.y + v.z * v.z + v.w * v.w;
#pragma unroll
    for (int o = 32; o; o >>= 1) { sum += __shfl_xor(sum, o); sq += __shfl_xor(sq, o); }
    __shared__ float red[8];
    int w = threadIdx.x >> 6;
    if ((threadIdx.x & 63) == 0) { red[w] = sum; red[4 + w] = sq; }
    __syncthreads();
    sum = red[0] + red[1] + red[2] + red[3];
    sq  = red[4] + red[5] + red[6] + red[7];
    float mean = sum * (1.f / ND);
    float var  = fmaxf(sq * (1.f / ND) - mean * mean, 0.f);
    float inv  = rsqrtf(var + 1e-5f);
    float4 s4 = *reinterpret_cast<const float4*>(&sc[d4]);
    float4 b4 = *reinterpret_cast<const float4*>(&bi[d4]);
    uint2 p;
    p.x = (unsigned)f2bf((v.x - mean) * inv * s4.x + b4.x)
        | ((unsigned)f2bf((v.y - mean) * inv * s4.y + b4.y) << 16);
    p.y = (unsigned)f2bf((v.z - mean) * inv * s4.z + b4.z)
        | ((unsigned)f2bf((v.w - mean) * inv * s4.w + b4.w) << 16);
    *reinterpret_cast<uint2*>(y + (long)row * ND + d4) = p;
}

// =====================================================================
// Causal softmax: sc fp32 [BH,T,S] -> pbuf bf16 (scale fused)
// =====================================================================
__global__ __launch_bounds__(256)
void softmax_k(const float* __restrict__ sc, us* __restrict__ pbuf)
{
    int t = blockIdx.x;
    long rbase = ((long)blockIdx.y * NT + t) * NT;
    const float* row = sc + rbase;
    const float scale = 0.125f;
    int s0 = threadIdx.x * 2, s1 = s0 + 1;
    float v0 = (s0 <= t) ? row[s0] * scale : -3.4e38f;
    float v1 = (s1 <= t) ? row[s1] * scale : -3.4e38f;
    float m = fmaxf(v0, v1);
#pragma unroll
    for (int o = 32; o; o >>= 1) m = fmaxf(m, __shfl_xor(m, o));
    __shared__ float red[8];
    int w = threadIdx.x >> 6;
    if ((threadIdx.x & 63) == 0) red[w] = m;
    __syncthreads();
    m = fmaxf(fmaxf(red[0], red[1]), fmaxf(red[2], red[3]));
    float e0 = (s0 <= t) ? expf(v0 - m) : 0.f;
    float e1 = (s1 <= t) ? expf(v1 - m) : 0.f;
    float sum = e0 + e1;
#pragma unroll
    for (int o = 32; o; o >>= 1) sum += __shfl_xor(sum, o);
    if ((threadIdx.x & 63) == 0) red[4 + w] = sum;
    __syncthreads();
    float inv = 1.f / (red[4] + red[5] + red[6] + red[7]);
    unsigned p = (unsigned)f2bf(e0 * inv) | ((unsigned)f2bf(e1 * inv) << 16);
    *reinterpret_cast<unsigned*>(pbuf + rbase + s0) = p;
}

// sinusoid pos-emb (TXL order), bf16 out
__global__ __launch_bounds__(256)
void pemb_k(us* __restrict__ p)
{
    int t = blockIdx.x;
    float pos = (float)(NT - 1 - t);
    for (int j = threadIdx.x; j < ND / 2; j += 256) {
        float invf = expf(-(float)j * (9.210340371976184f / 512.0f));
        float ang  = pos * invf;
        p[(long)t * ND + j]           = f2bf(sinf(ang));
        p[(long)t * ND + ND / 2 + j]  = f2bf(cosf(ang));
    }
}

// adaptive input embedding -> h fp32
__global__ __launch_bounds__(256)
void embed_k(const int* __restrict__ x,
             const float* __restrict__ e0, const float* __restrict__ e1,
             const float* __restrict__ e2, const float* __restrict__ p1,
             const float* __restrict__ p2, float* __restrict__ h)
{
    __shared__ float e[256];
    int tok = blockIdx.x;
    int v = x[tok];
    float* outp = h + (long)tok * ND;
    if (v < 2000) {
        const float* r = e0 + (long)v * ND;
        for (int d = threadIdx.x; d < ND; d += 256) outp[d] = r[d] * 32.0f;
    } else if (v < 8000) {
        const float* r = e1 + (long)(v - 2000) * 256;
        e[threadIdx.x] = r[threadIdx.x];
        __syncthreads();
        for (int d = threadIdx.x; d < ND; d += 256) {
            float acc = 0.f;
#pragma unroll 4
            for (int i = 0; i < 256; ++i) acc += e[i] * p1[(long)i * ND + d];
            outp[d] = acc * 32.0f;
        }
    } else {
        const float* r = e2 + (long)(v - 8000) * 64;
        if (threadIdx.x < 64) e[threadIdx.x] = r[threadIdx.x];
        __syncthreads();
        for (int d = threadIdx.x; d < ND; d += 256) {
            float acc = 0.f;
#pragma unroll 4
            for (int i = 0; i < 64; ++i) acc += e[i] * p2[(long)i * ND + d];
            outp[d] = acc * 32.0f;
        }
    }
}

// ---------------------------------------------------------------- host
extern "C" void kernel_launch(void* const* d_in, const int* in_sizes, int n_in,
                              void* d_out, int out_size, void* d_ws, size_t ws_size,
                              hipStream_t stream)
{
    (void)in_sizes; (void)n_in; (void)out_size; (void)ws_size;
    const int*   x     = (const int*)  d_in[0];
    const float* emb0  = (const float*)d_in[1];
    const float* emb1  = (const float*)d_in[2];
    const float* emb2  = (const float*)d_in[3];
    const float* proj1 = (const float*)d_in[4];
    const float* proj2 = (const float*)d_in[5];
    const float* obias = (const float*)d_in[6];
    const float* rwb   = (const float*)d_in[7];
    const float* rrb   = (const float*)d_in[8];
    const float* ln1s  = (const float*)d_in[9];
    const float* ln1b  = (const float*)d_in[10];
    const float* Wq    = (const float*)d_in[11];
    const float* Wk    = (const float*)d_in[13];
    const float* bk    = (const float*)d_in[14];
    const float* bq    = (const float*)d_in[12];
    const float* Wv    = (const float*)d_in[15];
    const float* bv    = (const float*)d_in[16];
    const float* Wr    = (const float*)d_in[17];
    const float* Wo    = (const float*)d_in[18];
    const float* bo    = (const float*)d_in[19];
    const float* ln2s  = (const float*)d_in[20];
    const float* ln2b  = (const float*)d_in[21];
    const float* W1    = (const float*)d_in[22];
    const float* b1    = (const float*)d_in[23];
    const float* W2    = (const float*)d_in[24];
    const float* b2    = (const float*)d_in[25];
    float* out = (float*)d_out;

    // ---- d_out scratch layout (float units); all dead before vocab GEMMs ----
    float* sc      = out;                          // 16,777,216 f (fp32 scores)
    us*    pbuf    = (us*)(out + 16777216);        // 16,777,216 bf16 probs
    us*    mid_bf  = (us*)(out + 25165824);        // 2048*4096 bf16
    us*    qkvbuf  = (us*)(out + 29360128);        // 4 * QOFF bf16 (qw|qr|k|v)
    us*    wqkv_t  = (us*)(out + 33554432);        // [3072][1024] bf16
    us*    wr_t    = (us*)(out + 35127296);        // [1024][1024]
    us*    wo_t    = (us*)(out + 35651584);        // [1024][1024]
    us*    w1_t    = (us*)(out + 36175872);        // [4096][1024]
    us*    w2_t    = (us*)(out + 38273024);        // [1024][4096]
    us*    vt_bf   = (us*)(out + 40370176);        // [64][64][512]
    us*    o_bf    = (us*)(out + 41418752);        // [2048][1024]
    us*    ain_bf  = (us*)(out + 42467328);        // [2048][1024]
    us*    rk_bf   = (us*)(out + 43515904);        // [512][1024]
    us*    pemb_bf = (us*)(out + 43778048);        // [512][1024]  (ends 44,040,192 < 65,536,000)

    // ---- d_ws layout (live through vocab stage), ~25 MB ----
    float* wsf      = (float*)d_ws;
    float* h        = wsf;                         // 2,097,152 f
    us*    h_bf     = (us*)(wsf + 2097152);        // 2,097,152 us
    us*    hp1_bf   = h_bf   + 2097152;            // 524,288
    us*    hp2_bf   = hp1_bf + 524288;             // 131,072
    us*    emb0_bf  = hp2_bf + 131072;             // 2048*1024 (2000 real rows)
    us*    emb1_bf  = emb0_bf + 2097152;           // 6144*256  (6000 real)
    us*    emb2_bf  = emb1_bf + 1572864;           // 24064*64  (24000 real)
    us*    proj1_bf = emb2_bf + 1540096;           // 256*1024
    us*    proj2_bf = proj1_bf + 262144;           // 64*1024
    float* bqkv     = (float*)(proj2_bf + 65536);  // 12*3072 f

    // ---- one-time setup ----
    bcat_k<<<144, 256, 0, stream>>>(bq, bk, bv, bqkv);
    conv_k<<<2000, 256, 0, stream>>>(emb0,  emb0_bf,  2048000);
    conv_k<<<1500, 256, 0, stream>>>(emb1,  emb1_bf,  1536000);
    conv_k<<<1500, 256, 0, stream>>>(emb2,  emb2_bf,  1536000);
    conv_k<<<256,  256, 0, stream>>>(proj1, proj1_bf, 262144);
    conv_k<<<64,   256, 0, stream>>>(proj2, proj2_bf, 65536);
    pemb_k<<<NT, 256, 0, stream>>>(pemb_bf);
    embed_k<<<NBT, 256, 0, stream>>>(x, emb0, emb1, emb2, proj1, proj2, h);

    for (int l = 0; l < NL; ++l) {
        const long wOff = (long)l * ND * ND;
        // weight transpose-convert (fp32 [K][N] -> bf16 [N][K])
        tconv_k<<<dim3(32, 32), 256, 0, stream>>>(Wq + wOff, wqkv_t,               ND, ND);
        tconv_k<<<dim3(32, 32), 256, 0, stream>>>(Wk + wOff, wqkv_t + 1048576,     ND, ND);
        tconv_k<<<dim3(32, 32), 256, 0, stream>>>(Wv + wOff, wqkv_t + 2097152,     ND, ND);
        tconv_k<<<dim3(32, 32), 256, 0, stream>>>(Wr + wOff, wr_t, ND, ND);
        tconv_k<<<dim3(32, 32), 256, 0, stream>>>(Wo + wOff, wo_t, ND, ND);
        tconv_k<<<dim3(128, 32), 256, 0, stream>>>(W1 + (long)l * ND * NF, w1_t, ND, NF);
        tconv_k<<<dim3(32, 128), 256, 0, stream>>>(W2 + (long)l * ND * NF, w2_t, NF, ND);

        // pre-norm 1 -> bf16
        ln_k<<<NBT, 256, 0, stream>>>(h, ain_bf, ln1s + l * ND, ln1b + l * ND);
        // fused QKV (EPI=3): qw,qr,k,v all bf16 into qkvbuf
        bgemm_k<128, 128, 3, true><<<dim3(24, 16, 1), 256, 0, stream>>>(
            ain_bf, wqkv_t, qkvbuf, bqkv + l * 3072, nullptr, rwb, rrb,
            3072, 1024, 1024, 1024, 1024, 0, 0, 0, 0, 0, 0, 0, 0);
        // r_k = pemb @ Wr  -> bf16
        bgemm_k<128, 64, 0, true><<<dim3(16, 4, 1), 256, 0, stream>>>(
            pemb_bf, wr_t, rk_bf, nullptr, nullptr, nullptr, nullptr,
            1024, 1024, 1024, 1024, 1024, 0, 0, 0, 0, 0, 0, 0, 0);
        // v -> vt [B,H,HD,T]
        vtrans_k<<<dim3(2, 16, NB * NH), 256, 0, stream>>>(qkvbuf + 3 * QOFF, vt_bf);

        // content scores (fp32): sc[b,h,t,s] = qw . k
        bgemm_k<128, 128, 0, false><<<dim3(4, 4, NB * NH), 256, 0, stream>>>(
            qkvbuf, qkvbuf + 2 * QOFF, sc, nullptr, nullptr, nullptr, nullptr,
            512, 64, 1024, 1024, 512, 0,
            NH, (long)NT * ND, NHD, (long)NT * ND, NHD,
            (long)NH * NT * NT, (long)NT * NT);
        // rel scores with fused rel_shift scatter-accumulate
        bgemm_k<128, 128, 2, false><<<dim3(4, 4, NB * NH), 256, 0, stream>>>(
            qkvbuf + QOFF, rk_bf, sc, nullptr, nullptr, nullptr, nullptr,
            512, 64, 1024, 1024, 512, NT - 1,
            NH, (long)NT * ND, NHD, 0L, NHD,
            (long)NH * NT * NT, (long)NT * NT);
        // causal softmax -> bf16 probs
        softmax_k<<<dim3(NT, NB * NH), 256, 0, stream>>>(sc, pbuf);
        // o[b,t,h,:] = P @ V   (bf16 out)
        bgemm_k<128, 64, 0, true><<<dim3(1, 4, NB * NH), 256, 0, stream>>>(
            pbuf, vt_bf, o_bf, nullptr, nullptr, nullptr, nullptr,
            64, 512, 512, 512, 1024, 0,
            NH, (long)NH * NT * NT, (long)NT * NT,
            (long)NH * NHD * NT, (long)NHD * NT,
            (long)NT * ND, (long)NHD);
        // h += o @ Wo + bo  (fp32 residual)
        bgemm_k<128, 64, 0, false><<<dim3(16, 16, 1), 256, 0, stream>>>(
            o_bf, wo_t, h, bo + l * ND, h, nullptr, nullptr,
            1024, 1024, 1024, 1024, 1024, 0, 0, 0, 0, 0, 0, 0, 0);

        // FFN
        ln_k<<<NBT, 256, 0, stream>>>(h, ain_bf, ln2s + l * ND, ln2b + l * ND);
        bgemm_k<128, 128, 1, true><<<dim3(32, 16, 1), 256, 0, stream>>>(
            ain_bf, w1_t, mid_bf, b1 + (long)l * NF, nullptr, nullptr, nullptr,
            4096, 1024, 1024, 1024, 4096, 0, 0, 0, 0, 0, 0, 0, 0);
        bgemm_k<128, 64, 0, false><<<dim3(16, 16, 1), 256, 0, stream>>>(
            mid_bf, w2_t, h, b2 + l * ND, h, nullptr, nullptr,
            1024, 4096, 4096, 4096, 1024, 0, 0, 0, 0, 0, 0, 0, 0);
    }

    // ---- tied adaptive-softmax output: (h @ proj^T) @ emb^T ----
    conv_k<<<2048, 256, 0, stream>>>(h, h_bf, (long)NBT * ND);
    // cluster 0: cols [0,2000)
    bgemm_k<128, 128, 0, false><<<dim3(16, 16, 1), 256, 0, stream>>>(
        h_bf, emb0_bf, out, obias, nullptr, nullptr, nullptr,
        2000, 1024, 1024, 1024, NV, 0, 0, 0, 0, 0, 0, 0, 0);
    // cluster 1: hp1 = h @ proj1^T ; cols [2000,8000)
    bgemm_k<128, 64, 0, true><<<dim3(4, 16, 1), 256, 0, stream>>>(
        h_bf, proj1_bf, hp1_bf, nullptr, nullptr, nullptr, nullptr,
        256, 1024, 1024, 1024, 256, 0, 0, 0, 0, 0, 0, 0, 0);
    bgemm_k<128, 128, 0, false><<<dim3(47, 16, 1), 256, 0, stream>>>(
        hp1_bf, emb1_bf, out + 2000, obias + 2000, nullptr, nullptr, nullptr,
        6000, 256, 256, 256, NV, 0, 0, 0, 0, 0, 0, 0, 0);
    // cluster 2: hp2 = h @ proj2^T ; cols [8000,32000)
    bgemm_k<128, 64, 0, true><<<dim3(1, 16, 1), 256, 0, stream>>>(
        h_bf, proj2_bf, hp2_bf, nullptr, nullptr, nullptr, nullptr,
        64, 1024, 1024, 1024, 64, 0, 0, 0, 0, 0, 0, 0, 0);
    bgemm_k<128, 128, 0, false><<<dim3(188, 16, 1), 256, 0, stream>>>(
        hp2_bf, emb2_bf, out + 8000, obias + 8000, nullptr, nullptr, nullptr,
        24000, 64, 64, 64, NV, 0, 0, 0, 0, 0, 0, 0, 0);
}

// Round 5
// 3697.968 us; speedup vs baseline: 5.2040x; 1.9285x over previous
//
#include <hip/hip_runtime.h>

using us = unsigned short;
typedef short short8v __attribute__((ext_vector_type(8)));
typedef float float4v __attribute__((ext_vector_type(4)));

// ---------------- problem constants ----------------
constexpr int NB  = 4;
constexpr int NT  = 512;
constexpr int ND  = 1024;
constexpr int NL  = 12;
constexpr int NH  = 16;
constexpr int NF  = 4096;
constexpr int NHD = 64;
constexpr int NBT = NB * NT;   // 2048
constexpr int NV  = 32000;
constexpr long QOFF = (long)NBT * ND;  // qw|qr|k|v stride in qkvbuf

__device__ __forceinline__ us f2bf(float f) {
    unsigned u = __float_as_uint(f);
    u += 0x7fffu + ((u >> 16) & 1u);      // RNE
    return (us)(u >> 16);
}
__device__ __forceinline__ float b2f(us u) {
    return __uint_as_float((unsigned)u << 16);
}

// async global->LDS, 16B per lane. LDS dest is wave-uniform base + lane*16;
// global src is per-lane (pre-swizzled for bank-conflict-free ds_read).
__device__ __forceinline__ void gload16(const us* g, us* l) {
    __builtin_amdgcn_global_load_lds(
        (const __attribute__((address_space(1))) void*)g,
        (__attribute__((address_space(3))) void*)l, 16, 0, 0);
}

// =====================================================================
// bf16 MFMA GEMM:  C[M,N] = A[M,K] @ B[N,K]^T   (both row-major, k-contig)
// 256 threads = 4 waves (2x2), per-wave tile (BM/2)x(BN/2), BK=64.
// Staging: global_load_lds dwordx4, linear LDS rows of 128B, source slot
// pre-swizzled by s^(r&7); ds_read applies the same XOR (involution).
// EPI: 0 plain (+bias,+addsrc), 1 gelu->..., 3 fused QKV epilogue.
// Grid covers M exactly; N guarded at store (B buffers padded to tile).
// =====================================================================
template<int BM, int BN, int EPI, bool OUTBF>
__global__ __launch_bounds__(256)
void bgemm_k(const us* __restrict__ A, const us* __restrict__ B, void* Cv,
             const float* __restrict__ bias, const float* addsrc,
             const float* __restrict__ p0, const float* __restrict__ p1,
             int N, int K, int lda, int ldb, int ldc,
             int bdiv, long sAb, long sAh, long sBb, long sBh, long sCb, long sCh)
{
    constexpr int BK  = 64;
    constexpr int WTM = BM / 2, WTN = BN / 2;
    constexpr int FM  = WTM / 16, FN = WTN / 16;
    constexpr int AI  = BM / 32;       // gload16 instr per wave (A tile)
    constexpr int BI  = BN / 32;
    static_assert(BM % 32 == 0 && BN % 32 == 0, "");

    long coff = 0;
    if (bdiv > 0) {
        int z = blockIdx.z, zb = z / bdiv, zh = z % bdiv;
        A += zb * sAb + zh * sAh;
        B += zb * sBb + zh * sBh;
        coff = zb * sCb + zh * sCh;
    }
    float* Cf = (float*)Cv + coff;
    us*    Ch = (us*)Cv + coff;
    if (addsrc) addsrc += coff;

    __shared__ us As[BM * BK];
    __shared__ us Bs[BN * BK];

    const int tid  = threadIdx.x;
    const int lane = tid & 63;
    const int w    = tid >> 6;            // wave id 0..3
    const int wm   = w >> 1;              // wave row (0..1)
    const int wn   = w & 1;               // wave col (0..1)
    const int row0 = blockIdx.y * BM;
    const int col0 = blockIdx.x * BN;

    float4v acc[FM][FN];
#pragma unroll
    for (int i = 0; i < FM; ++i)
#pragma unroll
        for (int j = 0; j < FN; ++j) acc[i][j] = (float4v)0.f;

    for (int k0 = 0; k0 < K; k0 += BK) {
        // ---- stage via global_load_lds (per-wave chunks, 1KB/instr) ----
#pragma unroll
        for (int i = 0; i < AI; ++i) {
            int rb = w * (BM / 4) + i * 8;
            int r  = rb + (lane >> 3);
            int sc8 = ((lane & 7) ^ (r & 7)) << 3;
            gload16(A + (long)(row0 + r) * lda + k0 + sc8, As + rb * 64);
        }
#pragma unroll
        for (int i = 0; i < BI; ++i) {
            int rb = w * (BN / 4) + i * 8;
            int r  = rb + (lane >> 3);
            int sc8 = ((lane & 7) ^ (r & 7)) << 3;
            gload16(B + (long)(col0 + r) * ldb + k0 + sc8, Bs + rb * 64);
        }
        __syncthreads();   // drains vmcnt -> LDS tiles ready
#pragma unroll
        for (int ks = 0; ks < 2; ++ks) {
            short8v af[FM], bfr[FN];
            int sw = ks * 4 + (lane >> 4);
#pragma unroll
            for (int i = 0; i < FM; ++i) {
                int r = wm * WTM + i * 16 + (lane & 15);
                af[i] = *reinterpret_cast<const short8v*>((const char*)As + r * 128 + ((sw ^ (r & 7)) << 4));
            }
#pragma unroll
            for (int j = 0; j < FN; ++j) {
                int r = wn * WTN + j * 16 + (lane & 15);
                bfr[j] = *reinterpret_cast<const short8v*>((const char*)Bs + r * 128 + ((sw ^ (r & 7)) << 4));
            }
#pragma unroll
            for (int i = 0; i < FM; ++i)
#pragma unroll
                for (int j = 0; j < FN; ++j)
                    acc[i][j] = __builtin_amdgcn_mfma_f32_16x16x32_bf16(af[i], bfr[j], acc[i][j], 0, 0, 0);
        }
        __syncthreads();   // all waves done reading before next overwrite
    }

    // ---- epilogue.  D layout: col = lane&15, row = (lane>>4)*4 + reg ----
#pragma unroll
    for (int i = 0; i < FM; ++i) {
        int growb = row0 + wm * WTM + i * 16 + ((lane >> 4) << 2);
#pragma unroll
        for (int j = 0; j < FN; ++j) {
            int gcol = col0 + wn * WTN + j * 16 + (lane & 15);
            if (EPI != 3 && gcol >= N) continue;
#pragma unroll
            for (int r = 0; r < 4; ++r) {
                int gr = growb + r;
                float v = acc[i][j][r];
                if (EPI == 3) {
                    v += bias[gcol];               // concat bq|bk|bv
                    int seg = gcol >> 10, c = gcol & 1023;
                    long o = (long)gr * 1024 + c;
                    us* base = (us*)Cv;            // qkvbuf
                    if (seg == 0) {
                        base[o]        = f2bf(v + p0[c]);   // qw
                        base[o + QOFF] = f2bf(v + p1[c]);   // qr
                    } else if (seg == 1) base[o + 2 * QOFF] = f2bf(v);
                    else                 base[o + 3 * QOFF] = f2bf(v);
                } else {
                    if (bias) v += bias[gcol];
                    if (EPI == 1) {
                        float xx = v;
                        v = 0.5f * xx * (1.f + tanhf(0.7978845608028654f
                                                     * (xx + 0.044715f * xx * xx * xx)));
                    }
                    if (addsrc) v += addsrc[(long)gr * ldc + gcol];
                    if (OUTBF) Ch[(long)gr * ldc + gcol] = f2bf(v);
                    else       Cf[(long)gr * ldc + gcol] = v;
                }
            }
        }
    }
}

// =====================================================================
// Transpose-convert: fp32 in[R][C] -> bf16 out[C][R], optional layer batch
// =====================================================================
__global__ __launch_bounds__(256)
void tconv_k(const float* __restrict__ in, us* __restrict__ out, int R, int C,
             long inL, long outL)
{
    in  += (long)blockIdx.z * inL;
    out += (long)blockIdx.z * outL;
    __shared__ float t[32][33];
    int c0 = blockIdx.x * 32, r0 = blockIdx.y * 32;
    int tx = threadIdx.x & 31, ty = threadIdx.x >> 5;
#pragma unroll
    for (int j = 0; j < 4; ++j)
        t[ty + j * 8][tx] = in[(long)(r0 + ty + j * 8) * C + c0 + tx];
    __syncthreads();
#pragma unroll
    for (int j = 0; j < 4; ++j)
        out[(long)(c0 + ty + j * 8) * R + r0 + tx] = f2bf(t[tx][ty + j * 8]);
}

// Batched bf16 transpose: v[B,T,H,HD] -> vt[B,H,HD,T]
__global__ __launch_bounds__(256)
void vtrans_k(const us* __restrict__ v, us* __restrict__ vt)
{
    __shared__ us t[32][33];
    int z = blockIdx.z;                    // b*NH + h
    int b = z >> 4, h = z & 15;
    const us* in = v + ((long)b * NT) * ND + h * NHD;
    us* out = vt + (long)z * NHD * NT;
    int d0 = blockIdx.x * 32, t0 = blockIdx.y * 32;
    int tx = threadIdx.x & 31, ty = threadIdx.x >> 5;
#pragma unroll
    for (int j = 0; j < 4; ++j)
        t[ty + j * 8][tx] = in[(long)(t0 + ty + j * 8) * ND + d0 + tx];
    __syncthreads();
#pragma unroll
    for (int j = 0; j < 4; ++j)
        out[(long)(d0 + ty + j * 8) * NT + t0 + tx] = t[tx][ty + j * 8];
}

// flat fp32 -> bf16 (n % 4 == 0)
__global__ __launch_bounds__(256)
void conv_k(const float* __restrict__ in, us* __restrict__ out, long n)
{
    long i = ((long)blockIdx.x * 256 + threadIdx.x) * 4;
    if (i >= n) return;
    float4 v = *reinterpret_cast<const float4*>(in + i);
    uint2 p;
    p.x = (unsigned)f2bf(v.x) | ((unsigned)f2bf(v.y) << 16);
    p.y = (unsigned)f2bf(v.z) | ((unsigned)f2bf(v.w) << 16);
    *reinterpret_cast<uint2*>(out + i) = p;
}

// concat per-layer qkv biases: bqkv[l][3072] = [bq|bk|bv]
__global__ __launch_bounds__(256)
void bcat_k(const float* __restrict__ bq, const float* __restrict__ bk,
            const float* __restrict__ bv, float* __restrict__ o)
{
    int i = blockIdx.x * 256 + threadIdx.x;       // 12*3072
    int l = i / 3072, rr = i % 3072, seg = rr >> 10, c = rr & 1023;
    const float* s = seg == 0 ? bq : seg == 1 ? bk : bv;
    o[i] = s[l * 1024 + c];
}

// =====================================================================
// LayerNorm D=1024 fp32 -> bf16, one block/row
// =====================================================================
__global__ __launch_bounds__(256)
void ln_k(const float* __restrict__ x, us* __restrict__ y,
          const float* __restrict__ sc, const float* __restrict__ bi)
{
    int row = blockIdx.x;
    const float* xr = x + (long)row * ND;
    int d4 = threadIdx.x * 4;
    float4 v = *reinterpret_cast<const float4*>(&xr[d4]);
    float sum = v.x + v.y + v.z + v.w;
    float sq  = v.x * v.x + v.y * v.y + v.z * v.z + v.w * v.w;
#pragma unroll
    for (int o = 32; o; o >>= 1) { sum += __shfl_xor(sum, o); sq += __shfl_xor(sq, o); }
    __shared__ float red[8];
    int w = threadIdx.x >> 6;
    if ((threadIdx.x & 63) == 0) { red[w] = sum; red[4 + w] = sq; }
    __syncthreads();
    sum = red[0] + red[1] + red[2] + red[3];
    sq  = red[4] + red[5] + red[6] + red[7];
    float mean = sum * (1.f / ND);
    float var  = fmaxf(sq * (1.f / ND) - mean * mean, 0.f);
    float inv  = rsqrtf(var + 1e-5f);
    float4 s4 = *reinterpret_cast<const float4*>(&sc[d4]);
    float4 b4 = *reinterpret_cast<const float4*>(&bi[d4]);
    uint2 p;
    p.x = (unsigned)f2bf((v.x - mean) * inv * s4.x + b4.x)
        | ((unsigned)f2bf((v.y - mean) * inv * s4.y + b4.y) << 16);
    p.y = (unsigned)f2bf((v.z - mean) * inv * s4.z + b4.z)
        | ((unsigned)f2bf((v.w - mean) * inv * s4.w + b4.w) << 16);
    *reinterpret_cast<uint2*>(y + (long)row * ND + d4) = p;
}

// =====================================================================
// Causal softmax with fused rel_shift:
//   logits(t,s) = (content[t][s] + rel[t][s+NT-1-t]) * 0.125, s <= t
// content/rel bf16 in, P bf16 out.
// =====================================================================
__global__ __launch_bounds__(256)
void softmax_k(const us* __restrict__ cB, const us* __restrict__ rB,
               us* __restrict__ pbuf)
{
    int t = blockIdx.x;
    long base = ((long)blockIdx.y * NT + t) * NT;
    int s0 = threadIdx.x * 2, s1 = s0 + 1;
    float v0 = -3.4e38f, v1 = -3.4e38f;
    if (s0 <= t) v0 = (b2f(cB[base + s0]) + b2f(rB[base + s0 + NT - 1 - t])) * 0.125f;
    if (s1 <= t) v1 = (b2f(cB[base + s1]) + b2f(rB[base + s1 + NT - 1 - t])) * 0.125f;
    float m = fmaxf(v0, v1);
#pragma unroll
    for (int o = 32; o; o >>= 1) m = fmaxf(m, __shfl_xor(m, o));
    __shared__ float red[8];
    int w = threadIdx.x >> 6;
    if ((threadIdx.x & 63) == 0) red[w] = m;
    __syncthreads();
    m = fmaxf(fmaxf(red[0], red[1]), fmaxf(red[2], red[3]));
    float e0 = (s0 <= t) ? expf(v0 - m) : 0.f;
    float e1 = (s1 <= t) ? expf(v1 - m) : 0.f;
    float sum = e0 + e1;
#pragma unroll
    for (int o = 32; o; o >>= 1) sum += __shfl_xor(sum, o);
    if ((threadIdx.x & 63) == 0) red[4 + w] = sum;
    __syncthreads();
    float inv = 1.f / (red[4] + red[5] + red[6] + red[7]);
    unsigned p = (unsigned)f2bf(e0 * inv) | ((unsigned)f2bf(e1 * inv) << 16);
    *reinterpret_cast<unsigned*>(pbuf + base + s0) = p;
}

// sinusoid pos-emb (TXL order), bf16 out
__global__ __launch_bounds__(256)
void pemb_k(us* __restrict__ p)
{
    int t = blockIdx.x;
    float pos = (float)(NT - 1 - t);
    for (int j = threadIdx.x; j < ND / 2; j += 256) {
        float invf = expf(-(float)j * (9.210340371976184f / 512.0f));
        float ang  = pos * invf;
        p[(long)t * ND + j]           = f2bf(sinf(ang));
        p[(long)t * ND + ND / 2 + j]  = f2bf(cosf(ang));
    }
}

// adaptive input embedding -> h fp32
__global__ __launch_bounds__(256)
void embed_k(const int* __restrict__ x,
             const float* __restrict__ e0, const float* __restrict__ e1,
             const float* __restrict__ e2, const float* __restrict__ p1,
             const float* __restrict__ p2, float* __restrict__ h)
{
    __shared__ float e[256];
    int tok = blockIdx.x;
    int v = x[tok];
    float* outp = h + (long)tok * ND;
    if (v < 2000) {
        const float* r = e0 + (long)v * ND;
        for (int d = threadIdx.x; d < ND; d += 256) outp[d] = r[d] * 32.0f;
    } else if (v < 8000) {
        const float* r = e1 + (long)(v - 2000) * 256;
        e[threadIdx.x] = r[threadIdx.x];
        __syncthreads();
        for (int d = threadIdx.x; d < ND; d += 256) {
            float acc = 0.f;
#pragma unroll 4
            for (int i = 0; i < 256; ++i) acc += e[i] * p1[(long)i * ND + d];
            outp[d] = acc * 32.0f;
        }
    } else {
        const float* r = e2 + (long)(v - 8000) * 64;
        if (threadIdx.x < 64) e[threadIdx.x] = r[threadIdx.x];
        __syncthreads();
        for (int d = threadIdx.x; d < ND; d += 256) {
            float acc = 0.f;
#pragma unroll 4
            for (int i = 0; i < 64; ++i) acc += e[i] * p2[(long)i * ND + d];
            outp[d] = acc * 32.0f;
        }
    }
}

// ---------------------------------------------------------------- host
extern "C" void kernel_launch(void* const* d_in, const int* in_sizes, int n_in,
                              void* d_out, int out_size, void* d_ws, size_t ws_size,
                              hipStream_t stream)
{
    (void)in_sizes; (void)n_in; (void)out_size;
    const int*   x     = (const int*)  d_in[0];
    const float* emb0  = (const float*)d_in[1];
    const float* emb1  = (const float*)d_in[2];
    const float* emb2  = (const float*)d_in[3];
    const float* proj1 = (const float*)d_in[4];
    const float* proj2 = (const float*)d_in[5];
    const float* obias = (const float*)d_in[6];
    const float* rwb   = (const float*)d_in[7];
    const float* rrb   = (const float*)d_in[8];
    const float* ln1s  = (const float*)d_in[9];
    const float* ln1b  = (const float*)d_in[10];
    const float* Wq    = (const float*)d_in[11];
    const float* bq    = (const float*)d_in[12];
    const float* Wk    = (const float*)d_in[13];
    const float* bk    = (const float*)d_in[14];
    const float* Wv    = (const float*)d_in[15];
    const float* bv    = (const float*)d_in[16];
    const float* Wr    = (const float*)d_in[17];
    const float* Wo    = (const float*)d_in[18];
    const float* bo    = (const float*)d_in[19];
    const float* ln2s  = (const float*)d_in[20];
    const float* ln2b  = (const float*)d_in[21];
    const float* W1    = (const float*)d_in[22];
    const float* b1    = (const float*)d_in[23];
    const float* W2    = (const float*)d_in[24];
    const float* b2    = (const float*)d_in[25];
    float* out = (float*)d_out;

    // ---- d_out scratch (float-unit offsets); all dead before vocab GEMMs ----
    us* scB     = (us*)(out);                 // [64][512][512] bf16 content
    us* relB    = (us*)(out + 8388608);       // [64][512][512] bf16 rel (unshifted)
    us* pbuf    = (us*)(out + 16777216);      // [64][512][512] bf16 probs
    us* qkvbuf  = (us*)(out + 25165824);      // 4*QOFF bf16 (qw|qr|k|v)
    us* mid_bf  = (us*)(out + 29360128);      // [2048][4096]
    us* vt_bf   = (us*)(out + 33554432);      // [64][64][512]
    us* o_bf    = (us*)(out + 34078720);      // [2048][1024]
    us* ain_bf  = (us*)(out + 35127296);      // [2048][1024]
    us* rk_bf   = (us*)(out + 36175872);      // [512][1024]
    us* pemb_bf = (us*)(out + 36438016);      // [512][1024]
    // fallback per-layer weight scratch (only used if ws too small)
    us* wqkv_sc = (us*)(out + 36700160);      // [3072][1024]
    us* wr_sc   = (us*)(out + 38273024);      // [1024][1024]
    us* wo_sc   = (us*)(out + 38797312);      // [1024][1024]
    us* w1_sc   = (us*)(out + 39321600);      // [4096][1024]
    us* w2_sc   = (us*)(out + 41418752);      // [1024][4096]  (ends 43,515,904 f)

    // ---- d_ws layout ----
    float* wsf      = (float*)d_ws;
    float* h        = wsf;                         // 2,097,152 f
    us*    h_bf     = (us*)(wsf + 2097152);
    us*    hp1_bf   = h_bf   + 2097152;            // 524,288
    us*    hp2_bf   = hp1_bf + 524288;             // 131,072
    us*    emb0_bf  = hp2_bf + 131072;             // 2048x1024 (2000 real)
    us*    emb1_bf  = emb0_bf + 2097152;           // 6144x256  (6000 real)
    us*    emb2_bf  = emb1_bf + 1572864;           // 24064x64  (24000 real)
    us*    proj1_bf = emb2_bf + 1540096;           // 256x1024
    us*    proj2_bf = proj1_bf + 262144;           // 64x1024
    float* bqkv     = (float*)(proj2_bf + 65536);  // 12*3072 f
    us*    wq_all   = (us*)(bqkv + 36864);         // all-layer weights (bf16, transposed)
    us*    wqkv_all = wq_all;                      // [12][3072][1024]
    us*    wr_all   = wqkv_all + (long)NL * 3072 * 1024;   // [12][1024][1024]
    us*    wo_all   = wr_all   + (long)NL * 1024 * 1024;
    us*    w1_all   = wo_all   + (long)NL * 1024 * 1024;   // [12][4096][1024]
    us*    w2_all   = w1_all   + (long)NL * 4096 * 1024;   // [12][1024][4096]
    const bool big  = ws_size >= (size_t)352273408;        // full weight cache fits

    // ---- one-time setup ----
    bcat_k<<<144, 256, 0, stream>>>(bq, bk, bv, bqkv);
    conv_k<<<2000, 256, 0, stream>>>(emb0,  emb0_bf,  2048000);
    conv_k<<<1500, 256, 0, stream>>>(emb1,  emb1_bf,  1536000);
    conv_k<<<1500, 256, 0, stream>>>(emb2,  emb2_bf,  1536000);
    conv_k<<<256,  256, 0, stream>>>(proj1, proj1_bf, 262144);
    conv_k<<<64,   256, 0, stream>>>(proj2, proj2_bf, 65536);
    pemb_k<<<NT, 256, 0, stream>>>(pemb_bf);
    embed_k<<<NBT, 256, 0, stream>>>(x, emb0, emb1, emb2, proj1, proj2, h);
    if (big) {   // batched all-layer weight transpose-convert (7 launches)
        tconv_k<<<dim3(32, 32, NL), 256, 0, stream>>>(Wq, wqkv_all,           1024, 1024, 1048576, 3145728);
        tconv_k<<<dim3(32, 32, NL), 256, 0, stream>>>(Wk, wqkv_all + 1048576, 1024, 1024, 1048576, 3145728);
        tconv_k<<<dim3(32, 32, NL), 256, 0, stream>>>(Wv, wqkv_all + 2097152, 1024, 1024, 1048576, 3145728);
        tconv_k<<<dim3(32, 32, NL), 256, 0, stream>>>(Wr, wr_all, 1024, 1024, 1048576, 1048576);
        tconv_k<<<dim3(32, 32, NL), 256, 0, stream>>>(Wo, wo_all, 1024, 1024, 1048576, 1048576);
        tconv_k<<<dim3(128, 32, NL), 256, 0, stream>>>(W1, w1_all, 1024, 4096, 4194304, 4194304);
        tconv_k<<<dim3(32, 128, NL), 256, 0, stream>>>(W2, w2_all, 4096, 1024, 4194304, 4194304);
    }

    for (int l = 0; l < NL; ++l) {
        const us* wqkv_t = big ? wqkv_all + (long)l * 3145728 : wqkv_sc;
        const us* wr_t   = big ? wr_all   + (long)l * 1048576 : wr_sc;
        const us* wo_t   = big ? wo_all   + (long)l * 1048576 : wo_sc;
        const us* w1_t   = big ? w1_all   + (long)l * 4194304 : w1_sc;
        const us* w2_t   = big ? w2_all   + (long)l * 4194304 : w2_sc;
        if (!big) {
            const long wOff = (long)l * ND * ND;
            tconv_k<<<dim3(32, 32), 256, 0, stream>>>(Wq + wOff, wqkv_sc,           1024, 1024, 0, 0);
            tconv_k<<<dim3(32, 32), 256, 0, stream>>>(Wk + wOff, wqkv_sc + 1048576, 1024, 1024, 0, 0);
            tconv_k<<<dim3(32, 32), 256, 0, stream>>>(Wv + wOff, wqkv_sc + 2097152, 1024, 1024, 0, 0);
            tconv_k<<<dim3(32, 32), 256, 0, stream>>>(Wr + wOff, wr_sc, 1024, 1024, 0, 0);
            tconv_k<<<dim3(32, 32), 256, 0, stream>>>(Wo + wOff, wo_sc, 1024, 1024, 0, 0);
            tconv_k<<<dim3(128, 32), 256, 0, stream>>>(W1 + (long)l * ND * NF, w1_sc, 1024, 4096, 0, 0);
            tconv_k<<<dim3(32, 128), 256, 0, stream>>>(W2 + (long)l * ND * NF, w2_sc, 4096, 1024, 0, 0);
        }

        // pre-norm 1 -> bf16
        ln_k<<<NBT, 256, 0, stream>>>(h, ain_bf, ln1s + l * ND, ln1b + l * ND);
        // fused QKV (EPI=3): qw,qr,k,v bf16 into qkvbuf.  128x64 tiles, 768 blk
        bgemm_k<128, 64, 3, true><<<dim3(48, 16, 1), 256, 0, stream>>>(
            ain_bf, wqkv_t, qkvbuf, bqkv + l * 3072, nullptr, rwb, rrb,
            3072, 1024, 1024, 1024, 1024, 0, 0, 0, 0, 0, 0, 0);
        // r_k = pemb @ Wr -> bf16
        bgemm_k<64, 64, 0, true><<<dim3(16, 8, 1), 256, 0, stream>>>(
            pemb_bf, wr_t, rk_bf, nullptr, nullptr, nullptr, nullptr,
            1024, 1024, 1024, 1024, 1024, 0, 0, 0, 0, 0, 0, 0);
        // v -> vt [B,H,HD,T]
        vtrans_k<<<dim3(2, 16, NB * NH), 256, 0, stream>>>(qkvbuf + 3 * QOFF, vt_bf);

        // content scores -> bf16 (plain)
        bgemm_k<128, 128, 0, true><<<dim3(4, 4, NB * NH), 256, 0, stream>>>(
            qkvbuf, qkvbuf + 2 * QOFF, scB, nullptr, nullptr, nullptr, nullptr,
            512, 64, 1024, 1024, 512,
            NH, (long)NT * ND, NHD, (long)NT * ND, NHD,
            (long)NH * NT * NT, (long)NT * NT);
        // rel scores -> bf16 (plain, unshifted; shift applied in softmax)
        bgemm_k<128, 128, 0, true><<<dim3(4, 4, NB * NH), 256, 0, stream>>>(
            qkvbuf + QOFF, rk_bf, relB, nullptr, nullptr, nullptr, nullptr,
            512, 64, 1024, 1024, 512,
            NH, (long)NT * ND, NHD, 0L, NHD,
            (long)NH * NT * NT, (long)NT * NT);
        // causal softmax + rel_shift + scale -> bf16 probs
        softmax_k<<<dim3(NT, NB * NH), 256, 0, stream>>>(scB, relB, pbuf);
        // o[b,t,h,:] = P @ V
        bgemm_k<64, 64, 0, true><<<dim3(1, 8, NB * NH), 256, 0, stream>>>(
            pbuf, vt_bf, o_bf, nullptr, nullptr, nullptr, nullptr,
            64, 512, 512, 512, 1024,
            NH, (long)NH * NT * NT, (long)NT * NT,
            (long)NH * NHD * NT, (long)NHD * NT,
            (long)NT * ND, (long)NHD);
        // h += o @ Wo + bo (fp32 residual)
        bgemm_k<64, 64, 0, false><<<dim3(16, 32, 1), 256, 0, stream>>>(
            o_bf, wo_t, h, bo + l * ND, h, nullptr, nullptr,
            1024, 1024, 1024, 1024, 1024, 0, 0, 0, 0, 0, 0, 0);

        // FFN
        ln_k<<<NBT, 256, 0, stream>>>(h, ain_bf, ln2s + l * ND, ln2b + l * ND);
        bgemm_k<128, 128, 1, true><<<dim3(32, 16, 1), 256, 0, stream>>>(
            ain_bf, w1_t, mid_bf, b1 + (long)l * NF, nullptr, nullptr, nullptr,
            4096, 1024, 1024, 1024, 4096, 0, 0, 0, 0, 0, 0, 0);
        bgemm_k<64, 64, 0, false><<<dim3(16, 32, 1), 256, 0, stream>>>(
            mid_bf, w2_t, h, b2 + l * ND, h, nullptr, nullptr,
            1024, 4096, 4096, 4096, 1024, 0, 0, 0, 0, 0, 0, 0);
    }

    // ---- tied adaptive-softmax output: (h @ proj^T) @ emb^T ----
    conv_k<<<2048, 256, 0, stream>>>(h, h_bf, (long)NBT * ND);
    // cluster 0: cols [0,2000)
    bgemm_k<128, 64, 0, false><<<dim3(32, 16, 1), 256, 0, stream>>>(
        h_bf, emb0_bf, out, obias, nullptr, nullptr, nullptr,
        2000, 1024, 1024, 1024, NV, 0, 0, 0, 0, 0, 0, 0);
    // cluster 1: hp1 = h @ proj1^T ; cols [2000,8000)
    bgemm_k<64, 64, 0, true><<<dim3(4, 32, 1), 256, 0, stream>>>(
        h_bf, proj1_bf, hp1_bf, nullptr, nullptr, nullptr, nullptr,
        256, 1024, 1024, 1024, 256, 0, 0, 0, 0, 0, 0, 0);
    bgemm_k<128, 128, 0, false><<<dim3(47, 16, 1), 256, 0, stream>>>(
        hp1_bf, emb1_bf, out + 2000, obias + 2000, nullptr, nullptr, nullptr,
        6000, 256, 256, 256, NV, 0, 0, 0, 0, 0, 0, 0);
    // cluster 2: hp2 = h @ proj2^T ; cols [8000,32000)
    bgemm_k<64, 64, 0, true><<<dim3(1, 32, 1), 256, 0, stream>>>(
        h_bf, proj2_bf, hp2_bf, nullptr, nullptr, nullptr, nullptr,
        64, 1024, 1024, 1024, 64, 0, 0, 0, 0, 0, 0, 0);
    bgemm_k<128, 128, 0, false><<<dim3(188, 16, 1), 256, 0, stream>>>(
        hp2_bf, emb2_bf, out + 8000, obias + 8000, nullptr, nullptr, nullptr,
        24000, 64, 64, 64, NV, 0, 0, 0, 0, 0, 0, 0);
}

// Round 7
// 3101.125 us; speedup vs baseline: 6.2055x; 1.1925x over previous
//
#include <hip/hip_runtime.h>

using us = unsigned short;
typedef short short8v __attribute__((ext_vector_type(8)));
typedef float float4v __attribute__((ext_vector_type(4)));

// ---------------- problem constants ----------------
constexpr int NB  = 4;
constexpr int NT  = 512;
constexpr int ND  = 1024;
constexpr int NL  = 12;
constexpr int NH  = 16;
constexpr int NF  = 4096;
constexpr int NHD = 64;
constexpr int NBT = NB * NT;   // 2048
constexpr int NV  = 32000;
constexpr long QOFF = (long)NBT * ND;  // qw|qr|k|v stride in qkvbuf

__device__ __forceinline__ us f2bf(float f) {
    unsigned u = __float_as_uint(f);
    u += 0x7fffu + ((u >> 16) & 1u);      // RNE
    return (us)(u >> 16);
}

// async global->LDS, 16B per lane. LDS dest is wave-uniform base + lane*16;
// global src is per-lane (pre-swizzled for bank-conflict-free ds_read).
__device__ __forceinline__ void gload16(const us* g, us* l) {
    __builtin_amdgcn_global_load_lds(
        (const __attribute__((address_space(1))) void*)g,
        (__attribute__((address_space(3))) void*)l, 16, 0, 0);
}

// =====================================================================
// bf16 MFMA GEMM:  C[M,N] = A[M,K] @ B[N,K]^T   (both row-major, k-contig)
// 256 threads = 4 waves (2x2), per-wave tile (BM/2)x(BN/2), BK=64.
// Staging: global_load_lds dwordx4, linear LDS rows of 128B, source slot
// pre-swizzled by s^(r&7); ds_read applies the same XOR (involution).
// EPI: 0 plain (+bias,+addsrc), 1 gelu->..., 3 fused QKV epilogue.
// =====================================================================
template<int BM, int BN, int EPI, bool OUTBF>
__global__ __launch_bounds__(256)
void bgemm_k(const us* __restrict__ A, const us* __restrict__ B, void* Cv,
             const float* __restrict__ bias, const float* addsrc,
             const float* __restrict__ p0, const float* __restrict__ p1,
             int N, int K, int lda, int ldb, int ldc,
             int bdiv, long sAb, long sAh, long sBb, long sBh, long sCb, long sCh)
{
    constexpr int BK  = 64;
    constexpr int WTM = BM / 2, WTN = BN / 2;
    constexpr int FM  = WTM / 16, FN = WTN / 16;
    constexpr int AI  = BM / 32;       // gload16 instr per wave (A tile)
    constexpr int BI  = BN / 32;
    static_assert(BM % 32 == 0 && BN % 32 == 0, "");

    long coff = 0;
    if (bdiv > 0) {
        int z = blockIdx.z, zb = z / bdiv, zh = z % bdiv;
        A += zb * sAb + zh * sAh;
        B += zb * sBb + zh * sBh;
        coff = zb * sCb + zh * sCh;
    }
    float* Cf = (float*)Cv + coff;
    us*    Ch = (us*)Cv + coff;
    if (addsrc) addsrc += coff;

    __shared__ __align__(16) us As[BM * BK];
    __shared__ __align__(16) us Bs[BN * BK];

    const int tid  = threadIdx.x;
    const int lane = tid & 63;
    const int w    = tid >> 6;
    const int wm   = w >> 1;
    const int wn   = w & 1;
    const int row0 = blockIdx.y * BM;
    const int col0 = blockIdx.x * BN;

    float4v acc[FM][FN];
#pragma unroll
    for (int i = 0; i < FM; ++i)
#pragma unroll
        for (int j = 0; j < FN; ++j) acc[i][j] = (float4v)0.f;

    for (int k0 = 0; k0 < K; k0 += BK) {
#pragma unroll
        for (int i = 0; i < AI; ++i) {
            int rb = w * (BM / 4) + i * 8;
            int r  = rb + (lane >> 3);
            int sc8 = ((lane & 7) ^ (r & 7)) << 3;
            gload16(A + (long)(row0 + r) * lda + k0 + sc8, As + rb * 64);
        }
#pragma unroll
        for (int i = 0; i < BI; ++i) {
            int rb = w * (BN / 4) + i * 8;
            int r  = rb + (lane >> 3);
            int sc8 = ((lane & 7) ^ (r & 7)) << 3;
            gload16(B + (long)(col0 + r) * ldb + k0 + sc8, Bs + rb * 64);
        }
        __syncthreads();   // drains vmcnt -> LDS tiles ready
#pragma unroll
        for (int ks = 0; ks < 2; ++ks) {
            short8v af[FM], bfr[FN];
            int sw = ks * 4 + (lane >> 4);
#pragma unroll
            for (int i = 0; i < FM; ++i) {
                int r = wm * WTM + i * 16 + (lane & 15);
                af[i] = *reinterpret_cast<const short8v*>((const char*)As + r * 128 + ((sw ^ (r & 7)) << 4));
            }
#pragma unroll
            for (int j = 0; j < FN; ++j) {
                int r = wn * WTN + j * 16 + (lane & 15);
                bfr[j] = *reinterpret_cast<const short8v*>((const char*)Bs + r * 128 + ((sw ^ (r & 7)) << 4));
            }
#pragma unroll
            for (int i = 0; i < FM; ++i)
#pragma unroll
                for (int j = 0; j < FN; ++j)
                    acc[i][j] = __builtin_amdgcn_mfma_f32_16x16x32_bf16(af[i], bfr[j], acc[i][j], 0, 0, 0);
        }
        __syncthreads();
    }

    // ---- epilogue.  D layout: col = lane&15, row = (lane>>4)*4 + reg ----
#pragma unroll
    for (int i = 0; i < FM; ++i) {
        int growb = row0 + wm * WTM + i * 16 + ((lane >> 4) << 2);
#pragma unroll
        for (int j = 0; j < FN; ++j) {
            int gcol = col0 + wn * WTN + j * 16 + (lane & 15);
            if (EPI != 3 && gcol >= N) continue;
#pragma unroll
            for (int r = 0; r < 4; ++r) {
                int gr = growb + r;
                float v = acc[i][j][r];
                if (EPI == 3) {
                    v += bias[gcol];               // concat bq|bk|bv
                    int seg = gcol >> 10, c = gcol & 1023;
                    long o = (long)gr * 1024 + c;
                    us* base = (us*)Cv;            // qkvbuf
                    if (seg == 0) {
                        base[o]        = f2bf(v + p0[c]);   // qw
                        base[o + QOFF] = f2bf(v + p1[c]);   // qr
                    } else if (seg == 1) base[o + 2 * QOFF] = f2bf(v);
                    else                 base[o + 3 * QOFF] = f2bf(v);
                } else {
                    if (bias) v += bias[gcol];
                    if (EPI == 1) {
                        float xx = v;
                        v = 0.5f * xx * (1.f + tanhf(0.7978845608028654f
                                                     * (xx + 0.044715f * xx * xx * xx)));
                    }
                    if (addsrc) v += addsrc[(long)gr * ldc + gcol];
                    if (OUTBF) Ch[(long)gr * ldc + gcol] = f2bf(v);
                    else       Cf[(long)gr * ldc + gcol] = v;
                }
            }
        }
    }
}

// =====================================================================
// Fused TXL attention: per block = (64-row q-tile, b*h).  4 waves x 16 rows.
// logits(t,s) = (qw[t].k[s] + qr[t].rk[s+511-t]) * 0.125, causal; online
// softmax; O = P @ V.  qkv: qw|qr|k|v at QOFF.  vt: [bh][64 d][512 s].
// rk: [640][1024] bf16, rows 512..639 zero (j-window overhang).
// Wave w owns q-rows t0 + w*16 .. +15; within those, the D-fragment row
// for (rg,pr) is tw = w*16 + rg*4 + pr  (the w*16 term matters!).
// =====================================================================
__global__ __launch_bounds__(256)
void fattn_k(const us* __restrict__ qkv, const us* __restrict__ vt,
             const us* __restrict__ rk, us* __restrict__ obuf)
{
    __shared__ __align__(16) us lds_k[64 * 64];
    __shared__ __align__(16) us lds_v[64 * 64];
    __shared__ __align__(16) us lds_rk[128 * 64];
    __shared__ __align__(16) us lds_p[4 * 16 * 64];
    __shared__ float lds_r[4 * 16 * 132];       // per-wave R, row stride 132

    const int tid = threadIdx.x, lane = tid & 63, w = tid >> 6;
    const int qt = blockIdx.x, bh = blockIdx.y;
    const int b = bh >> 4, h = bh & 15;
    const int t0 = qt * 64;
    const int rg = lane >> 4, lc = lane & 15;

    const us* qwb = qkv + ((long)b * 512) * 1024 + h * 64;   // row stride 1024
    const us* qrb = qwb + QOFF;
    const us* kb  = qwb + 2 * QOFF;
    const us* vtb = vt + (long)bh * 64 * 512;                // rows d, stride 512
    const us* rkb = rk + h * 64;                             // rows j, stride 1024

    // Q fragments (rows t0 + w*16 + lc, k-slices kk*32 + rg*8)
    short8v aqw[2], aqr[2];
    {
        long qrow = (long)(t0 + w * 16 + lc) * 1024;
        int ko = rg * 8;
        aqw[0] = *(const short8v*)(qwb + qrow + ko);
        aqw[1] = *(const short8v*)(qwb + qrow + 32 + ko);
        aqr[0] = *(const short8v*)(qrb + qrow + ko);
        aqr[1] = *(const short8v*)(qrb + qrow + 32 + ko);
    }

    float4v oacc[4];
#pragma unroll
    for (int i = 0; i < 4; ++i) oacc[i] = (float4v)0.f;
    float mrow[4] = {-3e38f, -3e38f, -3e38f, -3e38f};
    float lrow[4] = {0.f, 0.f, 0.f, 0.f};

    float* rbase = lds_r + w * (16 * 132);
    us*    pbase = lds_p + w * (16 * 64);

    const int nst = qt + 1;
    for (int st = 0; st < nst; ++st) {
        const int s0 = st * 64;
        const int jb = s0 - t0 + 448;            // j-window base (>= 0)
        // ---- stage K, V(transposed), rk window (swizzled-source gload) ----
#pragma unroll
        for (int i = 0; i < 2; ++i) {
            int rb = w * 16 + i * 8;
            int r  = rb + (lane >> 3);
            int sl = ((lane & 7) ^ (r & 7)) << 3;
            gload16(kb + (long)(s0 + r) * 1024 + sl, lds_k + rb * 64);
            gload16(vtb + (long)r * 512 + s0 + sl, lds_v + rb * 64);
        }
#pragma unroll
        for (int i = 0; i < 4; ++i) {
            int rb = w * 32 + i * 8;
            int r  = rb + (lane >> 3);
            int sl = ((lane & 7) ^ (r & 7)) << 3;
            gload16(rkb + (long)(jb + r) * 1024 + sl, lds_rk + rb * 64);
        }
        __syncthreads();

        // ---- content scores (16 q-rows x 64 s) ----
        float4v sfr[4];
#pragma unroll
        for (int sn = 0; sn < 4; ++sn) {
            sfr[sn] = (float4v)0.f;
#pragma unroll
            for (int kk = 0; kk < 2; ++kk) {
                int r = sn * 16 + lc;
                int sw = kk * 4 + rg;
                short8v bf = *(const short8v*)((const char*)lds_k + r * 128 + ((sw ^ (r & 7)) << 4));
                sfr[sn] = __builtin_amdgcn_mfma_f32_16x16x32_bf16(aqw[kk], bf, sfr[sn], 0, 0, 0);
            }
        }
        // ---- rel band R[t][j] -> per-wave LDS ----
#pragma unroll
        for (int jn = 0; jn < 8; ++jn) {
            float4v rf = (float4v)0.f;
#pragma unroll
            for (int kk = 0; kk < 2; ++kk) {
                int r = jn * 16 + lc;
                int sw = kk * 4 + rg;
                short8v bf = *(const short8v*)((const char*)lds_rk + r * 128 + ((sw ^ (r & 7)) << 4));
                rf = __builtin_amdgcn_mfma_f32_16x16x32_bf16(aqr[kk], bf, rf, 0, 0, 0);
            }
#pragma unroll
            for (int pr = 0; pr < 4; ++pr)
                rbase[(rg * 4 + pr) * 132 + jn * 16 + lc] = rf[pr];
        }
        // ---- combine + shift + mask + online softmax ----
        // global t = t0 + w*16 + tt ; tw = w*16 + tt is the in-tile q-row.
        // rel local index = ss + 63 - tw ; causal: mask when ss > t0+tw-s0.
        float pv[4][4];
        float rmax[4] = {-3e38f, -3e38f, -3e38f, -3e38f};
#pragma unroll
        for (int pr = 0; pr < 4; ++pr) {
            int tt = rg * 4 + pr;
            int tw = w * 16 + tt;                 // FIX: include wave row offset
#pragma unroll
            for (int sn = 0; sn < 4; ++sn) {
                int ss = sn * 16 + lc;
                float lg = (sfr[sn][pr] + rbase[tt * 132 + ss + 63 - tw]) * 0.125f;
                if (ss > t0 - s0 + tw) lg = -1e30f;   // causal (active on diagonal)
                pv[sn][pr] = lg;
                rmax[pr] = fmaxf(rmax[pr], lg);
            }
        }
#pragma unroll
        for (int o = 1; o < 16; o <<= 1)
#pragma unroll
            for (int pr = 0; pr < 4; ++pr)
                rmax[pr] = fmaxf(rmax[pr], __shfl_xor(rmax[pr], o));
        float rsum[4];
#pragma unroll
        for (int pr = 0; pr < 4; ++pr) {
            float mn = fmaxf(mrow[pr], rmax[pr]);
            float al = __expf(mrow[pr] - mn);
            mrow[pr] = mn;
            lrow[pr] *= al;
            float s = 0.f;
#pragma unroll
            for (int sn = 0; sn < 4; ++sn) {
                float p = __expf(pv[sn][pr] - mn);
                pv[sn][pr] = p;
                s += p;
            }
            rsum[pr] = s;
#pragma unroll
            for (int dn = 0; dn < 4; ++dn) oacc[dn][pr] *= al;
        }
#pragma unroll
        for (int o = 1; o < 16; o <<= 1)
#pragma unroll
            for (int pr = 0; pr < 4; ++pr)
                rsum[pr] += __shfl_xor(rsum[pr], o);
#pragma unroll
        for (int pr = 0; pr < 4; ++pr) lrow[pr] += rsum[pr];
        // ---- P -> per-wave LDS (bf16, swizzled for A-frag reads) ----
#pragma unroll
        for (int pr = 0; pr < 4; ++pr) {
            int row = rg * 4 + pr;
#pragma unroll
            for (int sn = 0; sn < 4; ++sn) {
                int col = sn * 16 + lc;
                *(us*)((char*)pbase + row * 128 + (((col >> 3) ^ (row & 7)) << 4) + (col & 7) * 2)
                    = f2bf(pv[sn][pr]);
            }
        }
        // ---- PV accumulate ----
        short8v pa[2];
#pragma unroll
        for (int kk = 0; kk < 2; ++kk)
            pa[kk] = *(const short8v*)((const char*)pbase + lc * 128 + (((kk * 4 + rg) ^ (lc & 7)) << 4));
#pragma unroll
        for (int dn = 0; dn < 4; ++dn) {
#pragma unroll
            for (int kk = 0; kk < 2; ++kk) {
                int r = dn * 16 + lc;
                int sw = kk * 4 + rg;
                short8v vb = *(const short8v*)((const char*)lds_v + r * 128 + ((sw ^ (r & 7)) << 4));
                oacc[dn] = __builtin_amdgcn_mfma_f32_16x16x32_bf16(pa[kk], vb, oacc[dn], 0, 0, 0);
            }
        }
        __syncthreads();   // all waves done with K/V/rk before next stage
    }
    // ---- normalize + store ----
#pragma unroll
    for (int pr = 0; pr < 4; ++pr) {
        int t = t0 + w * 16 + rg * 4 + pr;
        float inv = 1.f / lrow[pr];
        long rowo = ((long)b * 512 + t) * 1024 + h * 64;
#pragma unroll
        for (int dn = 0; dn < 4; ++dn)
            obuf[rowo + dn * 16 + lc] = f2bf(oacc[dn][pr] * inv);
    }
}

// =====================================================================
// Transpose-convert: fp32 in[R][C] -> bf16 out[C][R], optional layer batch
// =====================================================================
__global__ __launch_bounds__(256)
void tconv_k(const float* __restrict__ in, us* __restrict__ out, int R, int C,
             long inL, long outL)
{
    in  += (long)blockIdx.z * inL;
    out += (long)blockIdx.z * outL;
    __shared__ float t[32][33];
    int c0 = blockIdx.x * 32, r0 = blockIdx.y * 32;
    int tx = threadIdx.x & 31, ty = threadIdx.x >> 5;
#pragma unroll
    for (int j = 0; j < 4; ++j)
        t[ty + j * 8][tx] = in[(long)(r0 + ty + j * 8) * C + c0 + tx];
    __syncthreads();
#pragma unroll
    for (int j = 0; j < 4; ++j)
        out[(long)(c0 + ty + j * 8) * R + r0 + tx] = f2bf(t[tx][ty + j * 8]);
}

// Batched bf16 transpose: v[B,T,H,HD] -> vt[B,H,HD,T]
__global__ __launch_bounds__(256)
void vtrans_k(const us* __restrict__ v, us* __restrict__ vt)
{
    __shared__ us t[32][33];
    int z = blockIdx.z;                    // b*NH + h
    int b = z >> 4, h = z & 15;
    const us* in = v + ((long)b * NT) * ND + h * NHD;
    us* out = vt + (long)z * NHD * NT;
    int d0 = blockIdx.x * 32, t0 = blockIdx.y * 32;
    int tx = threadIdx.x & 31, ty = threadIdx.x >> 5;
#pragma unroll
    for (int j = 0; j < 4; ++j)
        t[ty + j * 8][tx] = in[(long)(t0 + ty + j * 8) * ND + d0 + tx];
    __syncthreads();
#pragma unroll
    for (int j = 0; j < 4; ++j)
        out[(long)(d0 + ty + j * 8) * NT + t0 + tx] = t[tx][ty + j * 8];
}

// flat fp32 -> bf16 (n % 4 == 0)
__global__ __launch_bounds__(256)
void conv_k(const float* __restrict__ in, us* __restrict__ out, long n)
{
    long i = ((long)blockIdx.x * 256 + threadIdx.x) * 4;
    if (i >= n) return;
    float4 v = *reinterpret_cast<const float4*>(in + i);
    uint2 p;
    p.x = (unsigned)f2bf(v.x) | ((unsigned)f2bf(v.y) << 16);
    p.y = (unsigned)f2bf(v.z) | ((unsigned)f2bf(v.w) << 16);
    *reinterpret_cast<uint2*>(out + i) = p;
}

// zero rk pad rows [512,640)
__global__ __launch_bounds__(256)
void rkpad_k(us* __restrict__ rk)
{
    int i = blockIdx.x * 256 + threadIdx.x;   // 16384 uint4
    reinterpret_cast<uint4*>(rk + 512 * 1024)[i] = make_uint4(0, 0, 0, 0);
}

// concat per-layer qkv biases: bqkv[l][3072] = [bq|bk|bv]
__global__ __launch_bounds__(256)
void bcat_k(const float* __restrict__ bq, const float* __restrict__ bk,
            const float* __restrict__ bv, float* __restrict__ o)
{
    int i = blockIdx.x * 256 + threadIdx.x;       // 12*3072
    int l = i / 3072, rr = i % 3072, seg = rr >> 10, c = rr & 1023;
    const float* s = seg == 0 ? bq : seg == 1 ? bk : bv;
    o[i] = s[l * 1024 + c];
}

// =====================================================================
// LayerNorm D=1024 fp32 -> bf16, one block/row
// =====================================================================
__global__ __launch_bounds__(256)
void ln_k(const float* __restrict__ x, us* __restrict__ y,
          const float* __restrict__ sc, const float* __restrict__ bi)
{
    int row = blockIdx.x;
    const float* xr = x + (long)row * ND;
    int d4 = threadIdx.x * 4;
    float4 v = *reinterpret_cast<const float4*>(&xr[d4]);
    float sum = v.x + v.y + v.z + v.w;
    float sq  = v.x * v.x + v.y * v.y + v.z * v.z + v.w * v.w;
#pragma unroll
    for (int o = 32; o; o >>= 1) { sum += __shfl_xor(sum, o); sq += __shfl_xor(sq, o); }
    __shared__ float red[8];
    int w = threadIdx.x >> 6;
    if ((threadIdx.x & 63) == 0) { red[w] = sum; red[4 + w] = sq; }
    __syncthreads();
    sum = red[0] + red[1] + red[2] + red[3];
    sq  = red[4] + red[5] + red[6] + red[7];
    float mean = sum * (1.f / ND);
    float var  = fmaxf(sq * (1.f / ND) - mean * mean, 0.f);
    float inv  = rsqrtf(var + 1e-5f);
    float4 s4 = *reinterpret_cast<const float4*>(&sc[d4]);
    float4 b4 = *reinterpret_cast<const float4*>(&bi[d4]);
    uint2 p;
    p.x = (unsigned)f2bf((v.x - mean) * inv * s4.x + b4.x)
        | ((unsigned)f2bf((v.y - mean) * inv * s4.y + b4.y) << 16);
    p.y = (unsigned)f2bf((v.z - mean) * inv * s4.z + b4.z)
        | ((unsigned)f2bf((v.w - mean) * inv * s4.w + b4.w) << 16);
    *reinterpret_cast<uint2*>(y + (long)row * ND + d4) = p;
}

// sinusoid pos-emb (TXL order), bf16 out
__global__ __launch_bounds__(256)
void pemb_k(us* __restrict__ p)
{
    int t = blockIdx.x;
    float pos = (float)(NT - 1 - t);
    for (int j = threadIdx.x; j < ND / 2; j += 256) {
        float invf = expf(-(float)j * (9.210340371976184f / 512.0f));
        float ang  = pos * invf;
        p[(long)t * ND + j]           = f2bf(sinf(ang));
        p[(long)t * ND + ND / 2 + j]  = f2bf(cosf(ang));
    }
}

// adaptive input embedding -> h fp32
__global__ __launch_bounds__(256)
void embed_k(const int* __restrict__ x,
             const float* __restrict__ e0, const float* __restrict__ e1,
             const float* __restrict__ e2, const float* __restrict__ p1,
             const float* __restrict__ p2, float* __restrict__ h)
{
    __shared__ float e[256];
    int tok = blockIdx.x;
    int v = x[tok];
    float* outp = h + (long)tok * ND;
    if (v < 2000) {
        const float* r = e0 + (long)v * ND;
        for (int d = threadIdx.x; d < ND; d += 256) outp[d] = r[d] * 32.0f;
    } else if (v < 8000) {
        const float* r = e1 + (long)(v - 2000) * 256;
        e[threadIdx.x] = r[threadIdx.x];
        __syncthreads();
        for (int d = threadIdx.x; d < ND; d += 256) {
            float acc = 0.f;
#pragma unroll 4
            for (int i = 0; i < 256; ++i) acc += e[i] * p1[(long)i * ND + d];
            outp[d] = acc * 32.0f;
        }
    } else {
        const float* r = e2 + (long)(v - 8000) * 64;
        if (threadIdx.x < 64) e[threadIdx.x] = r[threadIdx.x];
        __syncthreads();
        for (int d = threadIdx.x; d < ND; d += 256) {
            float acc = 0.f;
#pragma unroll 4
            for (int i = 0; i < 64; ++i) acc += e[i] * p2[(long)i * ND + d];
            outp[d] = acc * 32.0f;
        }
    }
}

// ---------------------------------------------------------------- host
extern "C" void kernel_launch(void* const* d_in, const int* in_sizes, int n_in,
                              void* d_out, int out_size, void* d_ws, size_t ws_size,
                              hipStream_t stream)
{
    (void)in_sizes; (void)n_in; (void)out_size;
    const int*   x     = (const int*)  d_in[0];
    const float* emb0  = (const float*)d_in[1];
    const float* emb1  = (const float*)d_in[2];
    const float* emb2  = (const float*)d_in[3];
    const float* proj1 = (const float*)d_in[4];
    const float* proj2 = (const float*)d_in[5];
    const float* obias = (const float*)d_in[6];
    const float* rwb   = (const float*)d_in[7];
    const float* rrb   = (const float*)d_in[8];
    const float* ln1s  = (const float*)d_in[9];
    const float* ln1b  = (const float*)d_in[10];
    const float* Wq    = (const float*)d_in[11];
    const float* bq    = (const float*)d_in[12];
    const float* Wk    = (const float*)d_in[13];
    const float* bk    = (const float*)d_in[14];
    const float* Wv    = (const float*)d_in[15];
    const float* bv    = (const float*)d_in[16];
    const float* Wr    = (const float*)d_in[17];
    const float* Wo    = (const float*)d_in[18];
    const float* bo    = (const float*)d_in[19];
    const float* ln2s  = (const float*)d_in[20];
    const float* ln2b  = (const float*)d_in[21];
    const float* W1    = (const float*)d_in[22];
    const float* b1    = (const float*)d_in[23];
    const float* W2    = (const float*)d_in[24];
    const float* b2    = (const float*)d_in[25];
    float* out = (float*)d_out;

    // ---- d_out scratch (us-unit offsets); all dead before vocab GEMMs ----
    us* ob      = (us*)out;
    us* qkvbuf  = ob;                 // 8,388,608  (qw|qr|k|v)
    us* mid_bf  = ob + 8388608;       // 8,388,608  [2048][4096]
    us* vt_bf   = ob + 16777216;      // 2,097,152  [64][64][512]
    us* o_bf    = ob + 18874368;      // 2,097,152  [2048][1024]
    us* ain_bf  = ob + 20971520;      // 2,097,152  [2048][1024]
    us* rk_bf   = ob + 23068672;      //   655,360  [640][1024] (pad rows zeroed)
    us* pemb_bf = ob + 23724032;      //   524,288  [512][1024]
    // fallback per-layer weight scratch (only used if ws too small)
    us* wqkv_sc = ob + 24248320;      // 3,145,728
    us* wr_sc   = ob + 27394048;      // 1,048,576
    us* wo_sc   = ob + 28442624;      // 1,048,576
    us* w1_sc   = ob + 29491200;      // 4,194,304
    us* w2_sc   = ob + 33685504;      // 4,194,304  (ends 37,879,808 us)

    // ---- d_ws layout ----
    float* wsf      = (float*)d_ws;
    float* h        = wsf;                         // 2,097,152 f
    us*    h_bf     = (us*)(wsf + 2097152);
    us*    hp1_bf   = h_bf   + 2097152;            // 524,288
    us*    hp2_bf   = hp1_bf + 524288;             // 131,072
    us*    emb0_bf  = hp2_bf + 131072;             // 2048x1024 (2000 real)
    us*    emb1_bf  = emb0_bf + 2097152;           // 6144x256  (6000 real)
    us*    emb2_bf  = emb1_bf + 1572864;           // 24064x64  (24000 real)
    us*    proj1_bf = emb2_bf + 1540096;           // 256x1024
    us*    proj2_bf = proj1_bf + 262144;           // 64x1024
    float* bqkv     = (float*)(proj2_bf + 65536);  // 12*3072 f
    us*    wqkv_all = (us*)(bqkv + 36864);         // [12][3072][1024]
    us*    wr_all   = wqkv_all + (long)NL * 3072 * 1024;
    us*    wo_all   = wr_all   + (long)NL * 1024 * 1024;
    us*    w1_all   = wo_all   + (long)NL * 1024 * 1024;   // [12][4096][1024]
    us*    w2_all   = w1_all   + (long)NL * 4096 * 1024;   // [12][1024][4096]
    const bool big  = ws_size >= (size_t)352273408;        // full weight cache fits

    // ---- one-time setup ----
    bcat_k<<<144, 256, 0, stream>>>(bq, bk, bv, bqkv);
    conv_k<<<2000, 256, 0, stream>>>(emb0,  emb0_bf,  2048000);
    conv_k<<<1500, 256, 0, stream>>>(emb1,  emb1_bf,  1536000);
    conv_k<<<1500, 256, 0, stream>>>(emb2,  emb2_bf,  1536000);
    conv_k<<<256,  256, 0, stream>>>(proj1, proj1_bf, 262144);
    conv_k<<<64,   256, 0, stream>>>(proj2, proj2_bf, 65536);
    pemb_k<<<NT, 256, 0, stream>>>(pemb_bf);
    rkpad_k<<<64, 256, 0, stream>>>(rk_bf);
    embed_k<<<NBT, 256, 0, stream>>>(x, emb0, emb1, emb2, proj1, proj2, h);
    if (big) {   // batched all-layer weight transpose-convert (7 launches)
        tconv_k<<<dim3(32, 32, NL), 256, 0, stream>>>(Wq, wqkv_all,           1024, 1024, 1048576, 3145728);
        tconv_k<<<dim3(32, 32, NL), 256, 0, stream>>>(Wk, wqkv_all + 1048576, 1024, 1024, 1048576, 3145728);
        tconv_k<<<dim3(32, 32, NL), 256, 0, stream>>>(Wv, wqkv_all + 2097152, 1024, 1024, 1048576, 3145728);
        tconv_k<<<dim3(32, 32, NL), 256, 0, stream>>>(Wr, wr_all, 1024, 1024, 1048576, 1048576);
        tconv_k<<<dim3(32, 32, NL), 256, 0, stream>>>(Wo, wo_all, 1024, 1024, 1048576, 1048576);
        tconv_k<<<dim3(128, 32, NL), 256, 0, stream>>>(W1, w1_all, 1024, 4096, 4194304, 4194304);
        tconv_k<<<dim3(32, 128, NL), 256, 0, stream>>>(W2, w2_all, 4096, 1024, 4194304, 4194304);
    }

    for (int l = 0; l < NL; ++l) {
        const us* wqkv_t = big ? wqkv_all + (long)l * 3145728 : wqkv_sc;
        const us* wr_t   = big ? wr_all   + (long)l * 1048576 : wr_sc;
        const us* wo_t   = big ? wo_all   + (long)l * 1048576 : wo_sc;
        const us* w1_t   = big ? w1_all   + (long)l * 4194304 : w1_sc;
        const us* w2_t   = big ? w2_all   + (long)l * 4194304 : w2_sc;
        if (!big) {
            const long wOff = (long)l * ND * ND;
            tconv_k<<<dim3(32, 32), 256, 0, stream>>>(Wq + wOff, wqkv_sc,           1024, 1024, 0, 0);
            tconv_k<<<dim3(32, 32), 256, 0, stream>>>(Wk + wOff, wqkv_sc + 1048576, 1024, 1024, 0, 0);
            tconv_k<<<dim3(32, 32), 256, 0, stream>>>(Wv + wOff, wqkv_sc + 2097152, 1024, 1024, 0, 0);
            tconv_k<<<dim3(32, 32), 256, 0, stream>>>(Wr + wOff, wr_sc, 1024, 1024, 0, 0);
            tconv_k<<<dim3(32, 32), 256, 0, stream>>>(Wo + wOff, wo_sc, 1024, 1024, 0, 0);
            tconv_k<<<dim3(128, 32), 256, 0, stream>>>(W1 + (long)l * ND * NF, w1_sc, 1024, 4096, 0, 0);
            tconv_k<<<dim3(32, 128), 256, 0, stream>>>(W2 + (long)l * ND * NF, w2_sc, 4096, 1024, 0, 0);
        }

        // pre-norm 1 -> bf16
        ln_k<<<NBT, 256, 0, stream>>>(h, ain_bf, ln1s + l * ND, ln1b + l * ND);
        // fused QKV (EPI=3): qw,qr,k,v bf16 into qkvbuf
        bgemm_k<128, 64, 3, true><<<dim3(48, 16, 1), 256, 0, stream>>>(
            ain_bf, wqkv_t, qkvbuf, bqkv + l * 3072, nullptr, rwb, rrb,
            3072, 1024, 1024, 1024, 1024, 0, 0, 0, 0, 0, 0, 0);
        // r_k = pemb @ Wr -> bf16 (rows 0..511; pad rows stay zero)
        bgemm_k<64, 64, 0, true><<<dim3(16, 8, 1), 256, 0, stream>>>(
            pemb_bf, wr_t, rk_bf, nullptr, nullptr, nullptr, nullptr,
            1024, 1024, 1024, 1024, 1024, 0, 0, 0, 0, 0, 0, 0);
        // v -> vt [B,H,HD,T]
        vtrans_k<<<dim3(2, 16, NB * NH), 256, 0, stream>>>(qkvbuf + 3 * QOFF, vt_bf);
        // fused attention: scores + rel_shift + causal softmax + PV
        fattn_k<<<dim3(8, NB * NH), 256, 0, stream>>>(qkvbuf, vt_bf, rk_bf, o_bf);
        // h += o @ Wo + bo (fp32 residual)
        bgemm_k<64, 64, 0, false><<<dim3(16, 32, 1), 256, 0, stream>>>(
            o_bf, wo_t, h, bo + l * ND, h, nullptr, nullptr,
            1024, 1024, 1024, 1024, 1024, 0, 0, 0, 0, 0, 0, 0);

        // FFN
        ln_k<<<NBT, 256, 0, stream>>>(h, ain_bf, ln2s + l * ND, ln2b + l * ND);
        bgemm_k<128, 128, 1, true><<<dim3(32, 16, 1), 256, 0, stream>>>(
            ain_bf, w1_t, mid_bf, b1 + (long)l * NF, nullptr, nullptr, nullptr,
            4096, 1024, 1024, 1024, 4096, 0, 0, 0, 0, 0, 0, 0);
        bgemm_k<64, 64, 0, false><<<dim3(16, 32, 1), 256, 0, stream>>>(
            mid_bf, w2_t, h, b2 + l * ND, h, nullptr, nullptr,
            1024, 4096, 4096, 4096, 1024, 0, 0, 0, 0, 0, 0, 0);
    }

    // ---- tied adaptive-softmax output: (h @ proj^T) @ emb^T ----
    conv_k<<<2048, 256, 0, stream>>>(h, h_bf, (long)NBT * ND);
    // cluster 0: cols [0,2000)
    bgemm_k<128, 64, 0, false><<<dim3(32, 16, 1), 256, 0, stream>>>(
        h_bf, emb0_bf, out, obias, nullptr, nullptr, nullptr,
        2000, 1024, 1024, 1024, NV, 0, 0, 0, 0, 0, 0, 0);
    // cluster 1: hp1 = h @ proj1^T ; cols [2000,8000)
    bgemm_k<64, 64, 0, true><<<dim3(4, 32, 1), 256, 0, stream>>>(
        h_bf, proj1_bf, hp1_bf, nullptr, nullptr, nullptr, nullptr,
        256, 1024, 1024, 1024, 256, 0, 0, 0, 0, 0, 0, 0);
    bgemm_k<128, 128, 0, false><<<dim3(47, 16, 1), 256, 0, stream>>>(
        hp1_bf, emb1_bf, out + 2000, obias + 2000, nullptr, nullptr, nullptr,
        6000, 256, 256, 256, NV, 0, 0, 0, 0, 0, 0, 0);
    // cluster 2: hp2 = h @ proj2^T ; cols [8000,32000)
    bgemm_k<64, 64, 0, true><<<dim3(1, 32, 1), 256, 0, stream>>>(
        h_bf, proj2_bf, hp2_bf, nullptr, nullptr, nullptr, nullptr,
        64, 1024, 1024, 1024, 64, 0, 0, 0, 0, 0, 0, 0);
    bgemm_k<128, 128, 0, false><<<dim3(188, 16, 1), 256, 0, stream>>>(
        hp2_bf, emb2_bf, out + 8000, obias + 8000, nullptr, nullptr, nullptr,
        24000, 64, 64, 64, NV, 0, 0, 0, 0, 0, 0, 0);
}

// Round 8
// 2878.333 us; speedup vs baseline: 6.6859x; 1.0774x over previous
//
#include <hip/hip_runtime.h>

using us = unsigned short;
typedef short short8v __attribute__((ext_vector_type(8)));
typedef float float4v __attribute__((ext_vector_type(4)));

// ---------------- problem constants ----------------
constexpr int NB  = 4;
constexpr int NT  = 512;
constexpr int ND  = 1024;
constexpr int NL  = 12;
constexpr int NH  = 16;
constexpr int NF  = 4096;
constexpr int NHD = 64;
constexpr int NBT = NB * NT;   // 2048
constexpr int NV  = 32000;
constexpr long QOFF = (long)NBT * ND;  // qw|qr|k stride in qkvbuf
constexpr long RKL  = 640L * 1024;     // per-layer rk stride (rows 512.. are zero pad)

__device__ __forceinline__ us f2bf(float f) {
    unsigned u = __float_as_uint(f);
    u += 0x7fffu + ((u >> 16) & 1u);      // RNE
    return (us)(u >> 16);
}

// async global->LDS, 16B per lane. LDS dest is wave-uniform base + lane*16;
// global src is per-lane (pre-swizzled for bank-conflict-free ds_read).
__device__ __forceinline__ void gload16(const us* g, us* l) {
    __builtin_amdgcn_global_load_lds(
        (const __attribute__((address_space(1))) void*)g,
        (__attribute__((address_space(3))) void*)l, 16, 0, 0);
}

// =====================================================================
// bf16 MFMA GEMM:  C[M,N] = A[M,K] @ B[N,K]^T   (both row-major, k-contig)
// 256 threads = 4 waves (2x2), per-wave tile (BM/2)x(BN/2), BK=64.
// Staging: global_load_lds dwordx4, linear LDS rows of 128B, source slot
// pre-swizzled by s^(r&7); ds_read applies the same XOR (involution).
// EPI: 0 plain (+bias,+addsrc), 1 gelu, 3 fused QKV epilogue:
//      seg0 -> qw,qr (+r_w/r_r bias), seg1 -> k, seg2 -> vt[b,h,d,t] packed.
// =====================================================================
template<int BM, int BN, int EPI, bool OUTBF>
__global__ __launch_bounds__(256)
void bgemm_k(const us* __restrict__ A, const us* __restrict__ B, void* Cv,
             const float* __restrict__ bias, const float* addsrc,
             const float* __restrict__ p0, const float* __restrict__ p1,
             us* __restrict__ vtp,
             int N, int K, int lda, int ldb, int ldc,
             int bdiv, long sAb, long sAh, long sBb, long sBh, long sCb, long sCh)
{
    constexpr int BK  = 64;
    constexpr int WTM = BM / 2, WTN = BN / 2;
    constexpr int FM  = WTM / 16, FN = WTN / 16;
    constexpr int AI  = BM / 32;       // gload16 instr per wave (A tile)
    constexpr int BI  = BN / 32;
    static_assert(BM % 32 == 0 && BN % 32 == 0, "");

    long coff = 0;
    if (bdiv > 0) {
        int z = blockIdx.z, zb = z / bdiv, zh = z % bdiv;
        A += zb * sAb + zh * sAh;
        B += zb * sBb + zh * sBh;
        coff = zb * sCb + zh * sCh;
    }
    float* Cf = (float*)Cv + coff;
    us*    Ch = (us*)Cv + coff;
    if (addsrc) addsrc += coff;

    __shared__ __align__(16) us As[BM * BK];
    __shared__ __align__(16) us Bs[BN * BK];

    const int tid  = threadIdx.x;
    const int lane = tid & 63;
    const int w    = tid >> 6;
    const int wm   = w >> 1;
    const int wn   = w & 1;
    const int row0 = blockIdx.y * BM;
    const int col0 = blockIdx.x * BN;

    float4v acc[FM][FN];
#pragma unroll
    for (int i = 0; i < FM; ++i)
#pragma unroll
        for (int j = 0; j < FN; ++j) acc[i][j] = (float4v)0.f;

    for (int k0 = 0; k0 < K; k0 += BK) {
#pragma unroll
        for (int i = 0; i < AI; ++i) {
            int rb = w * (BM / 4) + i * 8;
            int r  = rb + (lane >> 3);
            int sc8 = ((lane & 7) ^ (r & 7)) << 3;
            gload16(A + (long)(row0 + r) * lda + k0 + sc8, As + rb * 64);
        }
#pragma unroll
        for (int i = 0; i < BI; ++i) {
            int rb = w * (BN / 4) + i * 8;
            int r  = rb + (lane >> 3);
            int sc8 = ((lane & 7) ^ (r & 7)) << 3;
            gload16(B + (long)(col0 + r) * ldb + k0 + sc8, Bs + rb * 64);
        }
        __syncthreads();   // drains vmcnt -> LDS tiles ready
#pragma unroll
        for (int ks = 0; ks < 2; ++ks) {
            short8v af[FM], bfr[FN];
            int sw = ks * 4 + (lane >> 4);
#pragma unroll
            for (int i = 0; i < FM; ++i) {
                int r = wm * WTM + i * 16 + (lane & 15);
                af[i] = *reinterpret_cast<const short8v*>((const char*)As + r * 128 + ((sw ^ (r & 7)) << 4));
            }
#pragma unroll
            for (int j = 0; j < FN; ++j) {
                int r = wn * WTN + j * 16 + (lane & 15);
                bfr[j] = *reinterpret_cast<const short8v*>((const char*)Bs + r * 128 + ((sw ^ (r & 7)) << 4));
            }
#pragma unroll
            for (int i = 0; i < FM; ++i)
#pragma unroll
                for (int j = 0; j < FN; ++j)
                    acc[i][j] = __builtin_amdgcn_mfma_f32_16x16x32_bf16(af[i], bfr[j], acc[i][j], 0, 0, 0);
        }
        __syncthreads();
    }

    // ---- epilogue.  D layout: col = lane&15, row = (lane>>4)*4 + reg ----
#pragma unroll
    for (int i = 0; i < FM; ++i) {
        int growb = row0 + wm * WTM + i * 16 + ((lane >> 4) << 2);
#pragma unroll
        for (int j = 0; j < FN; ++j) {
            int gcol = col0 + wn * WTN + j * 16 + (lane & 15);
            if (EPI == 3) {
                int seg = gcol >> 10, c = gcol & 1023;
                float bb = bias[gcol];
                if (seg == 2) {
                    // v -> vt[b,h,d,t], 4 consecutive t packed into 8B
                    unsigned lo = (unsigned)f2bf(acc[i][j][0] + bb)
                                | ((unsigned)f2bf(acc[i][j][1] + bb) << 16);
                    unsigned hi = (unsigned)f2bf(acc[i][j][2] + bb)
                                | ((unsigned)f2bf(acc[i][j][3] + bb) << 16);
                    int bidx = growb >> 9, tb = growb & 511;
                    uint2 pk; pk.x = lo; pk.y = hi;
                    *reinterpret_cast<uint2*>(
                        vtp + ((long)((bidx * 16 + (c >> 6)) * 64 + (c & 63)) << 9) + tb) = pk;
                } else {
                    us* base = (us*)Cv;
#pragma unroll
                    for (int r = 0; r < 4; ++r) {
                        int gr = growb + r;
                        float v = acc[i][j][r] + bb;
                        long o = (long)gr * 1024 + c;
                        if (seg == 0) {
                            base[o]        = f2bf(v + p0[c]);   // qw
                            base[o + QOFF] = f2bf(v + p1[c]);   // qr
                        } else base[o + 2 * QOFF] = f2bf(v);    // k
                    }
                }
            } else {
                if (gcol >= N) continue;
#pragma unroll
                for (int r = 0; r < 4; ++r) {
                    int gr = growb + r;
                    float v = acc[i][j][r];
                    if (bias) v += bias[gcol];
                    if (EPI == 1) {
                        float xx = v;
                        v = 0.5f * xx * (1.f + tanhf(0.7978845608028654f
                                                     * (xx + 0.044715f * xx * xx * xx)));
                    }
                    if (addsrc) v += addsrc[(long)gr * ldc + gcol];
                    if (OUTBF) Ch[(long)gr * ldc + gcol] = f2bf(v);
                    else       Cf[(long)gr * ldc + gcol] = v;
                }
            }
        }
    }
}

// =====================================================================
// Fused TXL attention with ROLLING rel band.  Block = (64-row q-tile, b*h),
// 4 waves x 16 q-rows.  logits(t,s) = (qw[t].k[s] + qr[t].rk[s+511-t])/8,
// causal, online softmax, O = P@V.
// R window: 128 circular slots per q-row; slot(J) = J & 127 (J = global rk
// row).  Window base slot sb = ((st-qt+7)&1)<<6.  Step st==0 computes both
// halves; st>=1 stages+computes only the new upper half (slots sb^64) —
// the lower half is the previous step's upper half (window moves by 64).
// =====================================================================
__global__ __launch_bounds__(256)
void fattn_k(const us* __restrict__ qkv, const us* __restrict__ vt,
             const us* __restrict__ rk, us* __restrict__ obuf)
{
    __shared__ __align__(16) us lds_k[64 * 64];
    __shared__ __align__(16) us lds_v[64 * 64];
    __shared__ __align__(16) us lds_rk[64 * 64];
    __shared__ __align__(16) us lds_p[4 * 16 * 64];
    __shared__ float lds_r[4 * 16 * 132];       // per-wave R, row stride 132

    const int tid = threadIdx.x, lane = tid & 63, w = tid >> 6;
    const int qt = blockIdx.x, bh = blockIdx.y;
    const int b = bh >> 4, h = bh & 15;
    const int t0 = qt * 64;
    const int rg = lane >> 4, lc = lane & 15;

    const us* qwb = qkv + ((long)b * 512) * 1024 + h * 64;   // row stride 1024
    const us* qrb = qwb + QOFF;
    const us* kb  = qwb + 2 * QOFF;
    const us* vtb = vt + (long)bh * 64 * 512;                // rows d, stride 512
    const us* rkb = rk + h * 64;                             // rows j, stride 1024

    // Q fragments (rows t0 + w*16 + lc, k-slices kk*32 + rg*8)
    short8v aqw[2], aqr[2];
    {
        long qrow = (long)(t0 + w * 16 + lc) * 1024;
        int ko = rg * 8;
        aqw[0] = *(const short8v*)(qwb + qrow + ko);
        aqw[1] = *(const short8v*)(qwb + qrow + 32 + ko);
        aqr[0] = *(const short8v*)(qrb + qrow + ko);
        aqr[1] = *(const short8v*)(qrb + qrow + 32 + ko);
    }

    float4v oacc[4];
#pragma unroll
    for (int i = 0; i < 4; ++i) oacc[i] = (float4v)0.f;
    float mrow[4] = {-3e38f, -3e38f, -3e38f, -3e38f};
    float lrow[4] = {0.f, 0.f, 0.f, 0.f};

    float* rbase = lds_r + w * (16 * 132);
    us*    pbase = lds_p + w * (16 * 64);

    // stage one 64-row rk half starting at global row j0
    auto stage_rk = [&](int j0) {
#pragma unroll
        for (int i = 0; i < 2; ++i) {
            int rb = w * 16 + i * 8;
            int r  = rb + (lane >> 3);
            int sl = ((lane & 7) ^ (r & 7)) << 3;
            gload16(rkb + (long)(j0 + r) * 1024 + sl, lds_rk + rb * 64);
        }
    };
    // rel MFMA over the staged 64 rows -> R slots [wbase, wbase+64)
    auto rel_half = [&](int wbase) {
#pragma unroll
        for (int jn = 0; jn < 4; ++jn) {
            float4v rf = (float4v)0.f;
#pragma unroll
            for (int kk = 0; kk < 2; ++kk) {
                int r = jn * 16 + lc;
                int sw = kk * 4 + rg;
                short8v bf = *(const short8v*)((const char*)lds_rk + r * 128 + ((sw ^ (r & 7)) << 4));
                rf = __builtin_amdgcn_mfma_f32_16x16x32_bf16(aqr[kk], bf, rf, 0, 0, 0);
            }
#pragma unroll
            for (int pr = 0; pr < 4; ++pr)
                rbase[(rg * 4 + pr) * 132 + wbase + jn * 16 + lc] = rf[pr];
        }
    };

    const int nst = qt + 1;
    for (int st = 0; st < nst; ++st) {
        const int s0 = st * 64;
        const int jb = (st - qt) * 64 + 448;          // window base row (>=0)
        const int sb = ((st - qt + 7) & 1) << 6;      // window base slot

        // ---- stage K, V (every step) ----
#pragma unroll
        for (int i = 0; i < 2; ++i) {
            int rb = w * 16 + i * 8;
            int r  = rb + (lane >> 3);
            int sl = ((lane & 7) ^ (r & 7)) << 3;
            gload16(kb + (long)(s0 + r) * 1024 + sl, lds_k + rb * 64);
            gload16(vtb + (long)r * 512 + s0 + sl, lds_v + rb * 64);
        }
        if (st == 0) {
            stage_rk(jb);            // lower half
            __syncthreads();
            rel_half(sb);
            __syncthreads();         // all waves done with lds_rk
            stage_rk(jb + 64);       // upper half
            __syncthreads();
        } else {
            stage_rk(jb + 64);       // only the new upper half
            __syncthreads();
        }

        // ---- content scores (16 q-rows x 64 s) ----
        float4v sfr[4];
#pragma unroll
        for (int sn = 0; sn < 4; ++sn) {
            sfr[sn] = (float4v)0.f;
#pragma unroll
            for (int kk = 0; kk < 2; ++kk) {
                int r = sn * 16 + lc;
                int sw = kk * 4 + rg;
                short8v bf = *(const short8v*)((const char*)lds_k + r * 128 + ((sw ^ (r & 7)) << 4));
                sfr[sn] = __builtin_amdgcn_mfma_f32_16x16x32_bf16(aqw[kk], bf, sfr[sn], 0, 0, 0);
            }
        }
        rel_half(sb ^ 64);           // upper half of current window

        // ---- combine + shift + mask + online softmax ----
        // global t = t0 + tw, tw = w*16 + rg*4 + pr;  jloc = ss + 63 - tw;
        // R slot = (sb + jloc) & 127.
        float pv[4][4];
        float rmax[4] = {-3e38f, -3e38f, -3e38f, -3e38f};
#pragma unroll
        for (int pr = 0; pr < 4; ++pr) {
            int tt = rg * 4 + pr;
            int tw = w * 16 + tt;
#pragma unroll
            for (int sn = 0; sn < 4; ++sn) {
                int ss = sn * 16 + lc;
                int slot = (sb + ss + 63 - tw) & 127;
                float lg = (sfr[sn][pr] + rbase[tt * 132 + slot]) * 0.125f;
                if (ss > t0 - s0 + tw) lg = -1e30f;   // causal (active on diagonal)
                pv[sn][pr] = lg;
                rmax[pr] = fmaxf(rmax[pr], lg);
            }
        }
#pragma unroll
        for (int o = 1; o < 16; o <<= 1)
#pragma unroll
            for (int pr = 0; pr < 4; ++pr)
                rmax[pr] = fmaxf(rmax[pr], __shfl_xor(rmax[pr], o));
        float rsum[4];
#pragma unroll
        for (int pr = 0; pr < 4; ++pr) {
            float mn = fmaxf(mrow[pr], rmax[pr]);
            float al = __expf(mrow[pr] - mn);
            mrow[pr] = mn;
            lrow[pr] *= al;
            float s = 0.f;
#pragma unroll
            for (int sn = 0; sn < 4; ++sn) {
                float p = __expf(pv[sn][pr] - mn);
                pv[sn][pr] = p;
                s += p;
            }
            rsum[pr] = s;
#pragma unroll
            for (int dn = 0; dn < 4; ++dn) oacc[dn][pr] *= al;
        }
#pragma unroll
        for (int o = 1; o < 16; o <<= 1)
#pragma unroll
            for (int pr = 0; pr < 4; ++pr)
                rsum[pr] += __shfl_xor(rsum[pr], o);
#pragma unroll
        for (int pr = 0; pr < 4; ++pr) lrow[pr] += rsum[pr];

        // ---- P -> per-wave LDS (bf16, swizzled for A-frag reads) ----
#pragma unroll
        for (int pr = 0; pr < 4; ++pr) {
            int row = rg * 4 + pr;
#pragma unroll
            for (int sn = 0; sn < 4; ++sn) {
                int col = sn * 16 + lc;
                *(us*)((char*)pbase + row * 128 + (((col >> 3) ^ (row & 7)) << 4) + (col & 7) * 2)
                    = f2bf(pv[sn][pr]);
            }
        }
        // ---- PV accumulate ----
        short8v pa[2];
#pragma unroll
        for (int kk = 0; kk < 2; ++kk)
            pa[kk] = *(const short8v*)((const char*)pbase + lc * 128 + (((kk * 4 + rg) ^ (lc & 7)) << 4));
#pragma unroll
        for (int dn = 0; dn < 4; ++dn) {
#pragma unroll
            for (int kk = 0; kk < 2; ++kk) {
                int r = dn * 16 + lc;
                int sw = kk * 4 + rg;
                short8v vb = *(const short8v*)((const char*)lds_v + r * 128 + ((sw ^ (r & 7)) << 4));
                oacc[dn] = __builtin_amdgcn_mfma_f32_16x16x32_bf16(pa[kk], vb, oacc[dn], 0, 0, 0);
            }
        }
        __syncthreads();   // all waves done with lds_k/v/rk before next stage
    }
    // ---- normalize + store ----
#pragma unroll
    for (int pr = 0; pr < 4; ++pr) {
        int t = t0 + w * 16 + rg * 4 + pr;
        float inv = 1.f / lrow[pr];
        long rowo = ((long)b * 512 + t) * 1024 + h * 64;
#pragma unroll
        for (int dn = 0; dn < 4; ++dn)
            obuf[rowo + dn * 16 + lc] = f2bf(oacc[dn][pr] * inv);
    }
}

// =====================================================================
// Transpose-convert: fp32 in[R][C] -> bf16 out[C][R], optional layer batch
// =====================================================================
__global__ __launch_bounds__(256)
void tconv_k(const float* __restrict__ in, us* __restrict__ out, int R, int C,
             long inL, long outL)
{
    in  += (long)blockIdx.z * inL;
    out += (long)blockIdx.z * outL;
    __shared__ float t[32][33];
    int c0 = blockIdx.x * 32, r0 = blockIdx.y * 32;
    int tx = threadIdx.x & 31, ty = threadIdx.x >> 5;
#pragma unroll
    for (int j = 0; j < 4; ++j)
        t[ty + j * 8][tx] = in[(long)(r0 + ty + j * 8) * C + c0 + tx];
    __syncthreads();
#pragma unroll
    for (int j = 0; j < 4; ++j)
        out[(long)(c0 + ty + j * 8) * R + r0 + tx] = f2bf(t[tx][ty + j * 8]);
}

// flat fp32 -> bf16 (n % 4 == 0)
__global__ __launch_bounds__(256)
void conv_k(const float* __restrict__ in, us* __restrict__ out, long n)
{
    long i = ((long)blockIdx.x * 256 + threadIdx.x) * 4;
    if (i >= n) return;
    float4 v = *reinterpret_cast<const float4*>(in + i);
    uint2 p;
    p.x = (unsigned)f2bf(v.x) | ((unsigned)f2bf(v.y) << 16);
    p.y = (unsigned)f2bf(v.z) | ((unsigned)f2bf(v.w) << 16);
    *reinterpret_cast<uint2*>(out + i) = p;
}

// zero rk pad rows [512,640) for all 12 layers
__global__ __launch_bounds__(256)
void rkpad12_k(us* __restrict__ rk)
{
    int i = blockIdx.x * 256 + threadIdx.x;   // 98304 uint4 total
    int l = i >> 13, r = i & 8191;
    reinterpret_cast<uint4*>(rk + (long)l * RKL + 512 * 1024)[r] = make_uint4(0, 0, 0, 0);
}

// concat per-layer qkv biases: bqkv[l][3072] = [bq|bk|bv]
__global__ __launch_bounds__(256)
void bcat_k(const float* __restrict__ bq, const float* __restrict__ bk,
            const float* __restrict__ bv, float* __restrict__ o)
{
    int i = blockIdx.x * 256 + threadIdx.x;       // 12*3072
    int l = i / 3072, rr = i % 3072, seg = rr >> 10, c = rr & 1023;
    const float* s = seg == 0 ? bq : seg == 1 ? bk : bv;
    o[i] = s[l * 1024 + c];
}

// =====================================================================
// LayerNorm D=1024 fp32 -> bf16, one block/row
// =====================================================================
__global__ __launch_bounds__(256)
void ln_k(const float* __restrict__ x, us* __restrict__ y,
          const float* __restrict__ sc, const float* __restrict__ bi)
{
    int row = blockIdx.x;
    const float* xr = x + (long)row * ND;
    int d4 = threadIdx.x * 4;
    float4 v = *reinterpret_cast<const float4*>(&xr[d4]);
    float sum = v.x + v.y + v.z + v.w;
    float sq  = v.x * v.x + v.y * v.y + v.z * v.z + v.w * v.w;
#pragma unroll
    for (int o = 32; o; o >>= 1) { sum += __shfl_xor(sum, o); sq += __shfl_xor(sq, o); }
    __shared__ float red[8];
    int w = threadIdx.x >> 6;
    if ((threadIdx.x & 63) == 0) { red[w] = sum; red[4 + w] = sq; }
    __syncthreads();
    sum = red[0] + red[1] + red[2] + red[3];
    sq  = red[4] + red[5] + red[6] + red[7];
    float mean = sum * (1.f / ND);
    float var  = fmaxf(sq * (1.f / ND) - mean * mean, 0.f);
    float inv  = rsqrtf(var + 1e-5f);
    float4 s4 = *reinterpret_cast<const float4*>(&sc[d4]);
    float4 b4 = *reinterpret_cast<const float4*>(&bi[d4]);
    uint2 p;
    p.x = (unsigned)f2bf((v.x - mean) * inv * s4.x + b4.x)
        | ((unsigned)f2bf((v.y - mean) * inv * s4.y + b4.y) << 16);
    p.y = (unsigned)f2bf((v.z - mean) * inv * s4.z + b4.z)
        | ((unsigned)f2bf((v.w - mean) * inv * s4.w + b4.w) << 16);
    *reinterpret_cast<uint2*>(y + (long)row * ND + d4) = p;
}

// sinusoid pos-emb (TXL order), bf16 out
__global__ __launch_bounds__(256)
void pemb_k(us* __restrict__ p)
{
    int t = blockIdx.x;
    float pos = (float)(NT - 1 - t);
    for (int j = threadIdx.x; j < ND / 2; j += 256) {
        float invf = expf(-(float)j * (9.210340371976184f / 512.0f));
        float ang  = pos * invf;
        p[(long)t * ND + j]           = f2bf(sinf(ang));
        p[(long)t * ND + ND / 2 + j]  = f2bf(cosf(ang));
    }
}

// adaptive input embedding -> h fp32
__global__ __launch_bounds__(256)
void embed_k(const int* __restrict__ x,
             const float* __restrict__ e0, const float* __restrict__ e1,
             const float* __restrict__ e2, const float* __restrict__ p1,
             const float* __restrict__ p2, float* __restrict__ h)
{
    __shared__ float e[256];
    int tok = blockIdx.x;
    int v = x[tok];
    float* outp = h + (long)tok * ND;
    if (v < 2000) {
        const float* r = e0 + (long)v * ND;
        for (int d = threadIdx.x; d < ND; d += 256) outp[d] = r[d] * 32.0f;
    } else if (v < 8000) {
        const float* r = e1 + (long)(v - 2000) * 256;
        e[threadIdx.x] = r[threadIdx.x];
        __syncthreads();
        for (int d = threadIdx.x; d < ND; d += 256) {
            float acc = 0.f;
#pragma unroll 4
            for (int i = 0; i < 256; ++i) acc += e[i] * p1[(long)i * ND + d];
            outp[d] = acc * 32.0f;
        }
    } else {
        const float* r = e2 + (long)(v - 8000) * 64;
        if (threadIdx.x < 64) e[threadIdx.x] = r[threadIdx.x];
        __syncthreads();
        for (int d = threadIdx.x; d < ND; d += 256) {
            float acc = 0.f;
#pragma unroll 4
            for (int i = 0; i < 64; ++i) acc += e[i] * p2[(long)i * ND + d];
            outp[d] = acc * 32.0f;
        }
    }
}

// ---------------------------------------------------------------- host
extern "C" void kernel_launch(void* const* d_in, const int* in_sizes, int n_in,
                              void* d_out, int out_size, void* d_ws, size_t ws_size,
                              hipStream_t stream)
{
    (void)in_sizes; (void)n_in; (void)out_size;
    const int*   x     = (const int*)  d_in[0];
    const float* emb0  = (const float*)d_in[1];
    const float* emb1  = (const float*)d_in[2];
    const float* emb2  = (const float*)d_in[3];
    const float* proj1 = (const float*)d_in[4];
    const float* proj2 = (const float*)d_in[5];
    const float* obias = (const float*)d_in[6];
    const float* rwb   = (const float*)d_in[7];
    const float* rrb   = (const float*)d_in[8];
    const float* ln1s  = (const float*)d_in[9];
    const float* ln1b  = (const float*)d_in[10];
    const float* Wq    = (const float*)d_in[11];
    const float* bq    = (const float*)d_in[12];
    const float* Wk    = (const float*)d_in[13];
    const float* bk    = (const float*)d_in[14];
    const float* Wv    = (const float*)d_in[15];
    const float* bv    = (const float*)d_in[16];
    const float* Wr    = (const float*)d_in[17];
    const float* Wo    = (const float*)d_in[18];
    const float* bo    = (const float*)d_in[19];
    const float* ln2s  = (const float*)d_in[20];
    const float* ln2b  = (const float*)d_in[21];
    const float* W1    = (const float*)d_in[22];
    const float* b1    = (const float*)d_in[23];
    const float* W2    = (const float*)d_in[24];
    const float* b2    = (const float*)d_in[25];
    float* out = (float*)d_out;

    // ---- d_out scratch (us-unit offsets); all dead before vocab GEMMs ----
    us* ob      = (us*)out;
    us* qkvbuf  = ob;                 // 6,291,456  (qw|qr|k)
    us* mid_bf  = ob +  6291456;      // 8,388,608  [2048][4096]
    us* vt_bf   = ob + 14680064;      // 2,097,152  [64][64][512]
    us* o_bf    = ob + 16777216;      // 2,097,152  [2048][1024]
    us* ain_bf  = ob + 18874368;      // 2,097,152  [2048][1024]
    us* rk_all  = ob + 20971520;      // 7,864,320  [12][640][1024] (pad rows zero)
    us* pemb_bf = ob + 28835840;      //   524,288  [512][1024]
    // fallback per-layer weight scratch (only used if ws too small)
    us* wqkv_sc = ob + 29360128;      // 3,145,728
    us* wr_sc   = ob + 32505856;      // 1,048,576
    us* wo_sc   = ob + 33554432;      // 1,048,576
    us* w1_sc   = ob + 34603008;      // 4,194,304
    us* w2_sc   = ob + 38797312;      // 4,194,304  (ends 42,991,616 us)

    // ---- d_ws layout ----
    float* wsf      = (float*)d_ws;
    float* h        = wsf;                         // 2,097,152 f
    us*    h_bf     = (us*)(wsf + 2097152);
    us*    hp1_bf   = h_bf   + 2097152;            // 524,288
    us*    hp2_bf   = hp1_bf + 524288;             // 131,072
    us*    emb0_bf  = hp2_bf + 131072;             // 2048x1024 (2000 real)
    us*    emb1_bf  = emb0_bf + 2097152;           // 6144x256  (6000 real)
    us*    emb2_bf  = emb1_bf + 1572864;           // 24064x64  (24000 real)
    us*    proj1_bf = emb2_bf + 1540096;           // 256x1024
    us*    proj2_bf = proj1_bf + 262144;           // 64x1024
    float* bqkv     = (float*)(proj2_bf + 65536);  // 12*3072 f
    us*    wqkv_all = (us*)(bqkv + 36864);         // [12][3072][1024]
    us*    wr_all   = wqkv_all + (long)NL * 3072 * 1024;
    us*    wo_all   = wr_all   + (long)NL * 1024 * 1024;
    us*    w1_all   = wo_all   + (long)NL * 1024 * 1024;   // [12][4096][1024]
    us*    w2_all   = w1_all   + (long)NL * 4096 * 1024;   // [12][1024][4096]
    const bool big  = ws_size >= (size_t)352273408;        // full weight cache fits

    // ---- one-time setup ----
    bcat_k<<<144, 256, 0, stream>>>(bq, bk, bv, bqkv);
    conv_k<<<2000, 256, 0, stream>>>(emb0,  emb0_bf,  2048000);
    conv_k<<<1500, 256, 0, stream>>>(emb1,  emb1_bf,  1536000);
    conv_k<<<1500, 256, 0, stream>>>(emb2,  emb2_bf,  1536000);
    conv_k<<<256,  256, 0, stream>>>(proj1, proj1_bf, 262144);
    conv_k<<<64,   256, 0, stream>>>(proj2, proj2_bf, 65536);
    pemb_k<<<NT, 256, 0, stream>>>(pemb_bf);
    rkpad12_k<<<384, 256, 0, stream>>>(rk_all);
    embed_k<<<NBT, 256, 0, stream>>>(x, emb0, emb1, emb2, proj1, proj2, h);
    if (big) {   // batched all-layer weight transpose-convert (7 launches)
        tconv_k<<<dim3(32, 32, NL), 256, 0, stream>>>(Wq, wqkv_all,           1024, 1024, 1048576, 3145728);
        tconv_k<<<dim3(32, 32, NL), 256, 0, stream>>>(Wk, wqkv_all + 1048576, 1024, 1024, 1048576, 3145728);
        tconv_k<<<dim3(32, 32, NL), 256, 0, stream>>>(Wv, wqkv_all + 2097152, 1024, 1024, 1048576, 3145728);
        tconv_k<<<dim3(32, 32, NL), 256, 0, stream>>>(Wr, wr_all, 1024, 1024, 1048576, 1048576);
        tconv_k<<<dim3(32, 32, NL), 256, 0, stream>>>(Wo, wo_all, 1024, 1024, 1048576, 1048576);
        tconv_k<<<dim3(128, 32, NL), 256, 0, stream>>>(W1, w1_all, 1024, 4096, 4194304, 4194304);
        tconv_k<<<dim3(32, 128, NL), 256, 0, stream>>>(W2, w2_all, 4096, 1024, 4194304, 4194304);
        // batched r_k for all layers: rk_all[l] = pemb @ Wr[l]
        bgemm_k<64, 64, 0, true><<<dim3(16, 8, NL), 256, 0, stream>>>(
            pemb_bf, wr_all, rk_all, nullptr, nullptr, nullptr, nullptr, nullptr,
            1024, 1024, 1024, 1024, 1024,
            1, 0, 0, 1048576, 0, RKL, 0);
    }

    for (int l = 0; l < NL; ++l) {
        const us* wqkv_t = big ? wqkv_all + (long)l * 3145728 : wqkv_sc;
        const us* wo_t   = big ? wo_all   + (long)l * 1048576 : wo_sc;
        const us* w1_t   = big ? w1_all   + (long)l * 4194304 : w1_sc;
        const us* w2_t   = big ? w2_all   + (long)l * 4194304 : w2_sc;
        if (!big) {
            const long wOff = (long)l * ND * ND;
            tconv_k<<<dim3(32, 32), 256, 0, stream>>>(Wq + wOff, wqkv_sc,           1024, 1024, 0, 0);
            tconv_k<<<dim3(32, 32), 256, 0, stream>>>(Wk + wOff, wqkv_sc + 1048576, 1024, 1024, 0, 0);
            tconv_k<<<dim3(32, 32), 256, 0, stream>>>(Wv + wOff, wqkv_sc + 2097152, 1024, 1024, 0, 0);
            tconv_k<<<dim3(32, 32), 256, 0, stream>>>(Wr + wOff, wr_sc, 1024, 1024, 0, 0);
            tconv_k<<<dim3(32, 32), 256, 0, stream>>>(Wo + wOff, wo_sc, 1024, 1024, 0, 0);
            tconv_k<<<dim3(128, 32), 256, 0, stream>>>(W1 + (long)l * ND * NF, w1_sc, 1024, 4096, 0, 0);
            tconv_k<<<dim3(32, 128), 256, 0, stream>>>(W2 + (long)l * ND * NF, w2_sc, 4096, 1024, 0, 0);
            bgemm_k<64, 64, 0, true><<<dim3(16, 8, 1), 256, 0, stream>>>(
                pemb_bf, wr_sc, rk_all + (long)l * RKL, nullptr, nullptr, nullptr, nullptr, nullptr,
                1024, 1024, 1024, 1024, 1024, 0, 0, 0, 0, 0, 0, 0);
        }

        // pre-norm 1 -> bf16
        ln_k<<<NBT, 256, 0, stream>>>(h, ain_bf, ln1s + l * ND, ln1b + l * ND);
        // fused QKV (EPI=3): qw,qr,k into qkvbuf; v straight into vt
        bgemm_k<128, 64, 3, true><<<dim3(48, 16, 1), 256, 0, stream>>>(
            ain_bf, wqkv_t, qkvbuf, bqkv + l * 3072, nullptr, rwb, rrb, vt_bf,
            3072, 1024, 1024, 1024, 1024, 0, 0, 0, 0, 0, 0, 0);
        // fused attention: scores + rel_shift + causal softmax + PV
        fattn_k<<<dim3(8, NB * NH), 256, 0, stream>>>(
            qkvbuf, vt_bf, rk_all + (long)l * RKL, o_bf);
        // h += o @ Wo + bo (fp32 residual)
        bgemm_k<64, 64, 0, false><<<dim3(16, 32, 1), 256, 0, stream>>>(
            o_bf, wo_t, h, bo + l * ND, h, nullptr, nullptr, nullptr,
            1024, 1024, 1024, 1024, 1024, 0, 0, 0, 0, 0, 0, 0);

        // FFN
        ln_k<<<NBT, 256, 0, stream>>>(h, ain_bf, ln2s + l * ND, ln2b + l * ND);
        bgemm_k<128, 128, 1, true><<<dim3(32, 16, 1), 256, 0, stream>>>(
            ain_bf, w1_t, mid_bf, b1 + (long)l * NF, nullptr, nullptr, nullptr, nullptr,
            4096, 1024, 1024, 1024, 4096, 0, 0, 0, 0, 0, 0, 0);
        bgemm_k<64, 64, 0, false><<<dim3(16, 32, 1), 256, 0, stream>>>(
            mid_bf, w2_t, h, b2 + l * ND, h, nullptr, nullptr, nullptr,
            1024, 4096, 4096, 4096, 1024, 0, 0, 0, 0, 0, 0, 0);
    }

    // ---- tied adaptive-softmax output: (h @ proj^T) @ emb^T ----
    conv_k<<<2048, 256, 0, stream>>>(h, h_bf, (long)NBT * ND);
    // cluster 0: cols [0,2000)
    bgemm_k<128, 64, 0, false><<<dim3(32, 16, 1), 256, 0, stream>>>(
        h_bf, emb0_bf, out, obias, nullptr, nullptr, nullptr, nullptr,
        2000, 1024, 1024, 1024, NV, 0, 0, 0, 0, 0, 0, 0);
    // cluster 1: hp1 = h @ proj1^T ; cols [2000,8000)
    bgemm_k<64, 64, 0, true><<<dim3(4, 32, 1), 256, 0, stream>>>(
        h_bf, proj1_bf, hp1_bf, nullptr, nullptr, nullptr, nullptr, nullptr,
        256, 1024, 1024, 1024, 256, 0, 0, 0, 0, 0, 0, 0);
    bgemm_k<128, 128, 0, false><<<dim3(47, 16, 1), 256, 0, stream>>>(
        hp1_bf, emb1_bf, out + 2000, obias + 2000, nullptr, nullptr, nullptr, nullptr,
        6000, 256, 256, 256, NV, 0, 0, 0, 0, 0, 0, 0);
    // cluster 2: hp2 = h @ proj2^T ; cols [8000,32000)
    bgemm_k<64, 64, 0, true><<<dim3(1, 32, 1), 256, 0, stream>>>(
        h_bf, proj2_bf, hp2_bf, nullptr, nullptr, nullptr, nullptr, nullptr,
        64, 1024, 1024, 1024, 64, 0, 0, 0, 0, 0, 0, 0);
    bgemm_k<128, 128, 0, false><<<dim3(188, 16, 1), 256, 0, stream>>>(
        hp2_bf, emb2_bf, out + 8000, obias + 8000, nullptr, nullptr, nullptr, nullptr,
        24000, 64, 64, 64, NV, 0, 0, 0, 0, 0, 0, 0);
}

// Round 9
// 2571.603 us; speedup vs baseline: 7.4833x; 1.1193x over previous
//
#include <hip/hip_runtime.h>

using us = unsigned short;
typedef short short8v __attribute__((ext_vector_type(8)));
typedef float float4v __attribute__((ext_vector_type(4)));

// ---------------- problem constants ----------------
constexpr int NB  = 4;
constexpr int NT  = 512;
constexpr int ND  = 1024;
constexpr int NL  = 12;
constexpr int NH  = 16;
constexpr int NF  = 4096;
constexpr int NHD = 64;
constexpr int NBT = NB * NT;   // 2048
constexpr int NV  = 32000;
constexpr long QOFF = (long)NBT * ND;  // qw|qr|k stride in qkvbuf
constexpr long RKL  = 640L * 1024;     // per-layer rk stride (rows 512.. are zero pad)

__device__ __forceinline__ us f2bf(float f) {
    unsigned u = __float_as_uint(f);
    u += 0x7fffu + ((u >> 16) & 1u);      // RNE
    return (us)(u >> 16);
}

// async global->LDS, 16B per lane. LDS dest is wave-uniform base + lane*16;
// global src is per-lane (pre-swizzled for bank-conflict-free ds_read).
__device__ __forceinline__ void gload16(const us* g, us* l) {
    __builtin_amdgcn_global_load_lds(
        (const __attribute__((address_space(1))) void*)g,
        (__attribute__((address_space(3))) void*)l, 16, 0, 0);
}

// =====================================================================
// bf16 MFMA GEMM:  C[M,N] = A[M,K] @ B[N,K]^T   (both row-major, k-contig)
// 256 threads = 4 waves (2x2), per-wave tile (BM/2)x(BN/2), BK=64.
// TWO-PHASE double-buffered staging: issue global_load_lds for tile k+1
// into buf^1, then ds_read+MFMA on buf, then one __syncthreads() (vmcnt
// drain lands after the MFMA -> HBM latency hidden), flip.
// EPI: 0 plain (+bias,+addsrc), 1 gelu, 3 fused QKV epilogue:
//      seg0 -> qw,qr (+r_w/r_r bias), seg1 -> k, seg2 -> vt[b,h,d,t] packed.
// =====================================================================
template<int BM, int BN, int EPI, bool OUTBF>
__global__ __launch_bounds__(256)
void bgemm_k(const us* __restrict__ A, const us* __restrict__ B, void* Cv,
             const float* __restrict__ bias, const float* addsrc,
             const float* __restrict__ p0, const float* __restrict__ p1,
             us* __restrict__ vtp,
             int N, int K, int lda, int ldb, int ldc,
             int bdiv, long sAb, long sAh, long sBb, long sBh, long sCb, long sCh)
{
    constexpr int BK  = 64;
    constexpr int WTM = BM / 2, WTN = BN / 2;
    constexpr int FM  = WTM / 16, FN = WTN / 16;
    constexpr int AI  = BM / 32;       // gload16 instr per wave (A tile)
    constexpr int BI  = BN / 32;
    static_assert(BM % 32 == 0 && BN % 32 == 0, "");

    long coff = 0;
    if (bdiv > 0) {
        int z = blockIdx.z, zb = z / bdiv, zh = z % bdiv;
        A += zb * sAb + zh * sAh;
        B += zb * sBb + zh * sBh;
        coff = zb * sCb + zh * sCh;
    }
    float* Cf = (float*)Cv + coff;
    us*    Ch = (us*)Cv + coff;
    if (addsrc) addsrc += coff;

    __shared__ __align__(16) us As[2 * BM * BK];
    __shared__ __align__(16) us Bs[2 * BN * BK];

    const int tid  = threadIdx.x;
    const int lane = tid & 63;
    const int w    = tid >> 6;
    const int wm   = w >> 1;
    const int wn   = w & 1;
    const int row0 = blockIdx.y * BM;
    const int col0 = blockIdx.x * BN;

    float4v acc[FM][FN];
#pragma unroll
    for (int i = 0; i < FM; ++i)
#pragma unroll
        for (int j = 0; j < FN; ++j) acc[i][j] = (float4v)0.f;

    auto stage = [&](int buf, int k0) {
        us* Ad = As + buf * (BM * BK);
        us* Bd = Bs + buf * (BN * BK);
#pragma unroll
        for (int i = 0; i < AI; ++i) {
            int rb = w * (BM / 4) + i * 8;
            int r  = rb + (lane >> 3);
            int sc8 = ((lane & 7) ^ (r & 7)) << 3;
            gload16(A + (long)(row0 + r) * lda + k0 + sc8, Ad + rb * 64);
        }
#pragma unroll
        for (int i = 0; i < BI; ++i) {
            int rb = w * (BN / 4) + i * 8;
            int r  = rb + (lane >> 3);
            int sc8 = ((lane & 7) ^ (r & 7)) << 3;
            gload16(B + (long)(col0 + r) * ldb + k0 + sc8, Bd + rb * 64);
        }
    };

    stage(0, 0);
    __syncthreads();           // buf0 staged (vmcnt drained)
    int cur = 0;
    for (int k0 = 0; k0 < K; k0 += BK) {
        if (k0 + BK < K) stage(cur ^ 1, k0 + BK);   // prefetch next tile
        const char* Ac = (const char*)(As + cur * (BM * BK));
        const char* Bc = (const char*)(Bs + cur * (BN * BK));
#pragma unroll
        for (int ks = 0; ks < 2; ++ks) {
            short8v af[FM], bfr[FN];
            int sw = ks * 4 + (lane >> 4);
#pragma unroll
            for (int i = 0; i < FM; ++i) {
                int r = wm * WTM + i * 16 + (lane & 15);
                af[i] = *reinterpret_cast<const short8v*>(Ac + r * 128 + ((sw ^ (r & 7)) << 4));
            }
#pragma unroll
            for (int j = 0; j < FN; ++j) {
                int r = wn * WTN + j * 16 + (lane & 15);
                bfr[j] = *reinterpret_cast<const short8v*>(Bc + r * 128 + ((sw ^ (r & 7)) << 4));
            }
#pragma unroll
            for (int i = 0; i < FM; ++i)
#pragma unroll
                for (int j = 0; j < FN; ++j)
                    acc[i][j] = __builtin_amdgcn_mfma_f32_16x16x32_bf16(af[i], bfr[j], acc[i][j], 0, 0, 0);
        }
        __syncthreads();       // next tile staged; all waves done reading cur
        cur ^= 1;
    }

    // ---- epilogue.  D layout: col = lane&15, row = (lane>>4)*4 + reg ----
#pragma unroll
    for (int i = 0; i < FM; ++i) {
        int growb = row0 + wm * WTM + i * 16 + ((lane >> 4) << 2);
#pragma unroll
        for (int j = 0; j < FN; ++j) {
            int gcol = col0 + wn * WTN + j * 16 + (lane & 15);
            if (EPI == 3) {
                int seg = gcol >> 10, c = gcol & 1023;
                float bb = bias[gcol];
                if (seg == 2) {
                    // v -> vt[b,h,d,t], 4 consecutive t packed into 8B
                    unsigned lo = (unsigned)f2bf(acc[i][j][0] + bb)
                                | ((unsigned)f2bf(acc[i][j][1] + bb) << 16);
                    unsigned hi = (unsigned)f2bf(acc[i][j][2] + bb)
                                | ((unsigned)f2bf(acc[i][j][3] + bb) << 16);
                    int bidx = growb >> 9, tb = growb & 511;
                    uint2 pk; pk.x = lo; pk.y = hi;
                    *reinterpret_cast<uint2*>(
                        vtp + ((long)((bidx * 16 + (c >> 6)) * 64 + (c & 63)) << 9) + tb) = pk;
                } else {
                    us* base = (us*)Cv;
#pragma unroll
                    for (int r = 0; r < 4; ++r) {
                        int gr = growb + r;
                        float v = acc[i][j][r] + bb;
                        long o = (long)gr * 1024 + c;
                        if (seg == 0) {
                            base[o]        = f2bf(v + p0[c]);   // qw
                            base[o + QOFF] = f2bf(v + p1[c]);   // qr
                        } else base[o + 2 * QOFF] = f2bf(v);    // k
                    }
                }
            } else {
                if (gcol >= N) continue;
#pragma unroll
                for (int r = 0; r < 4; ++r) {
                    int gr = growb + r;
                    float v = acc[i][j][r];
                    if (bias) v += bias[gcol];
                    if (EPI == 1) {
                        float xx = v;
                        v = 0.5f * xx * (1.f + tanhf(0.7978845608028654f
                                                     * (xx + 0.044715f * xx * xx * xx)));
                    }
                    if (addsrc) v += addsrc[(long)gr * ldc + gcol];
                    if (OUTBF) Ch[(long)gr * ldc + gcol] = f2bf(v);
                    else       Cf[(long)gr * ldc + gcol] = v;
                }
            }
        }
    }
}

// =====================================================================
// FFN2 split-K reduce: h += b2 + sum_z part[z]   (2048x1024 fp32)
// =====================================================================
__global__ __launch_bounds__(256)
void ffnred_k(const float* __restrict__ part, const float* __restrict__ b2v,
              float* __restrict__ h)
{
    long i = ((long)blockIdx.x * 256 + threadIdx.x) * 4;
    float4 a0 = *reinterpret_cast<const float4*>(part + i);
    float4 a1 = *reinterpret_cast<const float4*>(part + i + 2097152);
    float4 a2 = *reinterpret_cast<const float4*>(part + i + 4194304);
    float4 a3 = *reinterpret_cast<const float4*>(part + i + 6291456);
    float4 hv = *reinterpret_cast<const float4*>(h + i);
    float4 bb = *reinterpret_cast<const float4*>(b2v + (int)(i & 1023));
    hv.x += a0.x + a1.x + a2.x + a3.x + bb.x;
    hv.y += a0.y + a1.y + a2.y + a3.y + bb.y;
    hv.z += a0.z + a1.z + a2.z + a3.z + bb.z;
    hv.w += a0.w + a1.w + a2.w + a3.w + bb.w;
    *reinterpret_cast<float4*>(h + i) = hv;
}

// =====================================================================
// Fused TXL attention with ROLLING rel band.  Block = (64-row q-tile, b*h),
// 4 waves x 16 q-rows.  logits(t,s) = (qw[t].k[s] + qr[t].rk[s+511-t])/8,
// causal, online softmax, O = P@V.  (unchanged from passing round 7)
// =====================================================================
__global__ __launch_bounds__(256)
void fattn_k(const us* __restrict__ qkv, const us* __restrict__ vt,
             const us* __restrict__ rk, us* __restrict__ obuf)
{
    __shared__ __align__(16) us lds_k[64 * 64];
    __shared__ __align__(16) us lds_v[64 * 64];
    __shared__ __align__(16) us lds_rk[64 * 64];
    __shared__ __align__(16) us lds_p[4 * 16 * 64];
    __shared__ float lds_r[4 * 16 * 132];       // per-wave R, row stride 132

    const int tid = threadIdx.x, lane = tid & 63, w = tid >> 6;
    const int qt = blockIdx.x, bh = blockIdx.y;
    const int b = bh >> 4, h = bh & 15;
    const int t0 = qt * 64;
    const int rg = lane >> 4, lc = lane & 15;

    const us* qwb = qkv + ((long)b * 512) * 1024 + h * 64;   // row stride 1024
    const us* qrb = qwb + QOFF;
    const us* kb  = qwb + 2 * QOFF;
    const us* vtb = vt + (long)bh * 64 * 512;                // rows d, stride 512
    const us* rkb = rk + h * 64;                             // rows j, stride 1024

    // Q fragments (rows t0 + w*16 + lc, k-slices kk*32 + rg*8)
    short8v aqw[2], aqr[2];
    {
        long qrow = (long)(t0 + w * 16 + lc) * 1024;
        int ko = rg * 8;
        aqw[0] = *(const short8v*)(qwb + qrow + ko);
        aqw[1] = *(const short8v*)(qwb + qrow + 32 + ko);
        aqr[0] = *(const short8v*)(qrb + qrow + ko);
        aqr[1] = *(const short8v*)(qrb + qrow + 32 + ko);
    }

    float4v oacc[4];
#pragma unroll
    for (int i = 0; i < 4; ++i) oacc[i] = (float4v)0.f;
    float mrow[4] = {-3e38f, -3e38f, -3e38f, -3e38f};
    float lrow[4] = {0.f, 0.f, 0.f, 0.f};

    float* rbase = lds_r + w * (16 * 132);
    us*    pbase = lds_p + w * (16 * 64);

    // stage one 64-row rk half starting at global row j0
    auto stage_rk = [&](int j0) {
#pragma unroll
        for (int i = 0; i < 2; ++i) {
            int rb = w * 16 + i * 8;
            int r  = rb + (lane >> 3);
            int sl = ((lane & 7) ^ (r & 7)) << 3;
            gload16(rkb + (long)(j0 + r) * 1024 + sl, lds_rk + rb * 64);
        }
    };
    // rel MFMA over the staged 64 rows -> R slots [wbase, wbase+64)
    auto rel_half = [&](int wbase) {
#pragma unroll
        for (int jn = 0; jn < 4; ++jn) {
            float4v rf = (float4v)0.f;
#pragma unroll
            for (int kk = 0; kk < 2; ++kk) {
                int r = jn * 16 + lc;
                int sw = kk * 4 + rg;
                short8v bf = *(const short8v*)((const char*)lds_rk + r * 128 + ((sw ^ (r & 7)) << 4));
                rf = __builtin_amdgcn_mfma_f32_16x16x32_bf16(aqr[kk], bf, rf, 0, 0, 0);
            }
#pragma unroll
            for (int pr = 0; pr < 4; ++pr)
                rbase[(rg * 4 + pr) * 132 + wbase + jn * 16 + lc] = rf[pr];
        }
    };

    const int nst = qt + 1;
    for (int st = 0; st < nst; ++st) {
        const int s0 = st * 64;
        const int jb = (st - qt) * 64 + 448;          // window base row (>=0)
        const int sb = ((st - qt + 7) & 1) << 6;      // window base slot

        // ---- stage K, V (every step) ----
#pragma unroll
        for (int i = 0; i < 2; ++i) {
            int rb = w * 16 + i * 8;
            int r  = rb + (lane >> 3);
            int sl = ((lane & 7) ^ (r & 7)) << 3;
            gload16(kb + (long)(s0 + r) * 1024 + sl, lds_k + rb * 64);
            gload16(vtb + (long)r * 512 + s0 + sl, lds_v + rb * 64);
        }
        if (st == 0) {
            stage_rk(jb);            // lower half
            __syncthreads();
            rel_half(sb);
            __syncthreads();         // all waves done with lds_rk
            stage_rk(jb + 64);       // upper half
            __syncthreads();
        } else {
            stage_rk(jb + 64);       // only the new upper half
            __syncthreads();
        }

        // ---- content scores (16 q-rows x 64 s) ----
        float4v sfr[4];
#pragma unroll
        for (int sn = 0; sn < 4; ++sn) {
            sfr[sn] = (float4v)0.f;
#pragma unroll
            for (int kk = 0; kk < 2; ++kk) {
                int r = sn * 16 + lc;
                int sw = kk * 4 + rg;
                short8v bf = *(const short8v*)((const char*)lds_k + r * 128 + ((sw ^ (r & 7)) << 4));
                sfr[sn] = __builtin_amdgcn_mfma_f32_16x16x32_bf16(aqw[kk], bf, sfr[sn], 0, 0, 0);
            }
        }
        rel_half(sb ^ 64);           // upper half of current window

        // ---- combine + shift + mask + online softmax ----
        float pv[4][4];
        float rmax[4] = {-3e38f, -3e38f, -3e38f, -3e38f};
#pragma unroll
        for (int pr = 0; pr < 4; ++pr) {
            int tt = rg * 4 + pr;
            int tw = w * 16 + tt;
#pragma unroll
            for (int sn = 0; sn < 4; ++sn) {
                int ss = sn * 16 + lc;
                int slot = (sb + ss + 63 - tw) & 127;
                float lg = (sfr[sn][pr] + rbase[tt * 132 + slot]) * 0.125f;
                if (ss > t0 - s0 + tw) lg = -1e30f;   // causal (active on diagonal)
                pv[sn][pr] = lg;
                rmax[pr] = fmaxf(rmax[pr], lg);
            }
        }
#pragma unroll
        for (int o = 1; o < 16; o <<= 1)
#pragma unroll
            for (int pr = 0; pr < 4; ++pr)
                rmax[pr] = fmaxf(rmax[pr], __shfl_xor(rmax[pr], o));
        float rsum[4];
#pragma unroll
        for (int pr = 0; pr < 4; ++pr) {
            float mn = fmaxf(mrow[pr], rmax[pr]);
            float al = __expf(mrow[pr] - mn);
            mrow[pr] = mn;
            lrow[pr] *= al;
            float s = 0.f;
#pragma unroll
            for (int sn = 0; sn < 4; ++sn) {
                float p = __expf(pv[sn][pr] - mn);
                pv[sn][pr] = p;
                s += p;
            }
            rsum[pr] = s;
#pragma unroll
            for (int dn = 0; dn < 4; ++dn) oacc[dn][pr] *= al;
        }
#pragma unroll
        for (int o = 1; o < 16; o <<= 1)
#pragma unroll
            for (int pr = 0; pr < 4; ++pr)
                rsum[pr] += __shfl_xor(rsum[pr], o);
#pragma unroll
        for (int pr = 0; pr < 4; ++pr) lrow[pr] += rsum[pr];

        // ---- P -> per-wave LDS (bf16, swizzled for A-frag reads) ----
#pragma unroll
        for (int pr = 0; pr < 4; ++pr) {
            int row = rg * 4 + pr;
#pragma unroll
            for (int sn = 0; sn < 4; ++sn) {
                int col = sn * 16 + lc;
                *(us*)((char*)pbase + row * 128 + (((col >> 3) ^ (row & 7)) << 4) + (col & 7) * 2)
                    = f2bf(pv[sn][pr]);
            }
        }
        // ---- PV accumulate ----
        short8v pa[2];
#pragma unroll
        for (int kk = 0; kk < 2; ++kk)
            pa[kk] = *(const short8v*)((const char*)pbase + lc * 128 + (((kk * 4 + rg) ^ (lc & 7)) << 4));
#pragma unroll
        for (int dn = 0; dn < 4; ++dn) {
#pragma unroll
            for (int kk = 0; kk < 2; ++kk) {
                int r = dn * 16 + lc;
                int sw = kk * 4 + rg;
                short8v vb = *(const short8v*)((const char*)lds_v + r * 128 + ((sw ^ (r & 7)) << 4));
                oacc[dn] = __builtin_amdgcn_mfma_f32_16x16x32_bf16(pa[kk], vb, oacc[dn], 0, 0, 0);
            }
        }
        __syncthreads();   // all waves done with lds_k/v/rk before next stage
    }
    // ---- normalize + store ----
#pragma unroll
    for (int pr = 0; pr < 4; ++pr) {
        int t = t0 + w * 16 + rg * 4 + pr;
        float inv = 1.f / lrow[pr];
        long rowo = ((long)b * 512 + t) * 1024 + h * 64;
#pragma unroll
        for (int dn = 0; dn < 4; ++dn)
            obuf[rowo + dn * 16 + lc] = f2bf(oacc[dn][pr] * inv);
    }
}

// =====================================================================
// Transpose-convert: fp32 in[R][C] -> bf16 out[C][R], optional layer batch
// =====================================================================
__global__ __launch_bounds__(256)
void tconv_k(const float* __restrict__ in, us* __restrict__ out, int R, int C,
             long inL, long outL)
{
    in  += (long)blockIdx.z * inL;
    out += (long)blockIdx.z * outL;
    __shared__ float t[32][33];
    int c0 = blockIdx.x * 32, r0 = blockIdx.y * 32;
    int tx = threadIdx.x & 31, ty = threadIdx.x >> 5;
#pragma unroll
    for (int j = 0; j < 4; ++j)
        t[ty + j * 8][tx] = in[(long)(r0 + ty + j * 8) * C + c0 + tx];
    __syncthreads();
#pragma unroll
    for (int j = 0; j < 4; ++j)
        out[(long)(c0 + ty + j * 8) * R + r0 + tx] = f2bf(t[tx][ty + j * 8]);
}

// flat fp32 -> bf16 (n % 4 == 0)
__global__ __launch_bounds__(256)
void conv_k(const float* __restrict__ in, us* __restrict__ out, long n)
{
    long i = ((long)blockIdx.x * 256 + threadIdx.x) * 4;
    if (i >= n) return;
    float4 v = *reinterpret_cast<const float4*>(in + i);
    uint2 p;
    p.x = (unsigned)f2bf(v.x) | ((unsigned)f2bf(v.y) << 16);
    p.y = (unsigned)f2bf(v.z) | ((unsigned)f2bf(v.w) << 16);
    *reinterpret_cast<uint2*>(out + i) = p;
}

// zero rk pad rows [512,640) for all 12 layers
__global__ __launch_bounds__(256)
void rkpad12_k(us* __restrict__ rk)
{
    int i = blockIdx.x * 256 + threadIdx.x;   // 98304 uint4 total
    int l = i >> 13, r = i & 8191;
    reinterpret_cast<uint4*>(rk + (long)l * RKL + 512 * 1024)[r] = make_uint4(0, 0, 0, 0);
}

// concat per-layer qkv biases: bqkv[l][3072] = [bq|bk|bv]
__global__ __launch_bounds__(256)
void bcat_k(const float* __restrict__ bq, const float* __restrict__ bk,
            const float* __restrict__ bv, float* __restrict__ o)
{
    int i = blockIdx.x * 256 + threadIdx.x;       // 12*3072
    int l = i / 3072, rr = i % 3072, seg = rr >> 10, c = rr & 1023;
    const float* s = seg == 0 ? bq : seg == 1 ? bk : bv;
    o[i] = s[l * 1024 + c];
}

// =====================================================================
// LayerNorm D=1024 fp32 -> bf16, one block/row
// =====================================================================
__global__ __launch_bounds__(256)
void ln_k(const float* __restrict__ x, us* __restrict__ y,
          const float* __restrict__ sc, const float* __restrict__ bi)
{
    int row = blockIdx.x;
    const float* xr = x + (long)row * ND;
    int d4 = threadIdx.x * 4;
    float4 v = *reinterpret_cast<const float4*>(&xr[d4]);
    float sum = v.x + v.y + v.z + v.w;
    float sq  = v.x * v.x + v.y * v.y + v.z * v.z + v.w * v.w;
#pragma unroll
    for (int o = 32; o; o >>= 1) { sum += __shfl_xor(sum, o); sq += __shfl_xor(sq, o); }
    __shared__ float red[8];
    int w = threadIdx.x >> 6;
    if ((threadIdx.x & 63) == 0) { red[w] = sum; red[4 + w] = sq; }
    __syncthreads();
    sum = red[0] + red[1] + red[2] + red[3];
    sq  = red[4] + red[5] + red[6] + red[7];
    float mean = sum * (1.f / ND);
    float var  = fmaxf(sq * (1.f / ND) - mean * mean, 0.f);
    float inv  = rsqrtf(var + 1e-5f);
    float4 s4 = *reinterpret_cast<const float4*>(&sc[d4]);
    float4 b4 = *reinterpret_cast<const float4*>(&bi[d4]);
    uint2 p;
    p.x = (unsigned)f2bf((v.x - mean) * inv * s4.x + b4.x)
        | ((unsigned)f2bf((v.y - mean) * inv * s4.y + b4.y) << 16);
    p.y = (unsigned)f2bf((v.z - mean) * inv * s4.z + b4.z)
        | ((unsigned)f2bf((v.w - mean) * inv * s4.w + b4.w) << 16);
    *reinterpret_cast<uint2*>(y + (long)row * ND + d4) = p;
}

// sinusoid pos-emb (TXL order), bf16 out
__global__ __launch_bounds__(256)
void pemb_k(us* __restrict__ p)
{
    int t = blockIdx.x;
    float pos = (float)(NT - 1 - t);
    for (int j = threadIdx.x; j < ND / 2; j += 256) {
        float invf = expf(-(float)j * (9.210340371976184f / 512.0f));
        float ang  = pos * invf;
        p[(long)t * ND + j]           = f2bf(sinf(ang));
        p[(long)t * ND + ND / 2 + j]  = f2bf(cosf(ang));
    }
}

// adaptive input embedding -> h fp32
__global__ __launch_bounds__(256)
void embed_k(const int* __restrict__ x,
             const float* __restrict__ e0, const float* __restrict__ e1,
             const float* __restrict__ e2, const float* __restrict__ p1,
             const float* __restrict__ p2, float* __restrict__ h)
{
    __shared__ float e[256];
    int tok = blockIdx.x;
    int v = x[tok];
    float* outp = h + (long)tok * ND;
    if (v < 2000) {
        const float* r = e0 + (long)v * ND;
        for (int d = threadIdx.x; d < ND; d += 256) outp[d] = r[d] * 32.0f;
    } else if (v < 8000) {
        const float* r = e1 + (long)(v - 2000) * 256;
        e[threadIdx.x] = r[threadIdx.x];
        __syncthreads();
        for (int d = threadIdx.x; d < ND; d += 256) {
            float acc = 0.f;
#pragma unroll 4
            for (int i = 0; i < 256; ++i) acc += e[i] * p1[(long)i * ND + d];
            outp[d] = acc * 32.0f;
        }
    } else {
        const float* r = e2 + (long)(v - 8000) * 64;
        if (threadIdx.x < 64) e[threadIdx.x] = r[threadIdx.x];
        __syncthreads();
        for (int d = threadIdx.x; d < ND; d += 256) {
            float acc = 0.f;
#pragma unroll 4
            for (int i = 0; i < 64; ++i) acc += e[i] * p2[(long)i * ND + d];
            outp[d] = acc * 32.0f;
        }
    }
}

// ---------------------------------------------------------------- host
extern "C" void kernel_launch(void* const* d_in, const int* in_sizes, int n_in,
                              void* d_out, int out_size, void* d_ws, size_t ws_size,
                              hipStream_t stream)
{
    (void)in_sizes; (void)n_in; (void)out_size;
    const int*   x     = (const int*)  d_in[0];
    const float* emb0  = (const float*)d_in[1];
    const float* emb1  = (const float*)d_in[2];
    const float* emb2  = (const float*)d_in[3];
    const float* proj1 = (const float*)d_in[4];
    const float* proj2 = (const float*)d_in[5];
    const float* obias = (const float*)d_in[6];
    const float* rwb   = (const float*)d_in[7];
    const float* rrb   = (const float*)d_in[8];
    const float* ln1s  = (const float*)d_in[9];
    const float* ln1b  = (const float*)d_in[10];
    const float* Wq    = (const float*)d_in[11];
    const float* bq    = (const float*)d_in[12];
    const float* Wk    = (const float*)d_in[13];
    const float* bk    = (const float*)d_in[14];
    const float* Wv    = (const float*)d_in[15];
    const float* bv    = (const float*)d_in[16];
    const float* Wr    = (const float*)d_in[17];
    const float* Wo    = (const float*)d_in[18];
    const float* bo    = (const float*)d_in[19];
    const float* ln2s  = (const float*)d_in[20];
    const float* ln2b  = (const float*)d_in[21];
    const float* W1    = (const float*)d_in[22];
    const float* b1    = (const float*)d_in[23];
    const float* W2    = (const float*)d_in[24];
    const float* b2    = (const float*)d_in[25];
    float* out = (float*)d_out;

    // ---- d_out scratch (us-unit offsets); all dead before vocab GEMMs ----
    us* ob      = (us*)out;
    us* qkvbuf  = ob;                 // 6,291,456  (qw|qr|k)
    us* mid_bf  = ob +  6291456;      // 8,388,608  [2048][4096]
    us* vt_bf   = ob + 14680064;      // 2,097,152  [64][64][512]
    us* o_bf    = ob + 16777216;      // 2,097,152  [2048][1024]
    us* ain_bf  = ob + 18874368;      // 2,097,152  [2048][1024]
    us* rk_all  = ob + 20971520;      // 7,864,320  [12][640][1024] (pad rows zero)
    us* pemb_bf = ob + 28835840;      //   524,288  [512][1024]
    // fallback per-layer weight scratch (only used if ws too small)
    us* wqkv_sc = ob + 29360128;      // 3,145,728
    us* wr_sc   = ob + 32505856;      // 1,048,576
    us* wo_sc   = ob + 33554432;      // 1,048,576
    us* w1_sc   = ob + 34603008;      // 4,194,304
    us* w2_sc   = ob + 38797312;      // 4,194,304  (ends 42,991,616 us)
    float* pffn = out + 21495808;     // 8,388,608 f: [4][2048][1024] fp32 partials

    // ---- d_ws layout ----
    float* wsf      = (float*)d_ws;
    float* h        = wsf;                         // 2,097,152 f
    us*    h_bf     = (us*)(wsf + 2097152);
    us*    hp1_bf   = h_bf   + 2097152;            // 524,288
    us*    hp2_bf   = hp1_bf + 524288;             // 131,072
    us*    emb0_bf  = hp2_bf + 131072;             // 2048x1024 (2000 real)
    us*    emb1_bf  = emb0_bf + 2097152;           // 6144x256  (6000 real)
    us*    emb2_bf  = emb1_bf + 1572864;           // 24064x64  (24000 real)
    us*    proj1_bf = emb2_bf + 1540096;           // 256x1024
    us*    proj2_bf = proj1_bf + 262144;           // 64x1024
    float* bqkv     = (float*)(proj2_bf + 65536);  // 12*3072 f
    us*    wqkv_all = (us*)(bqkv + 36864);         // [12][3072][1024]
    us*    wr_all   = wqkv_all + (long)NL * 3072 * 1024;
    us*    wo_all   = wr_all   + (long)NL * 1024 * 1024;
    us*    w1_all   = wo_all   + (long)NL * 1024 * 1024;   // [12][4096][1024]
    us*    w2_all   = w1_all   + (long)NL * 4096 * 1024;   // [12][1024][4096]
    const bool big  = ws_size >= (size_t)352273408;        // full weight cache fits

    // ---- one-time setup ----
    bcat_k<<<144, 256, 0, stream>>>(bq, bk, bv, bqkv);
    conv_k<<<2000, 256, 0, stream>>>(emb0,  emb0_bf,  2048000);
    conv_k<<<1500, 256, 0, stream>>>(emb1,  emb1_bf,  1536000);
    conv_k<<<1500, 256, 0, stream>>>(emb2,  emb2_bf,  1536000);
    conv_k<<<256,  256, 0, stream>>>(proj1, proj1_bf, 262144);
    conv_k<<<64,   256, 0, stream>>>(proj2, proj2_bf, 65536);
    pemb_k<<<NT, 256, 0, stream>>>(pemb_bf);
    rkpad12_k<<<384, 256, 0, stream>>>(rk_all);
    embed_k<<<NBT, 256, 0, stream>>>(x, emb0, emb1, emb2, proj1, proj2, h);
    if (big) {   // batched all-layer weight transpose-convert (7 launches)
        tconv_k<<<dim3(32, 32, NL), 256, 0, stream>>>(Wq, wqkv_all,           1024, 1024, 1048576, 3145728);
        tconv_k<<<dim3(32, 32, NL), 256, 0, stream>>>(Wk, wqkv_all + 1048576, 1024, 1024, 1048576, 3145728);
        tconv_k<<<dim3(32, 32, NL), 256, 0, stream>>>(Wv, wqkv_all + 2097152, 1024, 1024, 1048576, 3145728);
        tconv_k<<<dim3(32, 32, NL), 256, 0, stream>>>(Wr, wr_all, 1024, 1024, 1048576, 1048576);
        tconv_k<<<dim3(32, 32, NL), 256, 0, stream>>>(Wo, wo_all, 1024, 1024, 1048576, 1048576);
        tconv_k<<<dim3(128, 32, NL), 256, 0, stream>>>(W1, w1_all, 1024, 4096, 4194304, 4194304);
        tconv_k<<<dim3(32, 128, NL), 256, 0, stream>>>(W2, w2_all, 4096, 1024, 4194304, 4194304);
        // batched r_k for all layers: rk_all[l] = pemb @ Wr[l]
        bgemm_k<64, 64, 0, true><<<dim3(16, 8, NL), 256, 0, stream>>>(
            pemb_bf, wr_all, rk_all, nullptr, nullptr, nullptr, nullptr, nullptr,
            1024, 1024, 1024, 1024, 1024,
            1, 0, 0, 1048576, 0, RKL, 0);
    }

    for (int l = 0; l < NL; ++l) {
        const us* wqkv_t = big ? wqkv_all + (long)l * 3145728 : wqkv_sc;
        const us* wo_t   = big ? wo_all   + (long)l * 1048576 : wo_sc;
        const us* w1_t   = big ? w1_all   + (long)l * 4194304 : w1_sc;
        const us* w2_t   = big ? w2_all   + (long)l * 4194304 : w2_sc;
        if (!big) {
            const long wOff = (long)l * ND * ND;
            tconv_k<<<dim3(32, 32), 256, 0, stream>>>(Wq + wOff, wqkv_sc,           1024, 1024, 0, 0);
            tconv_k<<<dim3(32, 32), 256, 0, stream>>>(Wk + wOff, wqkv_sc + 1048576, 1024, 1024, 0, 0);
            tconv_k<<<dim3(32, 32), 256, 0, stream>>>(Wv + wOff, wqkv_sc + 2097152, 1024, 1024, 0, 0);
            tconv_k<<<dim3(32, 32), 256, 0, stream>>>(Wr + wOff, wr_sc, 1024, 1024, 0, 0);
            tconv_k<<<dim3(32, 32), 256, 0, stream>>>(Wo + wOff, wo_sc, 1024, 1024, 0, 0);
            tconv_k<<<dim3(128, 32), 256, 0, stream>>>(W1 + (long)l * ND * NF, w1_sc, 1024, 4096, 0, 0);
            tconv_k<<<dim3(32, 128), 256, 0, stream>>>(W2 + (long)l * ND * NF, w2_sc, 4096, 1024, 0, 0);
            bgemm_k<64, 64, 0, true><<<dim3(16, 8, 1), 256, 0, stream>>>(
                pemb_bf, wr_sc, rk_all + (long)l * RKL, nullptr, nullptr, nullptr, nullptr, nullptr,
                1024, 1024, 1024, 1024, 1024, 0, 0, 0, 0, 0, 0, 0);
        }

        // pre-norm 1 -> bf16
        ln_k<<<NBT, 256, 0, stream>>>(h, ain_bf, ln1s + l * ND, ln1b + l * ND);
        // fused QKV (EPI=3): qw,qr,k into qkvbuf; v straight into vt
        bgemm_k<128, 64, 3, true><<<dim3(48, 16, 1), 256, 0, stream>>>(
            ain_bf, wqkv_t, qkvbuf, bqkv + l * 3072, nullptr, rwb, rrb, vt_bf,
            3072, 1024, 1024, 1024, 1024, 0, 0, 0, 0, 0, 0, 0);
        // fused attention: scores + rel_shift + causal softmax + PV
        fattn_k<<<dim3(8, NB * NH), 256, 0, stream>>>(
            qkvbuf, vt_bf, rk_all + (long)l * RKL, o_bf);
        // h += o @ Wo + bo (fp32 residual)
        bgemm_k<64, 64, 0, false><<<dim3(16, 32, 1), 256, 0, stream>>>(
            o_bf, wo_t, h, bo + l * ND, h, nullptr, nullptr, nullptr,
            1024, 1024, 1024, 1024, 1024, 0, 0, 0, 0, 0, 0, 0);

        // FFN
        ln_k<<<NBT, 256, 0, stream>>>(h, ain_bf, ln2s + l * ND, ln2b + l * ND);
        bgemm_k<128, 128, 1, true><<<dim3(32, 16, 1), 256, 0, stream>>>(
            ain_bf, w1_t, mid_bf, b1 + (long)l * NF, nullptr, nullptr, nullptr, nullptr,
            4096, 1024, 1024, 1024, 4096, 0, 0, 0, 0, 0, 0, 0);
        // FFN2 split-K=4 at 128x128 tiles -> fp32 partials, then fused reduce
        bgemm_k<128, 128, 0, false><<<dim3(8, 16, 4), 256, 0, stream>>>(
            mid_bf, w2_t, pffn, nullptr, nullptr, nullptr, nullptr, nullptr,
            1024, 1024, 4096, 4096, 1024,
            1, 1024, 0, 1024, 0, 2097152, 0);
        ffnred_k<<<2048, 256, 0, stream>>>(pffn, b2 + (long)l * ND, h);
    }

    // ---- tied adaptive-softmax output: (h @ proj^T) @ emb^T ----
    conv_k<<<2048, 256, 0, stream>>>(h, h_bf, (long)NBT * ND);
    // cluster 0: cols [0,2000)
    bgemm_k<128, 64, 0, false><<<dim3(32, 16, 1), 256, 0, stream>>>(
        h_bf, emb0_bf, out, obias, nullptr, nullptr, nullptr, nullptr,
        2000, 1024, 1024, 1024, NV, 0, 0, 0, 0, 0, 0, 0);
    // cluster 1: hp1 = h @ proj1^T ; cols [2000,8000)
    bgemm_k<64, 64, 0, true><<<dim3(4, 32, 1), 256, 0, stream>>>(
        h_bf, proj1_bf, hp1_bf, nullptr, nullptr, nullptr, nullptr, nullptr,
        256, 1024, 1024, 1024, 256, 0, 0, 0, 0, 0, 0, 0);
    bgemm_k<128, 128, 0, false><<<dim3(47, 16, 1), 256, 0, stream>>>(
        hp1_bf, emb1_bf, out + 2000, obias + 2000, nullptr, nullptr, nullptr, nullptr,
        6000, 256, 256, 256, NV, 0, 0, 0, 0, 0, 0, 0);
    // cluster 2: hp2 = h @ proj2^T ; cols [8000,32000)
    bgemm_k<64, 64, 0, true><<<dim3(1, 32, 1), 256, 0, stream>>>(
        h_bf, proj2_bf, hp2_bf, nullptr, nullptr, nullptr, nullptr, nullptr,
        64, 1024, 1024, 1024, 64, 0, 0, 0, 0, 0, 0, 0);
    bgemm_k<128, 128, 0, false><<<dim3(188, 16, 1), 256, 0, stream>>>(
        hp2_bf, emb2_bf, out + 8000, obias + 8000, nullptr, nullptr, nullptr, nullptr,
        24000, 64, 64, 64, NV, 0, 0, 0, 0, 0, 0, 0);
}

// Round 10
// 2459.486 us; speedup vs baseline: 7.8245x; 1.0456x over previous
//
#include <hip/hip_runtime.h>

using us = unsigned short;
typedef short short8v __attribute__((ext_vector_type(8)));
typedef float float4v __attribute__((ext_vector_type(4)));

// ---------------- problem constants ----------------
constexpr int NB  = 4;
constexpr int NT  = 512;
constexpr int ND  = 1024;
constexpr int NL  = 12;
constexpr int NH  = 16;
constexpr int NF  = 4096;
constexpr int NHD = 64;
constexpr int NBT = NB * NT;   // 2048
constexpr int NV  = 32000;
constexpr long QOFF = (long)NBT * ND;  // qw|qr|k stride in qkvbuf
constexpr long RKL  = 640L * 1024;     // per-layer rk stride (rows 512.. are zero pad)

__device__ __forceinline__ us f2bf(float f) {
    unsigned u = __float_as_uint(f);
    u += 0x7fffu + ((u >> 16) & 1u);      // RNE
    return (us)(u >> 16);
}

// async global->LDS, 16B per lane. LDS dest is wave-uniform base + lane*16;
// global src is per-lane (pre-swizzled for bank-conflict-free ds_read).
__device__ __forceinline__ void gload16(const us* g, us* l) {
    __builtin_amdgcn_global_load_lds(
        (const __attribute__((address_space(1))) void*)g,
        (__attribute__((address_space(3))) void*)l, 16, 0, 0);
}

// =====================================================================
// bf16 MFMA GEMM:  C[M,N] = A[M,K] @ B[N,K]^T   (both row-major, k-contig)
// 256 threads = 4 waves (2x2), per-wave tile (BM/2)x(BN/2), BK=64.
// TWO-PHASE double-buffered staging (prefetch next tile under MFMA).
// EPI: 0 plain (+bias,+addsrc), 1 gelu, 3 fused QKV epilogue:
//      seg0 -> qw,qr (+r_w/r_r bias), seg1 -> k, seg2 -> vt[b,h,d,t] packed.
// =====================================================================
template<int BM, int BN, int EPI, bool OUTBF>
__global__ __launch_bounds__(256)
void bgemm_k(const us* __restrict__ A, const us* __restrict__ B, void* Cv,
             const float* __restrict__ bias, const float* addsrc,
             const float* __restrict__ p0, const float* __restrict__ p1,
             us* __restrict__ vtp,
             int N, int K, int lda, int ldb, int ldc,
             int bdiv, long sAb, long sAh, long sBb, long sBh, long sCb, long sCh)
{
    constexpr int BK  = 64;
    constexpr int WTM = BM / 2, WTN = BN / 2;
    constexpr int FM  = WTM / 16, FN = WTN / 16;
    constexpr int AI  = BM / 32;       // gload16 instr per wave (A tile)
    constexpr int BI  = BN / 32;
    static_assert(BM % 32 == 0 && BN % 32 == 0, "");

    long coff = 0;
    if (bdiv > 0) {
        int z = blockIdx.z, zb = z / bdiv, zh = z % bdiv;
        A += zb * sAb + zh * sAh;
        B += zb * sBb + zh * sBh;
        coff = zb * sCb + zh * sCh;
    }
    float* Cf = (float*)Cv + coff;
    us*    Ch = (us*)Cv + coff;
    if (addsrc) addsrc += coff;

    __shared__ __align__(16) us As[2 * BM * BK];
    __shared__ __align__(16) us Bs[2 * BN * BK];

    const int tid  = threadIdx.x;
    const int lane = tid & 63;
    const int w    = tid >> 6;
    const int wm   = w >> 1;
    const int wn   = w & 1;
    const int row0 = blockIdx.y * BM;
    const int col0 = blockIdx.x * BN;

    float4v acc[FM][FN];
#pragma unroll
    for (int i = 0; i < FM; ++i)
#pragma unroll
        for (int j = 0; j < FN; ++j) acc[i][j] = (float4v)0.f;

    auto stage = [&](int buf, int k0) {
        us* Ad = As + buf * (BM * BK);
        us* Bd = Bs + buf * (BN * BK);
#pragma unroll
        for (int i = 0; i < AI; ++i) {
            int rb = w * (BM / 4) + i * 8;
            int r  = rb + (lane >> 3);
            int sc8 = ((lane & 7) ^ (r & 7)) << 3;
            gload16(A + (long)(row0 + r) * lda + k0 + sc8, Ad + rb * 64);
        }
#pragma unroll
        for (int i = 0; i < BI; ++i) {
            int rb = w * (BN / 4) + i * 8;
            int r  = rb + (lane >> 3);
            int sc8 = ((lane & 7) ^ (r & 7)) << 3;
            gload16(B + (long)(col0 + r) * ldb + k0 + sc8, Bd + rb * 64);
        }
    };

    stage(0, 0);
    __syncthreads();           // buf0 staged (vmcnt drained)
    int cur = 0;
    for (int k0 = 0; k0 < K; k0 += BK) {
        if (k0 + BK < K) stage(cur ^ 1, k0 + BK);   // prefetch next tile
        const char* Ac = (const char*)(As + cur * (BM * BK));
        const char* Bc = (const char*)(Bs + cur * (BN * BK));
#pragma unroll
        for (int ks = 0; ks < 2; ++ks) {
            short8v af[FM], bfr[FN];
            int sw = ks * 4 + (lane >> 4);
#pragma unroll
            for (int i = 0; i < FM; ++i) {
                int r = wm * WTM + i * 16 + (lane & 15);
                af[i] = *reinterpret_cast<const short8v*>(Ac + r * 128 + ((sw ^ (r & 7)) << 4));
            }
#pragma unroll
            for (int j = 0; j < FN; ++j) {
                int r = wn * WTN + j * 16 + (lane & 15);
                bfr[j] = *reinterpret_cast<const short8v*>(Bc + r * 128 + ((sw ^ (r & 7)) << 4));
            }
#pragma unroll
            for (int i = 0; i < FM; ++i)
#pragma unroll
                for (int j = 0; j < FN; ++j)
                    acc[i][j] = __builtin_amdgcn_mfma_f32_16x16x32_bf16(af[i], bfr[j], acc[i][j], 0, 0, 0);
        }
        __syncthreads();       // next tile staged; all waves done reading cur
        cur ^= 1;
    }

    // ---- epilogue.  D layout: col = lane&15, row = (lane>>4)*4 + reg ----
#pragma unroll
    for (int i = 0; i < FM; ++i) {
        int growb = row0 + wm * WTM + i * 16 + ((lane >> 4) << 2);
#pragma unroll
        for (int j = 0; j < FN; ++j) {
            int gcol = col0 + wn * WTN + j * 16 + (lane & 15);
            if (EPI == 3) {
                int seg = gcol >> 10, c = gcol & 1023;
                float bb = bias[gcol];
                if (seg == 2) {
                    // v -> vt[b,h,d,t], 4 consecutive t packed into 8B
                    unsigned lo = (unsigned)f2bf(acc[i][j][0] + bb)
                                | ((unsigned)f2bf(acc[i][j][1] + bb) << 16);
                    unsigned hi = (unsigned)f2bf(acc[i][j][2] + bb)
                                | ((unsigned)f2bf(acc[i][j][3] + bb) << 16);
                    int bidx = growb >> 9, tb = growb & 511;
                    uint2 pk; pk.x = lo; pk.y = hi;
                    *reinterpret_cast<uint2*>(
                        vtp + ((long)((bidx * 16 + (c >> 6)) * 64 + (c & 63)) << 9) + tb) = pk;
                } else {
                    us* base = (us*)Cv;
#pragma unroll
                    for (int r = 0; r < 4; ++r) {
                        int gr = growb + r;
                        float v = acc[i][j][r] + bb;
                        long o = (long)gr * 1024 + c;
                        if (seg == 0) {
                            base[o]        = f2bf(v + p0[c]);   // qw
                            base[o + QOFF] = f2bf(v + p1[c]);   // qr
                        } else base[o + 2 * QOFF] = f2bf(v);    // k
                    }
                }
            } else {
                if (gcol >= N) continue;
#pragma unroll
                for (int r = 0; r < 4; ++r) {
                    int gr = growb + r;
                    float v = acc[i][j][r];
                    if (bias) v += bias[gcol];
                    if (EPI == 1) {
                        float xx = v;
                        v = 0.5f * xx * (1.f + tanhf(0.7978845608028654f
                                                     * (xx + 0.044715f * xx * xx * xx)));
                    }
                    if (addsrc) v += addsrc[(long)gr * ldc + gcol];
                    if (OUTBF) Ch[(long)gr * ldc + gcol] = f2bf(v);
                    else       Cf[(long)gr * ldc + gcol] = v;
                }
            }
        }
    }
}

// =====================================================================
// Fused split-K reduce + residual + (LN -> bf16 | bf16 convert).
//   h[row] += bias + sum_{z<NPART} part[z][row]
//   MODE 0: outb = bf16(LayerNorm(h_new, sc, bi))   (one block per row)
//   MODE 1: outb = bf16(h_new)
// =====================================================================
template<int NPART, int MODE>
__global__ __launch_bounds__(256)
void redln_k(const float* __restrict__ part, const float* __restrict__ bias,
             float* __restrict__ h, us* __restrict__ outb,
             const float* __restrict__ sc, const float* __restrict__ bi)
{
    int row = blockIdx.x;
    int d4 = threadIdx.x * 4;
    long i = (long)row * ND + d4;
    float4 hv = *reinterpret_cast<const float4*>(h + i);
    float4 bb = *reinterpret_cast<const float4*>(bias + d4);
    hv.x += bb.x; hv.y += bb.y; hv.z += bb.z; hv.w += bb.w;
#pragma unroll
    for (int z = 0; z < NPART; ++z) {
        float4 a = *reinterpret_cast<const float4*>(part + (long)z * 2097152 + i);
        hv.x += a.x; hv.y += a.y; hv.z += a.z; hv.w += a.w;
    }
    *reinterpret_cast<float4*>(h + i) = hv;
    if (MODE == 1) {
        uint2 p;
        p.x = (unsigned)f2bf(hv.x) | ((unsigned)f2bf(hv.y) << 16);
        p.y = (unsigned)f2bf(hv.z) | ((unsigned)f2bf(hv.w) << 16);
        *reinterpret_cast<uint2*>(outb + i) = p;
    } else {
        float sum = hv.x + hv.y + hv.z + hv.w;
        float sq  = hv.x * hv.x + hv.y * hv.y + hv.z * hv.z + hv.w * hv.w;
#pragma unroll
        for (int o = 32; o; o >>= 1) { sum += __shfl_xor(sum, o); sq += __shfl_xor(sq, o); }
        __shared__ float red[8];
        int w = threadIdx.x >> 6;
        if ((threadIdx.x & 63) == 0) { red[w] = sum; red[4 + w] = sq; }
        __syncthreads();
        sum = red[0] + red[1] + red[2] + red[3];
        sq  = red[4] + red[5] + red[6] + red[7];
        float mean = sum * (1.f / ND);
        float var  = fmaxf(sq * (1.f / ND) - mean * mean, 0.f);
        float inv  = rsqrtf(var + 1e-5f);
        float4 s4 = *reinterpret_cast<const float4*>(&sc[d4]);
        float4 b4 = *reinterpret_cast<const float4*>(&bi[d4]);
        uint2 p;
        p.x = (unsigned)f2bf((hv.x - mean) * inv * s4.x + b4.x)
            | ((unsigned)f2bf((hv.y - mean) * inv * s4.y + b4.y) << 16);
        p.y = (unsigned)f2bf((hv.z - mean) * inv * s4.z + b4.z)
            | ((unsigned)f2bf((hv.w - mean) * inv * s4.w + b4.w) << 16);
        *reinterpret_cast<uint2*>(outb + i) = p;
    }
}

// =====================================================================
// Fused TXL attention, ROLLING rel band, LOAD-BALANCED q-tile pairing:
// block (qtp, bh) processes q-tiles qtp and 7-qtp sequentially (both
// halves together = 9 kv-steps for every block -> even makespan).
// =====================================================================
__global__ __launch_bounds__(256)
void fattn_k(const us* __restrict__ qkv, const us* __restrict__ vt,
             const us* __restrict__ rk, us* __restrict__ obuf)
{
    __shared__ __align__(16) us lds_k[64 * 64];
    __shared__ __align__(16) us lds_v[64 * 64];
    __shared__ __align__(16) us lds_rk[64 * 64];
    __shared__ __align__(16) us lds_p[4 * 16 * 64];
    __shared__ float lds_r[4 * 16 * 132];       // per-wave R, row stride 132

    const int tid = threadIdx.x, lane = tid & 63, w = tid >> 6;
    const int qtp = blockIdx.x, bh = blockIdx.y;
    const int b = bh >> 4, h = bh & 15;
    const int rg = lane >> 4, lc = lane & 15;

    const us* qwb = qkv + ((long)b * 512) * 1024 + h * 64;   // row stride 1024
    const us* qrb = qwb + QOFF;
    const us* kb  = qwb + 2 * QOFF;
    const us* vtb = vt + (long)bh * 64 * 512;                // rows d, stride 512
    const us* rkb = rk + h * 64;                             // rows j, stride 1024

    float* rbase = lds_r + w * (16 * 132);
    us*    pbase = lds_p + w * (16 * 64);

    for (int hh = 0; hh < 2; ++hh) {
        const int qt = hh ? 7 - qtp : qtp;
        const int t0 = qt * 64;

        // Q fragments (rows t0 + w*16 + lc, k-slices kk*32 + rg*8)
        short8v aqw[2], aqr[2];
        {
            long qrow = (long)(t0 + w * 16 + lc) * 1024;
            int ko = rg * 8;
            aqw[0] = *(const short8v*)(qwb + qrow + ko);
            aqw[1] = *(const short8v*)(qwb + qrow + 32 + ko);
            aqr[0] = *(const short8v*)(qrb + qrow + ko);
            aqr[1] = *(const short8v*)(qrb + qrow + 32 + ko);
        }

        float4v oacc[4];
#pragma unroll
        for (int i = 0; i < 4; ++i) oacc[i] = (float4v)0.f;
        float mrow[4] = {-3e38f, -3e38f, -3e38f, -3e38f};
        float lrow[4] = {0.f, 0.f, 0.f, 0.f};

        // stage one 64-row rk half starting at global row j0
        auto stage_rk = [&](int j0) {
#pragma unroll
            for (int i = 0; i < 2; ++i) {
                int rb = w * 16 + i * 8;
                int r  = rb + (lane >> 3);
                int sl = ((lane & 7) ^ (r & 7)) << 3;
                gload16(rkb + (long)(j0 + r) * 1024 + sl, lds_rk + rb * 64);
            }
        };
        // rel MFMA over the staged 64 rows -> R slots [wbase, wbase+64)
        auto rel_half = [&](int wbase) {
#pragma unroll
            for (int jn = 0; jn < 4; ++jn) {
                float4v rf = (float4v)0.f;
#pragma unroll
                for (int kk = 0; kk < 2; ++kk) {
                    int r = jn * 16 + lc;
                    int sw = kk * 4 + rg;
                    short8v bf = *(const short8v*)((const char*)lds_rk + r * 128 + ((sw ^ (r & 7)) << 4));
                    rf = __builtin_amdgcn_mfma_f32_16x16x32_bf16(aqr[kk], bf, rf, 0, 0, 0);
                }
#pragma unroll
                for (int pr = 0; pr < 4; ++pr)
                    rbase[(rg * 4 + pr) * 132 + wbase + jn * 16 + lc] = rf[pr];
            }
        };

        const int nst = qt + 1;
        for (int st = 0; st < nst; ++st) {
            const int s0 = st * 64;
            const int jb = (st - qt) * 64 + 448;          // window base row (>=0)
            const int sb = ((st - qt + 7) & 1) << 6;      // window base slot

            // ---- stage K, V (every step) ----
#pragma unroll
            for (int i = 0; i < 2; ++i) {
                int rb = w * 16 + i * 8;
                int r  = rb + (lane >> 3);
                int sl = ((lane & 7) ^ (r & 7)) << 3;
                gload16(kb + (long)(s0 + r) * 1024 + sl, lds_k + rb * 64);
                gload16(vtb + (long)r * 512 + s0 + sl, lds_v + rb * 64);
            }
            if (st == 0) {
                stage_rk(jb);            // lower half
                __syncthreads();
                rel_half(sb);
                __syncthreads();         // all waves done with lds_rk
                stage_rk(jb + 64);       // upper half
                __syncthreads();
            } else {
                stage_rk(jb + 64);       // only the new upper half
                __syncthreads();
            }

            // ---- content scores (16 q-rows x 64 s) ----
            float4v sfr[4];
#pragma unroll
            for (int sn = 0; sn < 4; ++sn) {
                sfr[sn] = (float4v)0.f;
#pragma unroll
                for (int kk = 0; kk < 2; ++kk) {
                    int r = sn * 16 + lc;
                    int sw = kk * 4 + rg;
                    short8v bf = *(const short8v*)((const char*)lds_k + r * 128 + ((sw ^ (r & 7)) << 4));
                    sfr[sn] = __builtin_amdgcn_mfma_f32_16x16x32_bf16(aqw[kk], bf, sfr[sn], 0, 0, 0);
                }
            }
            rel_half(sb ^ 64);           // upper half of current window

            // ---- combine + shift + mask + online softmax ----
            float pv[4][4];
            float rmax[4] = {-3e38f, -3e38f, -3e38f, -3e38f};
#pragma unroll
            for (int pr = 0; pr < 4; ++pr) {
                int tt = rg * 4 + pr;
                int tw = w * 16 + tt;
#pragma unroll
                for (int sn = 0; sn < 4; ++sn) {
                    int ss = sn * 16 + lc;
                    int slot = (sb + ss + 63 - tw) & 127;
                    float lg = (sfr[sn][pr] + rbase[tt * 132 + slot]) * 0.125f;
                    if (ss > t0 - s0 + tw) lg = -1e30f;   // causal
                    pv[sn][pr] = lg;
                    rmax[pr] = fmaxf(rmax[pr], lg);
                }
            }
#pragma unroll
            for (int o = 1; o < 16; o <<= 1)
#pragma unroll
                for (int pr = 0; pr < 4; ++pr)
                    rmax[pr] = fmaxf(rmax[pr], __shfl_xor(rmax[pr], o));
            float rsum[4];
#pragma unroll
            for (int pr = 0; pr < 4; ++pr) {
                float mn = fmaxf(mrow[pr], rmax[pr]);
                float al = __expf(mrow[pr] - mn);
                mrow[pr] = mn;
                lrow[pr] *= al;
                float s = 0.f;
#pragma unroll
                for (int sn = 0; sn < 4; ++sn) {
                    float p = __expf(pv[sn][pr] - mn);
                    pv[sn][pr] = p;
                    s += p;
                }
                rsum[pr] = s;
#pragma unroll
                for (int dn = 0; dn < 4; ++dn) oacc[dn][pr] *= al;
            }
#pragma unroll
            for (int o = 1; o < 16; o <<= 1)
#pragma unroll
                for (int pr = 0; pr < 4; ++pr)
                    rsum[pr] += __shfl_xor(rsum[pr], o);
#pragma unroll
            for (int pr = 0; pr < 4; ++pr) lrow[pr] += rsum[pr];

            // ---- P -> per-wave LDS (bf16, swizzled for A-frag reads) ----
#pragma unroll
            for (int pr = 0; pr < 4; ++pr) {
                int row = rg * 4 + pr;
#pragma unroll
                for (int sn = 0; sn < 4; ++sn) {
                    int col = sn * 16 + lc;
                    *(us*)((char*)pbase + row * 128 + (((col >> 3) ^ (row & 7)) << 4) + (col & 7) * 2)
                        = f2bf(pv[sn][pr]);
                }
            }
            // ---- PV accumulate ----
            short8v pa[2];
#pragma unroll
            for (int kk = 0; kk < 2; ++kk)
                pa[kk] = *(const short8v*)((const char*)pbase + lc * 128 + (((kk * 4 + rg) ^ (lc & 7)) << 4));
#pragma unroll
            for (int dn = 0; dn < 4; ++dn) {
#pragma unroll
                for (int kk = 0; kk < 2; ++kk) {
                    int r = dn * 16 + lc;
                    int sw = kk * 4 + rg;
                    short8v vb = *(const short8v*)((const char*)lds_v + r * 128 + ((sw ^ (r & 7)) << 4));
                    oacc[dn] = __builtin_amdgcn_mfma_f32_16x16x32_bf16(pa[kk], vb, oacc[dn], 0, 0, 0);
                }
            }
            __syncthreads();   // all waves done with lds_k/v/rk before next stage
        }
        // ---- normalize + store (regs only; safe before next half stages) ----
#pragma unroll
        for (int pr = 0; pr < 4; ++pr) {
            int t = t0 + w * 16 + rg * 4 + pr;
            float inv = 1.f / lrow[pr];
            long rowo = ((long)b * 512 + t) * 1024 + h * 64;
#pragma unroll
            for (int dn = 0; dn < 4; ++dn)
                obuf[rowo + dn * 16 + lc] = f2bf(oacc[dn][pr] * inv);
        }
    }
}

// =====================================================================
// Transpose-convert: fp32 in[R][C] -> bf16 out[C][R], optional layer batch
// =====================================================================
__global__ __launch_bounds__(256)
void tconv_k(const float* __restrict__ in, us* __restrict__ out, int R, int C,
             long inL, long outL)
{
    in  += (long)blockIdx.z * inL;
    out += (long)blockIdx.z * outL;
    __shared__ float t[32][33];
    int c0 = blockIdx.x * 32, r0 = blockIdx.y * 32;
    int tx = threadIdx.x & 31, ty = threadIdx.x >> 5;
#pragma unroll
    for (int j = 0; j < 4; ++j)
        t[ty + j * 8][tx] = in[(long)(r0 + ty + j * 8) * C + c0 + tx];
    __syncthreads();
#pragma unroll
    for (int j = 0; j < 4; ++j)
        out[(long)(c0 + ty + j * 8) * R + r0 + tx] = f2bf(t[tx][ty + j * 8]);
}

// flat fp32 -> bf16 (n % 4 == 0)
__global__ __launch_bounds__(256)
void conv_k(const float* __restrict__ in, us* __restrict__ out, long n)
{
    long i = ((long)blockIdx.x * 256 + threadIdx.x) * 4;
    if (i >= n) return;
    float4 v = *reinterpret_cast<const float4*>(in + i);
    uint2 p;
    p.x = (unsigned)f2bf(v.x) | ((unsigned)f2bf(v.y) << 16);
    p.y = (unsigned)f2bf(v.z) | ((unsigned)f2bf(v.w) << 16);
    *reinterpret_cast<uint2*>(out + i) = p;
}

// zero rk pad rows [512,640) for all 12 layers
__global__ __launch_bounds__(256)
void rkpad12_k(us* __restrict__ rk)
{
    int i = blockIdx.x * 256 + threadIdx.x;   // 98304 uint4 total
    int l = i >> 13, r = i & 8191;
    reinterpret_cast<uint4*>(rk + (long)l * RKL + 512 * 1024)[r] = make_uint4(0, 0, 0, 0);
}

// concat per-layer qkv biases: bqkv[l][3072] = [bq|bk|bv]
__global__ __launch_bounds__(256)
void bcat_k(const float* __restrict__ bq, const float* __restrict__ bk,
            const float* __restrict__ bv, float* __restrict__ o)
{
    int i = blockIdx.x * 256 + threadIdx.x;       // 12*3072
    int l = i / 3072, rr = i % 3072, seg = rr >> 10, c = rr & 1023;
    const float* s = seg == 0 ? bq : seg == 1 ? bk : bv;
    o[i] = s[l * 1024 + c];
}

// =====================================================================
// LayerNorm D=1024 fp32 -> bf16, one block/row (prologue only)
// =====================================================================
__global__ __launch_bounds__(256)
void ln_k(const float* __restrict__ x, us* __restrict__ y,
          const float* __restrict__ sc, const float* __restrict__ bi)
{
    int row = blockIdx.x;
    const float* xr = x + (long)row * ND;
    int d4 = threadIdx.x * 4;
    float4 v = *reinterpret_cast<const float4*>(&xr[d4]);
    float sum = v.x + v.y + v.z + v.w;
    float sq  = v.x * v.x + v.y * v.y + v.z * v.z + v.w * v.w;
#pragma unroll
    for (int o = 32; o; o >>= 1) { sum += __shfl_xor(sum, o); sq += __shfl_xor(sq, o); }
    __shared__ float red[8];
    int w = threadIdx.x >> 6;
    if ((threadIdx.x & 63) == 0) { red[w] = sum; red[4 + w] = sq; }
    __syncthreads();
    sum = red[0] + red[1] + red[2] + red[3];
    sq  = red[4] + red[5] + red[6] + red[7];
    float mean = sum * (1.f / ND);
    float var  = fmaxf(sq * (1.f / ND) - mean * mean, 0.f);
    float inv  = rsqrtf(var + 1e-5f);
    float4 s4 = *reinterpret_cast<const float4*>(&sc[d4]);
    float4 b4 = *reinterpret_cast<const float4*>(&bi[d4]);
    uint2 p;
    p.x = (unsigned)f2bf((v.x - mean) * inv * s4.x + b4.x)
        | ((unsigned)f2bf((v.y - mean) * inv * s4.y + b4.y) << 16);
    p.y = (unsigned)f2bf((v.z - mean) * inv * s4.z + b4.z)
        | ((unsigned)f2bf((v.w - mean) * inv * s4.w + b4.w) << 16);
    *reinterpret_cast<uint2*>(y + (long)row * ND + d4) = p;
}

// sinusoid pos-emb (TXL order), bf16 out
__global__ __launch_bounds__(256)
void pemb_k(us* __restrict__ p)
{
    int t = blockIdx.x;
    float pos = (float)(NT - 1 - t);
    for (int j = threadIdx.x; j < ND / 2; j += 256) {
        float invf = expf(-(float)j * (9.210340371976184f / 512.0f));
        float ang  = pos * invf;
        p[(long)t * ND + j]           = f2bf(sinf(ang));
        p[(long)t * ND + ND / 2 + j]  = f2bf(cosf(ang));
    }
}

// adaptive input embedding -> h fp32
__global__ __launch_bounds__(256)
void embed_k(const int* __restrict__ x,
             const float* __restrict__ e0, const float* __restrict__ e1,
             const float* __restrict__ e2, const float* __restrict__ p1,
             const float* __restrict__ p2, float* __restrict__ h)
{
    __shared__ float e[256];
    int tok = blockIdx.x;
    int v = x[tok];
    float* outp = h + (long)tok * ND;
    if (v < 2000) {
        const float* r = e0 + (long)v * ND;
        for (int d = threadIdx.x; d < ND; d += 256) outp[d] = r[d] * 32.0f;
    } else if (v < 8000) {
        const float* r = e1 + (long)(v - 2000) * 256;
        e[threadIdx.x] = r[threadIdx.x];
        __syncthreads();
        for (int d = threadIdx.x; d < ND; d += 256) {
            float acc = 0.f;
#pragma unroll 4
            for (int i = 0; i < 256; ++i) acc += e[i] * p1[(long)i * ND + d];
            outp[d] = acc * 32.0f;
        }
    } else {
        const float* r = e2 + (long)(v - 8000) * 64;
        if (threadIdx.x < 64) e[threadIdx.x] = r[threadIdx.x];
        __syncthreads();
        for (int d = threadIdx.x; d < ND; d += 256) {
            float acc = 0.f;
#pragma unroll 4
            for (int i = 0; i < 64; ++i) acc += e[i] * p2[(long)i * ND + d];
            outp[d] = acc * 32.0f;
        }
    }
}

// ---------------------------------------------------------------- host
extern "C" void kernel_launch(void* const* d_in, const int* in_sizes, int n_in,
                              void* d_out, int out_size, void* d_ws, size_t ws_size,
                              hipStream_t stream)
{
    (void)in_sizes; (void)n_in; (void)out_size;
    const int*   x     = (const int*)  d_in[0];
    const float* emb0  = (const float*)d_in[1];
    const float* emb1  = (const float*)d_in[2];
    const float* emb2  = (const float*)d_in[3];
    const float* proj1 = (const float*)d_in[4];
    const float* proj2 = (const float*)d_in[5];
    const float* obias = (const float*)d_in[6];
    const float* rwb   = (const float*)d_in[7];
    const float* rrb   = (const float*)d_in[8];
    const float* ln1s  = (const float*)d_in[9];
    const float* ln1b  = (const float*)d_in[10];
    const float* Wq    = (const float*)d_in[11];
    const float* bq    = (const float*)d_in[12];
    const float* Wk    = (const float*)d_in[13];
    const float* bk    = (const float*)d_in[14];
    const float* Wv    = (const float*)d_in[15];
    const float* bv    = (const float*)d_in[16];
    const float* Wr    = (const float*)d_in[17];
    const float* Wo    = (const float*)d_in[18];
    const float* bo    = (const float*)d_in[19];
    const float* ln2s  = (const float*)d_in[20];
    const float* ln2b  = (const float*)d_in[21];
    const float* W1    = (const float*)d_in[22];
    const float* b1    = (const float*)d_in[23];
    const float* W2    = (const float*)d_in[24];
    const float* b2    = (const float*)d_in[25];
    float* out = (float*)d_out;

    // ---- d_out scratch (us-unit offsets); all dead before vocab GEMMs ----
    us* ob      = (us*)out;
    us* qkvbuf  = ob;                 // 6,291,456  (qw|qr|k)
    us* mid_bf  = ob +  6291456;      // 8,388,608  [2048][4096]
    us* vt_bf   = ob + 14680064;      // 2,097,152  [64][64][512]
    us* o_bf    = ob + 16777216;      // 2,097,152  [2048][1024]
    us* ain_bf  = ob + 18874368;      // 2,097,152  [2048][1024]
    us* rk_all  = ob + 20971520;      // 7,864,320  [12][640][1024] (pad rows zero)
    us* pemb_bf = ob + 28835840;      //   524,288  [512][1024]
    // fallback per-layer weight scratch (only used if ws too small)
    us* wqkv_sc = ob + 29360128;      // 3,145,728
    us* wr_sc   = ob + 32505856;      // 1,048,576
    us* wo_sc   = ob + 33554432;      // 1,048,576
    us* w1_sc   = ob + 34603008;      // 4,194,304
    us* w2_sc   = ob + 38797312;      // 4,194,304  (ends 42,991,616 us)
    float* pffn = out + 21495808;     // 8,388,608 f: [4][2048][1024] fp32 partials
    float* pwo  = out + 29884416;     // 4,194,304 f: [2][2048][1024] fp32 partials

    // ---- d_ws layout ----
    float* wsf      = (float*)d_ws;
    float* h        = wsf;                         // 2,097,152 f
    us*    h_bf     = (us*)(wsf + 2097152);
    us*    hp1_bf   = h_bf   + 2097152;            // 524,288
    us*    hp2_bf   = hp1_bf + 524288;             // 131,072
    us*    emb0_bf  = hp2_bf + 131072;             // 2048x1024 (2000 real)
    us*    emb1_bf  = emb0_bf + 2097152;           // 6144x256  (6000 real)
    us*    emb2_bf  = emb1_bf + 1572864;           // 24064x64  (24000 real)
    us*    proj1_bf = emb2_bf + 1540096;           // 256x1024
    us*    proj2_bf = proj1_bf + 262144;           // 64x1024
    float* bqkv     = (float*)(proj2_bf + 65536);  // 12*3072 f
    us*    wqkv_all = (us*)(bqkv + 36864);         // [12][3072][1024]
    us*    wr_all   = wqkv_all + (long)NL * 3072 * 1024;
    us*    wo_all   = wr_all   + (long)NL * 1024 * 1024;
    us*    w1_all   = wo_all   + (long)NL * 1024 * 1024;   // [12][4096][1024]
    us*    w2_all   = w1_all   + (long)NL * 4096 * 1024;   // [12][1024][4096]
    const bool big  = ws_size >= (size_t)352273408;        // full weight cache fits

    // ---- one-time setup ----
    bcat_k<<<144, 256, 0, stream>>>(bq, bk, bv, bqkv);
    conv_k<<<2000, 256, 0, stream>>>(emb0,  emb0_bf,  2048000);
    conv_k<<<1500, 256, 0, stream>>>(emb1,  emb1_bf,  1536000);
    conv_k<<<1500, 256, 0, stream>>>(emb2,  emb2_bf,  1536000);
    conv_k<<<256,  256, 0, stream>>>(proj1, proj1_bf, 262144);
    conv_k<<<64,   256, 0, stream>>>(proj2, proj2_bf, 65536);
    pemb_k<<<NT, 256, 0, stream>>>(pemb_bf);
    rkpad12_k<<<384, 256, 0, stream>>>(rk_all);
    embed_k<<<NBT, 256, 0, stream>>>(x, emb0, emb1, emb2, proj1, proj2, h);
    if (big) {   // batched all-layer weight transpose-convert (7 launches)
        tconv_k<<<dim3(32, 32, NL), 256, 0, stream>>>(Wq, wqkv_all,           1024, 1024, 1048576, 3145728);
        tconv_k<<<dim3(32, 32, NL), 256, 0, stream>>>(Wk, wqkv_all + 1048576, 1024, 1024, 1048576, 3145728);
        tconv_k<<<dim3(32, 32, NL), 256, 0, stream>>>(Wv, wqkv_all + 2097152, 1024, 1024, 1048576, 3145728);
        tconv_k<<<dim3(32, 32, NL), 256, 0, stream>>>(Wr, wr_all, 1024, 1024, 1048576, 1048576);
        tconv_k<<<dim3(32, 32, NL), 256, 0, stream>>>(Wo, wo_all, 1024, 1024, 1048576, 1048576);
        tconv_k<<<dim3(128, 32, NL), 256, 0, stream>>>(W1, w1_all, 1024, 4096, 4194304, 4194304);
        tconv_k<<<dim3(32, 128, NL), 256, 0, stream>>>(W2, w2_all, 4096, 1024, 4194304, 4194304);
        // batched r_k for all layers: rk_all[l] = pemb @ Wr[l]
        bgemm_k<64, 64, 0, true><<<dim3(16, 8, NL), 256, 0, stream>>>(
            pemb_bf, wr_all, rk_all, nullptr, nullptr, nullptr, nullptr, nullptr,
            1024, 1024, 1024, 1024, 1024,
            1, 0, 0, 1048576, 0, RKL, 0);
    }
    // prologue: ln1 of layer 0
    ln_k<<<NBT, 256, 0, stream>>>(h, ain_bf, ln1s, ln1b);

    for (int l = 0; l < NL; ++l) {
        const us* wqkv_t = big ? wqkv_all + (long)l * 3145728 : wqkv_sc;
        const us* wo_t   = big ? wo_all   + (long)l * 1048576 : wo_sc;
        const us* w1_t   = big ? w1_all   + (long)l * 4194304 : w1_sc;
        const us* w2_t   = big ? w2_all   + (long)l * 4194304 : w2_sc;
        if (!big) {
            const long wOff = (long)l * ND * ND;
            tconv_k<<<dim3(32, 32), 256, 0, stream>>>(Wq + wOff, wqkv_sc,           1024, 1024, 0, 0);
            tconv_k<<<dim3(32, 32), 256, 0, stream>>>(Wk + wOff, wqkv_sc + 1048576, 1024, 1024, 0, 0);
            tconv_k<<<dim3(32, 32), 256, 0, stream>>>(Wv + wOff, wqkv_sc + 2097152, 1024, 1024, 0, 0);
            tconv_k<<<dim3(32, 32), 256, 0, stream>>>(Wr + wOff, wr_sc, 1024, 1024, 0, 0);
            tconv_k<<<dim3(32, 32), 256, 0, stream>>>(Wo + wOff, wo_sc, 1024, 1024, 0, 0);
            tconv_k<<<dim3(128, 32), 256, 0, stream>>>(W1 + (long)l * ND * NF, w1_sc, 1024, 4096, 0, 0);
            tconv_k<<<dim3(32, 128), 256, 0, stream>>>(W2 + (long)l * ND * NF, w2_sc, 4096, 1024, 0, 0);
            bgemm_k<64, 64, 0, true><<<dim3(16, 8, 1), 256, 0, stream>>>(
                pemb_bf, wr_sc, rk_all + (long)l * RKL, nullptr, nullptr, nullptr, nullptr, nullptr,
                1024, 1024, 1024, 1024, 1024, 0, 0, 0, 0, 0, 0, 0);
        }

        // fused QKV (EPI=3): qw,qr,k into qkvbuf; v straight into vt
        bgemm_k<128, 64, 3, true><<<dim3(48, 16, 1), 256, 0, stream>>>(
            ain_bf, wqkv_t, qkvbuf, bqkv + l * 3072, nullptr, rwb, rrb, vt_bf,
            3072, 1024, 1024, 1024, 1024, 0, 0, 0, 0, 0, 0, 0);
        // fused attention (load-balanced q-tile pairing)
        fattn_k<<<dim3(4, NB * NH), 256, 0, stream>>>(
            qkvbuf, vt_bf, rk_all + (long)l * RKL, o_bf);
        // Wo split-K=2 at 128x64 tiles -> fp32 partials
        bgemm_k<128, 64, 0, false><<<dim3(16, 16, 2), 256, 0, stream>>>(
            o_bf, wo_t, pwo, nullptr, nullptr, nullptr, nullptr, nullptr,
            1024, 512, 1024, 1024, 1024,
            1, 512, 0, 512, 0, 2097152, 0);
        // h += bo + sum(pwo); ain = LN2(h)
        redln_k<2, 0><<<NBT, 256, 0, stream>>>(
            pwo, bo + l * ND, h, ain_bf, ln2s + l * ND, ln2b + l * ND);

        // FFN
        bgemm_k<128, 128, 1, true><<<dim3(32, 16, 1), 256, 0, stream>>>(
            ain_bf, w1_t, mid_bf, b1 + (long)l * NF, nullptr, nullptr, nullptr, nullptr,
            4096, 1024, 1024, 1024, 4096, 0, 0, 0, 0, 0, 0, 0);
        // FFN2 split-K=4 at 128x128 tiles -> fp32 partials
        bgemm_k<128, 128, 0, false><<<dim3(8, 16, 4), 256, 0, stream>>>(
            mid_bf, w2_t, pffn, nullptr, nullptr, nullptr, nullptr, nullptr,
            1024, 1024, 4096, 4096, 1024,
            1, 1024, 0, 1024, 0, 2097152, 0);
        // h += b2 + sum(pffn); then LN1(next layer) or bf16 convert (last)
        if (l < NL - 1)
            redln_k<4, 0><<<NBT, 256, 0, stream>>>(
                pffn, b2 + (long)l * ND, h, ain_bf,
                ln1s + (l + 1) * ND, ln1b + (l + 1) * ND);
        else
            redln_k<4, 1><<<NBT, 256, 0, stream>>>(
                pffn, b2 + (long)l * ND, h, h_bf, nullptr, nullptr);
    }

    // ---- tied adaptive-softmax output: (h @ proj^T) @ emb^T ----
    // cluster 0: cols [0,2000)
    bgemm_k<128, 64, 0, false><<<dim3(32, 16, 1), 256, 0, stream>>>(
        h_bf, emb0_bf, out, obias, nullptr, nullptr, nullptr, nullptr,
        2000, 1024, 1024, 1024, NV, 0, 0, 0, 0, 0, 0, 0);
    // cluster 1: hp1 = h @ proj1^T ; cols [2000,8000)
    bgemm_k<64, 64, 0, true><<<dim3(4, 32, 1), 256, 0, stream>>>(
        h_bf, proj1_bf, hp1_bf, nullptr, nullptr, nullptr, nullptr, nullptr,
        256, 1024, 1024, 1024, 256, 0, 0, 0, 0, 0, 0, 0);
    bgemm_k<128, 128, 0, false><<<dim3(47, 16, 1), 256, 0, stream>>>(
        hp1_bf, emb1_bf, out + 2000, obias + 2000, nullptr, nullptr, nullptr, nullptr,
        6000, 256, 256, 256, NV, 0, 0, 0, 0, 0, 0, 0);
    // cluster 2: hp2 = h @ proj2^T ; cols [8000,32000)
    bgemm_k<64, 64, 0, true><<<dim3(1, 32, 1), 256, 0, stream>>>(
        h_bf, proj2_bf, hp2_bf, nullptr, nullptr, nullptr, nullptr, nullptr,
        64, 1024, 1024, 1024, 64, 0, 0, 0, 0, 0, 0, 0);
    bgemm_k<128, 128, 0, false><<<dim3(188, 16, 1), 256, 0, stream>>>(
        hp2_bf, emb2_bf, out + 8000, obias + 8000, nullptr, nullptr, nullptr, nullptr,
        24000, 64, 64, 64, NV, 0, 0, 0, 0, 0, 0, 0);
}

// Round 11
// 2449.499 us; speedup vs baseline: 7.8564x; 1.0041x over previous
//
#include <hip/hip_runtime.h>

using us = unsigned short;
typedef short short8v __attribute__((ext_vector_type(8)));
typedef float float4v __attribute__((ext_vector_type(4)));

// ---------------- problem constants ----------------
constexpr int NB  = 4;
constexpr int NT  = 512;
constexpr int ND  = 1024;
constexpr int NL  = 12;
constexpr int NH  = 16;
constexpr int NF  = 4096;
constexpr int NHD = 64;
constexpr int NBT = NB * NT;   // 2048
constexpr int NV  = 32000;
constexpr long QOFF = (long)NBT * ND;  // qw|qr|k stride in qkvbuf
constexpr long RKL  = 640L * 1024;     // per-layer rk stride (rows 512.. are zero pad)

__device__ __forceinline__ us f2bf(float f) {
    unsigned u = __float_as_uint(f);
    u += 0x7fffu + ((u >> 16) & 1u);      // RNE
    return (us)(u >> 16);
}

// async global->LDS, 16B per lane. LDS dest is wave-uniform base + lane*16;
// global src is per-lane (pre-swizzled for bank-conflict-free ds_read).
__device__ __forceinline__ void gload16(const us* g, us* l) {
    __builtin_amdgcn_global_load_lds(
        (const __attribute__((address_space(1))) void*)g,
        (__attribute__((address_space(3))) void*)l, 16, 0, 0);
}

// =====================================================================
// bf16 MFMA GEMM:  C[M,N] = A[M,K] @ B[N,K]^T   (both row-major, k-contig)
// 256 threads = 4 waves (2x2), per-wave tile (BM/2)x(BN/2), BK=64.
// TWO-PHASE double-buffered staging (prefetch next tile under MFMA).
// EPI: 0 plain (+bias,+addsrc), 1 gelu, 3 fused QKV epilogue:
//      seg0 -> qw,qr (+r_w/r_r bias), seg1 -> k, seg2 -> vt[b,h,d,t] packed.
// =====================================================================
template<int BM, int BN, int EPI, bool OUTBF>
__global__ __launch_bounds__(256)
void bgemm_k(const us* __restrict__ A, const us* __restrict__ B, void* Cv,
             const float* __restrict__ bias, const float* addsrc,
             const float* __restrict__ p0, const float* __restrict__ p1,
             us* __restrict__ vtp,
             int N, int K, int lda, int ldb, int ldc,
             int bdiv, long sAb, long sAh, long sBb, long sBh, long sCb, long sCh)
{
    constexpr int BK  = 64;
    constexpr int WTM = BM / 2, WTN = BN / 2;
    constexpr int FM  = WTM / 16, FN = WTN / 16;
    constexpr int AI  = BM / 32;       // gload16 instr per wave (A tile)
    constexpr int BI  = BN / 32;
    static_assert(BM % 32 == 0 && BN % 32 == 0, "");

    long coff = 0;
    if (bdiv > 0) {
        int z = blockIdx.z, zb = z / bdiv, zh = z % bdiv;
        A += zb * sAb + zh * sAh;
        B += zb * sBb + zh * sBh;
        coff = zb * sCb + zh * sCh;
    }
    float* Cf = (float*)Cv + coff;
    us*    Ch = (us*)Cv + coff;
    if (addsrc) addsrc += coff;

    __shared__ __align__(16) us As[2 * BM * BK];
    __shared__ __align__(16) us Bs[2 * BN * BK];

    const int tid  = threadIdx.x;
    const int lane = tid & 63;
    const int w    = tid >> 6;
    const int wm   = w >> 1;
    const int wn   = w & 1;
    const int row0 = blockIdx.y * BM;
    const int col0 = blockIdx.x * BN;

    float4v acc[FM][FN];
#pragma unroll
    for (int i = 0; i < FM; ++i)
#pragma unroll
        for (int j = 0; j < FN; ++j) acc[i][j] = (float4v)0.f;

    auto stage = [&](int buf, int k0) {
        us* Ad = As + buf * (BM * BK);
        us* Bd = Bs + buf * (BN * BK);
#pragma unroll
        for (int i = 0; i < AI; ++i) {
            int rb = w * (BM / 4) + i * 8;
            int r  = rb + (lane >> 3);
            int sc8 = ((lane & 7) ^ (r & 7)) << 3;
            gload16(A + (long)(row0 + r) * lda + k0 + sc8, Ad + rb * 64);
        }
#pragma unroll
        for (int i = 0; i < BI; ++i) {
            int rb = w * (BN / 4) + i * 8;
            int r  = rb + (lane >> 3);
            int sc8 = ((lane & 7) ^ (r & 7)) << 3;
            gload16(B + (long)(col0 + r) * ldb + k0 + sc8, Bd + rb * 64);
        }
    };

    stage(0, 0);
    __syncthreads();           // buf0 staged (vmcnt drained)
    int cur = 0;
    for (int k0 = 0; k0 < K; k0 += BK) {
        if (k0 + BK < K) stage(cur ^ 1, k0 + BK);   // prefetch next tile
        const char* Ac = (const char*)(As + cur * (BM * BK));
        const char* Bc = (const char*)(Bs + cur * (BN * BK));
#pragma unroll
        for (int ks = 0; ks < 2; ++ks) {
            short8v af[FM], bfr[FN];
            int sw = ks * 4 + (lane >> 4);
#pragma unroll
            for (int i = 0; i < FM; ++i) {
                int r = wm * WTM + i * 16 + (lane & 15);
                af[i] = *reinterpret_cast<const short8v*>(Ac + r * 128 + ((sw ^ (r & 7)) << 4));
            }
#pragma unroll
            for (int j = 0; j < FN; ++j) {
                int r = wn * WTN + j * 16 + (lane & 15);
                bfr[j] = *reinterpret_cast<const short8v*>(Bc + r * 128 + ((sw ^ (r & 7)) << 4));
            }
#pragma unroll
            for (int i = 0; i < FM; ++i)
#pragma unroll
                for (int j = 0; j < FN; ++j)
                    acc[i][j] = __builtin_amdgcn_mfma_f32_16x16x32_bf16(af[i], bfr[j], acc[i][j], 0, 0, 0);
        }
        __syncthreads();       // next tile staged; all waves done reading cur
        cur ^= 1;
    }

    // ---- epilogue.  D layout: col = lane&15, row = (lane>>4)*4 + reg ----
#pragma unroll
    for (int i = 0; i < FM; ++i) {
        int growb = row0 + wm * WTM + i * 16 + ((lane >> 4) << 2);
#pragma unroll
        for (int j = 0; j < FN; ++j) {
            int gcol = col0 + wn * WTN + j * 16 + (lane & 15);
            if (EPI == 3) {
                int seg = gcol >> 10, c = gcol & 1023;
                float bb = bias[gcol];
                if (seg == 2) {
                    // v -> vt[b,h,d,t], 4 consecutive t packed into 8B
                    unsigned lo = (unsigned)f2bf(acc[i][j][0] + bb)
                                | ((unsigned)f2bf(acc[i][j][1] + bb) << 16);
                    unsigned hi = (unsigned)f2bf(acc[i][j][2] + bb)
                                | ((unsigned)f2bf(acc[i][j][3] + bb) << 16);
                    int bidx = growb >> 9, tb = growb & 511;
                    uint2 pk; pk.x = lo; pk.y = hi;
                    *reinterpret_cast<uint2*>(
                        vtp + ((long)((bidx * 16 + (c >> 6)) * 64 + (c & 63)) << 9) + tb) = pk;
                } else {
                    us* base = (us*)Cv;
#pragma unroll
                    for (int r = 0; r < 4; ++r) {
                        int gr = growb + r;
                        float v = acc[i][j][r] + bb;
                        long o = (long)gr * 1024 + c;
                        if (seg == 0) {
                            base[o]        = f2bf(v + p0[c]);   // qw
                            base[o + QOFF] = f2bf(v + p1[c]);   // qr
                        } else base[o + 2 * QOFF] = f2bf(v);    // k
                    }
                }
            } else {
                if (gcol >= N) continue;
#pragma unroll
                for (int r = 0; r < 4; ++r) {
                    int gr = growb + r;
                    float v = acc[i][j][r];
                    if (bias) v += bias[gcol];
                    if (EPI == 1) {
                        float xx = v;
                        v = 0.5f * xx * (1.f + tanhf(0.7978845608028654f
                                                     * (xx + 0.044715f * xx * xx * xx)));
                    }
                    if (addsrc) v += addsrc[(long)gr * ldc + gcol];
                    if (OUTBF) Ch[(long)gr * ldc + gcol] = f2bf(v);
                    else       Cf[(long)gr * ldc + gcol] = v;
                }
            }
        }
    }
}

// =====================================================================
// Fused split-K reduce + residual + (LN -> bf16 | bf16 convert).
//   h[row] += bias + sum_{z<NPART} part[z][row]
//   MODE 0: outb = bf16(LayerNorm(h_new, sc, bi))   (one block per row)
//   MODE 1: outb = bf16(h_new)
// =====================================================================
template<int NPART, int MODE>
__global__ __launch_bounds__(256)
void redln_k(const float* __restrict__ part, const float* __restrict__ bias,
             float* __restrict__ h, us* __restrict__ outb,
             const float* __restrict__ sc, const float* __restrict__ bi)
{
    int row = blockIdx.x;
    int d4 = threadIdx.x * 4;
    long i = (long)row * ND + d4;
    float4 hv = *reinterpret_cast<const float4*>(h + i);
    float4 bb = *reinterpret_cast<const float4*>(bias + d4);
    hv.x += bb.x; hv.y += bb.y; hv.z += bb.z; hv.w += bb.w;
#pragma unroll
    for (int z = 0; z < NPART; ++z) {
        float4 a = *reinterpret_cast<const float4*>(part + (long)z * 2097152 + i);
        hv.x += a.x; hv.y += a.y; hv.z += a.z; hv.w += a.w;
    }
    *reinterpret_cast<float4*>(h + i) = hv;
    if (MODE == 1) {
        uint2 p;
        p.x = (unsigned)f2bf(hv.x) | ((unsigned)f2bf(hv.y) << 16);
        p.y = (unsigned)f2bf(hv.z) | ((unsigned)f2bf(hv.w) << 16);
        *reinterpret_cast<uint2*>(outb + i) = p;
    } else {
        float sum = hv.x + hv.y + hv.z + hv.w;
        float sq  = hv.x * hv.x + hv.y * hv.y + hv.z * hv.z + hv.w * hv.w;
#pragma unroll
        for (int o = 32; o; o >>= 1) { sum += __shfl_xor(sum, o); sq += __shfl_xor(sq, o); }
        __shared__ float red[8];
        int w = threadIdx.x >> 6;
        if ((threadIdx.x & 63) == 0) { red[w] = sum; red[4 + w] = sq; }
        __syncthreads();
        sum = red[0] + red[1] + red[2] + red[3];
        sq  = red[4] + red[5] + red[6] + red[7];
        float mean = sum * (1.f / ND);
        float var  = fmaxf(sq * (1.f / ND) - mean * mean, 0.f);
        float inv  = rsqrtf(var + 1e-5f);
        float4 s4 = *reinterpret_cast<const float4*>(&sc[d4]);
        float4 b4 = *reinterpret_cast<const float4*>(&bi[d4]);
        uint2 p;
        p.x = (unsigned)f2bf((hv.x - mean) * inv * s4.x + b4.x)
            | ((unsigned)f2bf((hv.y - mean) * inv * s4.y + b4.y) << 16);
        p.y = (unsigned)f2bf((hv.z - mean) * inv * s4.z + b4.z)
            | ((unsigned)f2bf((hv.w - mean) * inv * s4.w + b4.w) << 16);
        *reinterpret_cast<uint2*>(outb + i) = p;
    }
}

// =====================================================================
// Fused TXL attention, ROLLING rel band, load-balanced q-tile pairing,
// TWO-PHASE pipeline: K/V double-buffered, rk 3-buffer rotation
// (step st consumes rk buf[(st+1)%3], stages st+1's half into buf[(st+2)%3];
// every staged buffer was last read >=1 barrier earlier).  One barrier
// per kv-step; staging latency hides under MFMA + softmax.
// =====================================================================
__global__ __launch_bounds__(256)
void fattn_k(const us* __restrict__ qkv, const us* __restrict__ vt,
             const us* __restrict__ rk, us* __restrict__ obuf)
{
    __shared__ __align__(16) us lds_k[2][64 * 64];
    __shared__ __align__(16) us lds_v[2][64 * 64];
    __shared__ __align__(16) us lds_rk[3][64 * 64];
    __shared__ __align__(16) us lds_p[4 * 16 * 64];
    __shared__ float lds_r[4 * 16 * 132];       // per-wave R, row stride 132

    const int tid = threadIdx.x, lane = tid & 63, w = tid >> 6;
    const int qtp = blockIdx.x, bh = blockIdx.y;
    const int b = bh >> 4, h = bh & 15;
    const int rg = lane >> 4, lc = lane & 15;

    const us* qwb = qkv + ((long)b * 512) * 1024 + h * 64;   // row stride 1024
    const us* qrb = qwb + QOFF;
    const us* kb  = qwb + 2 * QOFF;
    const us* vtb = vt + (long)bh * 64 * 512;                // rows d, stride 512
    const us* rkb = rk + h * 64;                             // rows j, stride 1024

    float* rbase = lds_r + w * (16 * 132);
    us*    pbase = lds_p + w * (16 * 64);

    auto stage_kv = [&](int buf, int s0) {
#pragma unroll
        for (int i = 0; i < 2; ++i) {
            int rb = w * 16 + i * 8;
            int r  = rb + (lane >> 3);
            int sl = ((lane & 7) ^ (r & 7)) << 3;
            gload16(kb + (long)(s0 + r) * 1024 + sl, lds_k[buf] + rb * 64);
            gload16(vtb + (long)r * 512 + s0 + sl, lds_v[buf] + rb * 64);
        }
    };
    auto stage_rk = [&](int buf, int j0) {
#pragma unroll
        for (int i = 0; i < 2; ++i) {
            int rb = w * 16 + i * 8;
            int r  = rb + (lane >> 3);
            int sl = ((lane & 7) ^ (r & 7)) << 3;
            gload16(rkb + (long)(j0 + r) * 1024 + sl, lds_rk[buf] + rb * 64);
        }
    };

    for (int hh = 0; hh < 2; ++hh) {
        const int qt = hh ? 7 - qtp : qtp;
        const int t0 = qt * 64;

        // Q fragments (rows t0 + w*16 + lc, k-slices kk*32 + rg*8)
        short8v aqw[2], aqr[2];
        {
            long qrow = (long)(t0 + w * 16 + lc) * 1024;
            int ko = rg * 8;
            aqw[0] = *(const short8v*)(qwb + qrow + ko);
            aqw[1] = *(const short8v*)(qwb + qrow + 32 + ko);
            aqr[0] = *(const short8v*)(qrb + qrow + ko);
            aqr[1] = *(const short8v*)(qrb + qrow + 32 + ko);
        }

        float4v oacc[4];
#pragma unroll
        for (int i = 0; i < 4; ++i) oacc[i] = (float4v)0.f;
        float mrow[4] = {-3e38f, -3e38f, -3e38f, -3e38f};
        float lrow[4] = {0.f, 0.f, 0.f, 0.f};

        // rel MFMA over staged rk buf -> R slots [wbase, wbase+64)
        auto rel_half = [&](int buf, int wbase) {
#pragma unroll
            for (int jn = 0; jn < 4; ++jn) {
                float4v rf = (float4v)0.f;
#pragma unroll
                for (int kk = 0; kk < 2; ++kk) {
                    int r = jn * 16 + lc;
                    int sw = kk * 4 + rg;
                    short8v bf = *(const short8v*)((const char*)lds_rk[buf] + r * 128 + ((sw ^ (r & 7)) << 4));
                    rf = __builtin_amdgcn_mfma_f32_16x16x32_bf16(aqr[kk], bf, rf, 0, 0, 0);
                }
#pragma unroll
                for (int pr = 0; pr < 4; ++pr)
                    rbase[(rg * 4 + pr) * 132 + wbase + jn * 16 + lc] = rf[pr];
            }
        };

        const int jb0 = 448 - qt * 64;          // window base row at st=0 (>=0)
        // ---- prologue: stage step 0 (K/V + both rk halves) ----
        stage_kv(0, 0);
        stage_rk(0, jb0);
        stage_rk(1, jb0 + 64);
        __syncthreads();

        for (int st = 0; st <= qt; ++st) {
            const int s0 = st * 64;
            const int sb = ((st - qt + 7) & 1) << 6;      // window base slot
            // ---- issue next-step stages (land at end-of-step barrier) ----
            if (st < qt) {
                stage_kv((st + 1) & 1, s0 + 64);
                stage_rk((st + 2) % 3, (st + 1 - qt) * 64 + 448 + 64);
            }
            // ---- rel band -> per-wave R slots ----
            if (st == 0) { rel_half(0, sb); rel_half(1, sb ^ 64); }
            else         rel_half((st + 1) % 3, sb ^ 64);
            // ---- content scores (16 q-rows x 64 s) ----
            const char* Kc = (const char*)lds_k[st & 1];
            const char* Vc = (const char*)lds_v[st & 1];
            float4v sfr[4];
#pragma unroll
            for (int sn = 0; sn < 4; ++sn) {
                sfr[sn] = (float4v)0.f;
#pragma unroll
                for (int kk = 0; kk < 2; ++kk) {
                    int r = sn * 16 + lc;
                    int sw = kk * 4 + rg;
                    short8v bf = *(const short8v*)(Kc + r * 128 + ((sw ^ (r & 7)) << 4));
                    sfr[sn] = __builtin_amdgcn_mfma_f32_16x16x32_bf16(aqw[kk], bf, sfr[sn], 0, 0, 0);
                }
            }

            // ---- combine + shift + mask + online softmax ----
            float pv[4][4];
            float rmax[4] = {-3e38f, -3e38f, -3e38f, -3e38f};
#pragma unroll
            for (int pr = 0; pr < 4; ++pr) {
                int tt = rg * 4 + pr;
                int tw = w * 16 + tt;
#pragma unroll
                for (int sn = 0; sn < 4; ++sn) {
                    int ss = sn * 16 + lc;
                    int slot = (sb + ss + 63 - tw) & 127;
                    float lg = (sfr[sn][pr] + rbase[tt * 132 + slot]) * 0.125f;
                    if (ss > t0 - s0 + tw) lg = -1e30f;   // causal
                    pv[sn][pr] = lg;
                    rmax[pr] = fmaxf(rmax[pr], lg);
                }
            }
#pragma unroll
            for (int o = 1; o < 16; o <<= 1)
#pragma unroll
                for (int pr = 0; pr < 4; ++pr)
                    rmax[pr] = fmaxf(rmax[pr], __shfl_xor(rmax[pr], o));
            float rsum[4];
#pragma unroll
            for (int pr = 0; pr < 4; ++pr) {
                float mn = fmaxf(mrow[pr], rmax[pr]);
                float al = __expf(mrow[pr] - mn);
                mrow[pr] = mn;
                lrow[pr] *= al;
                float s = 0.f;
#pragma unroll
                for (int sn = 0; sn < 4; ++sn) {
                    float p = __expf(pv[sn][pr] - mn);
                    pv[sn][pr] = p;
                    s += p;
                }
                rsum[pr] = s;
#pragma unroll
                for (int dn = 0; dn < 4; ++dn) oacc[dn][pr] *= al;
            }
#pragma unroll
            for (int o = 1; o < 16; o <<= 1)
#pragma unroll
                for (int pr = 0; pr < 4; ++pr)
                    rsum[pr] += __shfl_xor(rsum[pr], o);
#pragma unroll
            for (int pr = 0; pr < 4; ++pr) lrow[pr] += rsum[pr];

            // ---- P -> per-wave LDS (bf16, swizzled for A-frag reads) ----
#pragma unroll
            for (int pr = 0; pr < 4; ++pr) {
                int row = rg * 4 + pr;
#pragma unroll
                for (int sn = 0; sn < 4; ++sn) {
                    int col = sn * 16 + lc;
                    *(us*)((char*)pbase + row * 128 + (((col >> 3) ^ (row & 7)) << 4) + (col & 7) * 2)
                        = f2bf(pv[sn][pr]);
                }
            }
            // ---- PV accumulate ----
            short8v pa[2];
#pragma unroll
            for (int kk = 0; kk < 2; ++kk)
                pa[kk] = *(const short8v*)((const char*)pbase + lc * 128 + (((kk * 4 + rg) ^ (lc & 7)) << 4));
#pragma unroll
            for (int dn = 0; dn < 4; ++dn) {
#pragma unroll
                for (int kk = 0; kk < 2; ++kk) {
                    int r = dn * 16 + lc;
                    int sw = kk * 4 + rg;
                    short8v vb = *(const short8v*)(Vc + r * 128 + ((sw ^ (r & 7)) << 4));
                    oacc[dn] = __builtin_amdgcn_mfma_f32_16x16x32_bf16(pa[kk], vb, oacc[dn], 0, 0, 0);
                }
            }
            __syncthreads();   // next-step stages landed; all waves done with cur bufs
        }
        // ---- normalize + store (regs only; safe before next half stages) ----
#pragma unroll
        for (int pr = 0; pr < 4; ++pr) {
            int t = t0 + w * 16 + rg * 4 + pr;
            float inv = 1.f / lrow[pr];
            long rowo = ((long)b * 512 + t) * 1024 + h * 64;
#pragma unroll
            for (int dn = 0; dn < 4; ++dn)
                obuf[rowo + dn * 16 + lc] = f2bf(oacc[dn][pr] * inv);
        }
    }
}

// =====================================================================
// Transpose-convert: fp32 in[R][C] -> bf16 out[C][R], optional layer batch
// =====================================================================
__global__ __launch_bounds__(256)
void tconv_k(const float* __restrict__ in, us* __restrict__ out, int R, int C,
             long inL, long outL)
{
    in  += (long)blockIdx.z * inL;
    out += (long)blockIdx.z * outL;
    __shared__ float t[32][33];
    int c0 = blockIdx.x * 32, r0 = blockIdx.y * 32;
    int tx = threadIdx.x & 31, ty = threadIdx.x >> 5;
#pragma unroll
    for (int j = 0; j < 4; ++j)
        t[ty + j * 8][tx] = in[(long)(r0 + ty + j * 8) * C + c0 + tx];
    __syncthreads();
#pragma unroll
    for (int j = 0; j < 4; ++j)
        out[(long)(c0 + ty + j * 8) * R + r0 + tx] = f2bf(t[tx][ty + j * 8]);
}

// all small fp32->bf16 conversions in one launch (block ranges align to
// region boundaries: 2000|1500|1500|256|64 blocks of 1024 floats each)
__global__ __launch_bounds__(256)
void convall_k(const float* __restrict__ e0, const float* __restrict__ e1,
               const float* __restrict__ e2, const float* __restrict__ p1,
               const float* __restrict__ p2,
               us* __restrict__ d0, us* __restrict__ d1, us* __restrict__ d2,
               us* __restrict__ d3, us* __restrict__ d4)
{
    int blk = blockIdx.x;
    const float* s; us* d; long off;
    if (blk < 2000)      { s = e0; d = d0; off = (long)blk * 1024; }
    else if (blk < 3500) { s = e1; d = d1; off = (long)(blk - 2000) * 1024; }
    else if (blk < 5000) { s = e2; d = d2; off = (long)(blk - 3500) * 1024; }
    else if (blk < 5256) { s = p1; d = d3; off = (long)(blk - 5000) * 1024; }
    else                 { s = p2; d = d4; off = (long)(blk - 5256) * 1024; }
    long i = off + (long)threadIdx.x * 4;
    float4 v = *reinterpret_cast<const float4*>(s + i);
    uint2 p;
    p.x = (unsigned)f2bf(v.x) | ((unsigned)f2bf(v.y) << 16);
    p.y = (unsigned)f2bf(v.z) | ((unsigned)f2bf(v.w) << 16);
    *reinterpret_cast<uint2*>(d + i) = p;
}

// zero rk pad rows [512,640) for all 12 layers
__global__ __launch_bounds__(256)
void rkpad12_k(us* __restrict__ rk)
{
    int i = blockIdx.x * 256 + threadIdx.x;   // 98304 uint4 total
    int l = i >> 13, r = i & 8191;
    reinterpret_cast<uint4*>(rk + (long)l * RKL + 512 * 1024)[r] = make_uint4(0, 0, 0, 0);
}

// concat per-layer qkv biases: bqkv[l][3072] = [bq|bk|bv]
__global__ __launch_bounds__(256)
void bcat_k(const float* __restrict__ bq, const float* __restrict__ bk,
            const float* __restrict__ bv, float* __restrict__ o)
{
    int i = blockIdx.x * 256 + threadIdx.x;       // 12*3072
    int l = i / 3072, rr = i % 3072, seg = rr >> 10, c = rr & 1023;
    const float* s = seg == 0 ? bq : seg == 1 ? bk : bv;
    o[i] = s[l * 1024 + c];
}

// =====================================================================
// LayerNorm D=1024 fp32 -> bf16, one block/row (prologue only)
// =====================================================================
__global__ __launch_bounds__(256)
void ln_k(const float* __restrict__ x, us* __restrict__ y,
          const float* __restrict__ sc, const float* __restrict__ bi)
{
    int row = blockIdx.x;
    const float* xr = x + (long)row * ND;
    int d4 = threadIdx.x * 4;
    float4 v = *reinterpret_cast<const float4*>(&xr[d4]);
    float sum = v.x + v.y + v.z + v.w;
    float sq  = v.x * v.x + v.y * v.y + v.z * v.z + v.w * v.w;
#pragma unroll
    for (int o = 32; o; o >>= 1) { sum += __shfl_xor(sum, o); sq += __shfl_xor(sq, o); }
    __shared__ float red[8];
    int w = threadIdx.x >> 6;
    if ((threadIdx.x & 63) == 0) { red[w] = sum; red[4 + w] = sq; }
    __syncthreads();
    sum = red[0] + red[1] + red[2] + red[3];
    sq  = red[4] + red[5] + red[6] + red[7];
    float mean = sum * (1.f / ND);
    float var  = fmaxf(sq * (1.f / ND) - mean * mean, 0.f);
    float inv  = rsqrtf(var + 1e-5f);
    float4 s4 = *reinterpret_cast<const float4*>(&sc[d4]);
    float4 b4 = *reinterpret_cast<const float4*>(&bi[d4]);
    uint2 p;
    p.x = (unsigned)f2bf((v.x - mean) * inv * s4.x + b4.x)
        | ((unsigned)f2bf((v.y - mean) * inv * s4.y + b4.y) << 16);
    p.y = (unsigned)f2bf((v.z - mean) * inv * s4.z + b4.z)
        | ((unsigned)f2bf((v.w - mean) * inv * s4.w + b4.w) << 16);
    *reinterpret_cast<uint2*>(y + (long)row * ND + d4) = p;
}

// sinusoid pos-emb (TXL order), bf16 out
__global__ __launch_bounds__(256)
void pemb_k(us* __restrict__ p)
{
    int t = blockIdx.x;
    float pos = (float)(NT - 1 - t);
    for (int j = threadIdx.x; j < ND / 2; j += 256) {
        float invf = expf(-(float)j * (9.210340371976184f / 512.0f));
        float ang  = pos * invf;
        p[(long)t * ND + j]           = f2bf(sinf(ang));
        p[(long)t * ND + ND / 2 + j]  = f2bf(cosf(ang));
    }
}

// adaptive input embedding -> h fp32
__global__ __launch_bounds__(256)
void embed_k(const int* __restrict__ x,
             const float* __restrict__ e0, const float* __restrict__ e1,
             const float* __restrict__ e2, const float* __restrict__ p1,
             const float* __restrict__ p2, float* __restrict__ h)
{
    __shared__ float e[256];
    int tok = blockIdx.x;
    int v = x[tok];
    float* outp = h + (long)tok * ND;
    if (v < 2000) {
        const float* r = e0 + (long)v * ND;
        for (int d = threadIdx.x; d < ND; d += 256) outp[d] = r[d] * 32.0f;
    } else if (v < 8000) {
        const float* r = e1 + (long)(v - 2000) * 256;
        e[threadIdx.x] = r[threadIdx.x];
        __syncthreads();
        for (int d = threadIdx.x; d < ND; d += 256) {
            float acc = 0.f;
#pragma unroll 4
            for (int i = 0; i < 256; ++i) acc += e[i] * p1[(long)i * ND + d];
            outp[d] = acc * 32.0f;
        }
    } else {
        const float* r = e2 + (long)(v - 8000) * 64;
        if (threadIdx.x < 64) e[threadIdx.x] = r[threadIdx.x];
        __syncthreads();
        for (int d = threadIdx.x; d < ND; d += 256) {
            float acc = 0.f;
#pragma unroll 4
            for (int i = 0; i < 64; ++i) acc += e[i] * p2[(long)i * ND + d];
            outp[d] = acc * 32.0f;
        }
    }
}

// ---------------------------------------------------------------- host
extern "C" void kernel_launch(void* const* d_in, const int* in_sizes, int n_in,
                              void* d_out, int out_size, void* d_ws, size_t ws_size,
                              hipStream_t stream)
{
    (void)in_sizes; (void)n_in; (void)out_size;
    const int*   x     = (const int*)  d_in[0];
    const float* emb0  = (const float*)d_in[1];
    const float* emb1  = (const float*)d_in[2];
    const float* emb2  = (const float*)d_in[3];
    const float* proj1 = (const float*)d_in[4];
    const float* proj2 = (const float*)d_in[5];
    const float* obias = (const float*)d_in[6];
    const float* rwb   = (const float*)d_in[7];
    const float* rrb   = (const float*)d_in[8];
    const float* ln1s  = (const float*)d_in[9];
    const float* ln1b  = (const float*)d_in[10];
    const float* Wq    = (const float*)d_in[11];
    const float* bq    = (const float*)d_in[12];
    const float* Wk    = (const float*)d_in[13];
    const float* bk    = (const float*)d_in[14];
    const float* Wv    = (const float*)d_in[15];
    const float* bv    = (const float*)d_in[16];
    const float* Wr    = (const float*)d_in[17];
    const float* Wo    = (const float*)d_in[18];
    const float* bo    = (const float*)d_in[19];
    const float* ln2s  = (const float*)d_in[20];
    const float* ln2b  = (const float*)d_in[21];
    const float* W1    = (const float*)d_in[22];
    const float* b1    = (const float*)d_in[23];
    const float* W2    = (const float*)d_in[24];
    const float* b2    = (const float*)d_in[25];
    float* out = (float*)d_out;

    // ---- d_out scratch (us-unit offsets); all dead before vocab GEMMs ----
    us* ob      = (us*)out;
    us* qkvbuf  = ob;                 // 6,291,456  (qw|qr|k)
    us* mid_bf  = ob +  6291456;      // 8,388,608  [2048][4096]
    us* vt_bf   = ob + 14680064;      // 2,097,152  [64][64][512]
    us* o_bf    = ob + 16777216;      // 2,097,152  [2048][1024]
    us* ain_bf  = ob + 18874368;      // 2,097,152  [2048][1024]
    us* rk_all  = ob + 20971520;      // 7,864,320  [12][640][1024] (pad rows zero)
    us* pemb_bf = ob + 28835840;      //   524,288  [512][1024]
    // fallback per-layer weight scratch (only used if ws too small)
    us* wqkv_sc = ob + 29360128;      // 3,145,728
    us* wr_sc   = ob + 32505856;      // 1,048,576
    us* wo_sc   = ob + 33554432;      // 1,048,576
    us* w1_sc   = ob + 34603008;      // 4,194,304
    us* w2_sc   = ob + 38797312;      // 4,194,304  (ends 42,991,616 us)
    float* pffn = out + 21495808;     // 8,388,608 f: [4][2048][1024] fp32 partials
    float* pwo  = out + 29884416;     // 4,194,304 f: [2][2048][1024] fp32 partials

    // ---- d_ws layout ----
    float* wsf      = (float*)d_ws;
    float* h        = wsf;                         // 2,097,152 f
    us*    h_bf     = (us*)(wsf + 2097152);
    us*    hp1_bf   = h_bf   + 2097152;            // 524,288
    us*    hp2_bf   = hp1_bf + 524288;             // 131,072
    us*    emb0_bf  = hp2_bf + 131072;             // 2048x1024 (2000 real)
    us*    emb1_bf  = emb0_bf + 2097152;           // 6144x256  (6000 real)
    us*    emb2_bf  = emb1_bf + 1572864;           // 24064x64  (24000 real)
    us*    proj1_bf = emb2_bf + 1540096;           // 256x1024
    us*    proj2_bf = proj1_bf + 262144;           // 64x1024
    float* bqkv     = (float*)(proj2_bf + 65536);  // 12*3072 f
    us*    wqkv_all = (us*)(bqkv + 36864);         // [12][3072][1024]
    us*    wr_all   = wqkv_all + (long)NL * 3072 * 1024;
    us*    wo_all   = wr_all   + (long)NL * 1024 * 1024;
    us*    w1_all   = wo_all   + (long)NL * 1024 * 1024;   // [12][4096][1024]
    us*    w2_all   = w1_all   + (long)NL * 4096 * 1024;   // [12][1024][4096]
    const bool big  = ws_size >= (size_t)352273408;        // full weight cache fits

    // ---- one-time setup ----
    bcat_k<<<144, 256, 0, stream>>>(bq, bk, bv, bqkv);
    convall_k<<<5320, 256, 0, stream>>>(emb0, emb1, emb2, proj1, proj2,
                                        emb0_bf, emb1_bf, emb2_bf, proj1_bf, proj2_bf);
    pemb_k<<<NT, 256, 0, stream>>>(pemb_bf);
    rkpad12_k<<<384, 256, 0, stream>>>(rk_all);
    embed_k<<<NBT, 256, 0, stream>>>(x, emb0, emb1, emb2, proj1, proj2, h);
    if (big) {   // batched all-layer weight transpose-convert (7 launches)
        tconv_k<<<dim3(32, 32, NL), 256, 0, stream>>>(Wq, wqkv_all,           1024, 1024, 1048576, 3145728);
        tconv_k<<<dim3(32, 32, NL), 256, 0, stream>>>(Wk, wqkv_all + 1048576, 1024, 1024, 1048576, 3145728);
        tconv_k<<<dim3(32, 32, NL), 256, 0, stream>>>(Wv, wqkv_all + 2097152, 1024, 1024, 1048576, 3145728);
        tconv_k<<<dim3(32, 32, NL), 256, 0, stream>>>(Wr, wr_all, 1024, 1024, 1048576, 1048576);
        tconv_k<<<dim3(32, 32, NL), 256, 0, stream>>>(Wo, wo_all, 1024, 1024, 1048576, 1048576);
        tconv_k<<<dim3(128, 32, NL), 256, 0, stream>>>(W1, w1_all, 1024, 4096, 4194304, 4194304);
        tconv_k<<<dim3(32, 128, NL), 256, 0, stream>>>(W2, w2_all, 4096, 1024, 4194304, 4194304);
        // batched r_k for all layers: rk_all[l] = pemb @ Wr[l]
        bgemm_k<64, 64, 0, true><<<dim3(16, 8, NL), 256, 0, stream>>>(
            pemb_bf, wr_all, rk_all, nullptr, nullptr, nullptr, nullptr, nullptr,
            1024, 1024, 1024, 1024, 1024,
            1, 0, 0, 1048576, 0, RKL, 0);
    }
    // prologue: ln1 of layer 0
    ln_k<<<NBT, 256, 0, stream>>>(h, ain_bf, ln1s, ln1b);

    for (int l = 0; l < NL; ++l) {
        const us* wqkv_t = big ? wqkv_all + (long)l * 3145728 : wqkv_sc;
        const us* wo_t   = big ? wo_all   + (long)l * 1048576 : wo_sc;
        const us* w1_t   = big ? w1_all   + (long)l * 4194304 : w1_sc;
        const us* w2_t   = big ? w2_all   + (long)l * 4194304 : w2_sc;
        if (!big) {
            const long wOff = (long)l * ND * ND;
            tconv_k<<<dim3(32, 32), 256, 0, stream>>>(Wq + wOff, wqkv_sc,           1024, 1024, 0, 0);
            tconv_k<<<dim3(32, 32), 256, 0, stream>>>(Wk + wOff, wqkv_sc + 1048576, 1024, 1024, 0, 0);
            tconv_k<<<dim3(32, 32), 256, 0, stream>>>(Wv + wOff, wqkv_sc + 2097152, 1024, 1024, 0, 0);
            tconv_k<<<dim3(32, 32), 256, 0, stream>>>(Wr + wOff, wr_sc, 1024, 1024, 0, 0);
            tconv_k<<<dim3(32, 32), 256, 0, stream>>>(Wo + wOff, wo_sc, 1024, 1024, 0, 0);
            tconv_k<<<dim3(128, 32), 256, 0, stream>>>(W1 + (long)l * ND * NF, w1_sc, 1024, 4096, 0, 0);
            tconv_k<<<dim3(32, 128), 256, 0, stream>>>(W2 + (long)l * ND * NF, w2_sc, 4096, 1024, 0, 0);
            bgemm_k<64, 64, 0, true><<<dim3(16, 8, 1), 256, 0, stream>>>(
                pemb_bf, wr_sc, rk_all + (long)l * RKL, nullptr, nullptr, nullptr, nullptr, nullptr,
                1024, 1024, 1024, 1024, 1024, 0, 0, 0, 0, 0, 0, 0);
        }

        // fused QKV (EPI=3): qw,qr,k into qkvbuf; v straight into vt
        bgemm_k<128, 64, 3, true><<<dim3(48, 16, 1), 256, 0, stream>>>(
            ain_bf, wqkv_t, qkvbuf, bqkv + l * 3072, nullptr, rwb, rrb, vt_bf,
            3072, 1024, 1024, 1024, 1024, 0, 0, 0, 0, 0, 0, 0);
        // fused attention (load-balanced pairing, 2-phase pipeline)
        fattn_k<<<dim3(4, NB * NH), 256, 0, stream>>>(
            qkvbuf, vt_bf, rk_all + (long)l * RKL, o_bf);
        // Wo split-K=2 at 128x64 tiles -> fp32 partials
        bgemm_k<128, 64, 0, false><<<dim3(16, 16, 2), 256, 0, stream>>>(
            o_bf, wo_t, pwo, nullptr, nullptr, nullptr, nullptr, nullptr,
            1024, 512, 1024, 1024, 1024,
            1, 512, 0, 512, 0, 2097152, 0);
        // h += bo + sum(pwo); ain = LN2(h)
        redln_k<2, 0><<<NBT, 256, 0, stream>>>(
            pwo, bo + l * ND, h, ain_bf, ln2s + l * ND, ln2b + l * ND);

        // FFN
        bgemm_k<128, 128, 1, true><<<dim3(32, 16, 1), 256, 0, stream>>>(
            ain_bf, w1_t, mid_bf, b1 + (long)l * NF, nullptr, nullptr, nullptr, nullptr,
            4096, 1024, 1024, 1024, 4096, 0, 0, 0, 0, 0, 0, 0);
        // FFN2 split-K=4 at 128x128 tiles -> fp32 partials
        bgemm_k<128, 128, 0, false><<<dim3(8, 16, 4), 256, 0, stream>>>(
            mid_bf, w2_t, pffn, nullptr, nullptr, nullptr, nullptr, nullptr,
            1024, 1024, 4096, 4096, 1024,
            1, 1024, 0, 1024, 0, 2097152, 0);
        // h += b2 + sum(pffn); then LN1(next layer) or bf16 convert (last)
        if (l < NL - 1)
            redln_k<4, 0><<<NBT, 256, 0, stream>>>(
                pffn, b2 + (long)l * ND, h, ain_bf,
                ln1s + (l + 1) * ND, ln1b + (l + 1) * ND);
        else
            redln_k<4, 1><<<NBT, 256, 0, stream>>>(
                pffn, b2 + (long)l * ND, h, h_bf, nullptr, nullptr);
    }

    // ---- tied adaptive-softmax output: (h @ proj^T) @ emb^T ----
    // cluster 0: cols [0,2000)
    bgemm_k<128, 64, 0, false><<<dim3(32, 16, 1), 256, 0, stream>>>(
        h_bf, emb0_bf, out, obias, nullptr, nullptr, nullptr, nullptr,
        2000, 1024, 1024, 1024, NV, 0, 0, 0, 0, 0, 0, 0);
    // cluster 1: hp1 = h @ proj1^T ; cols [2000,8000)
    bgemm_k<64, 64, 0, true><<<dim3(4, 32, 1), 256, 0, stream>>>(
        h_bf, proj1_bf, hp1_bf, nullptr, nullptr, nullptr, nullptr, nullptr,
        256, 1024, 1024, 1024, 256, 0, 0, 0, 0, 0, 0, 0);
    bgemm_k<128, 128, 0, false><<<dim3(47, 16, 1), 256, 0, stream>>>(
        hp1_bf, emb1_bf, out + 2000, obias + 2000, nullptr, nullptr, nullptr, nullptr,
        6000, 256, 256, 256, NV, 0, 0, 0, 0, 0, 0, 0);
    // cluster 2: hp2 = h @ proj2^T ; cols [8000,32000)
    bgemm_k<64, 64, 0, true><<<dim3(1, 32, 1), 256, 0, stream>>>(
        h_bf, proj2_bf, hp2_bf, nullptr, nullptr, nullptr, nullptr, nullptr,
        64, 1024, 1024, 1024, 64, 0, 0, 0, 0, 0, 0, 0);
    bgemm_k<128, 128, 0, false><<<dim3(188, 16, 1), 256, 0, stream>>>(
        hp2_bf, emb2_bf, out + 8000, obias + 8000, nullptr, nullptr, nullptr, nullptr,
        24000, 64, 64, 64, NV, 0, 0, 0, 0, 0, 0, 0);
}